// Round 1
// 430.054 us; speedup vs baseline: 1.0018x; 1.0018x over previous
//
#include <hip/hip_runtime.h>
#include <cstdint>
#include <cstddef>

using u16 = unsigned short;
using u32 = unsigned int;

typedef __bf16 bf16x8 __attribute__((ext_vector_type(8)));
typedef float f32x4 __attribute__((ext_vector_type(4)));

static constexpr int Bb = 2, S = 2048, D = 1024, H = 16, W = 64, F = 4096;
static constexpr int M = Bb * S;   // 4096 rows

__device__ __forceinline__ float bf2f(u16 u) {
  union { u32 i; float f; } c; c.i = ((u32)u) << 16; return c.f;
}
__device__ __forceinline__ u16 f2bf(float f) {
  union { float f; u32 i; } c; c.f = f;
  u32 i = c.i;
  u32 r = (i + 0x7fffu + ((i >> 16) & 1u)) >> 16;
  return (u16)r;
}
__device__ __forceinline__ u16 f2bf_cvt(float f) {
  __bf16 b = (__bf16)f;
  union { __bf16 b; u16 u; } c; c.b = b; return c.u;
}
__device__ __forceinline__ __bf16 u2b(u16 x) {
  union { u16 u; __bf16 b; } c; c.u = x; return c.b;
}
__device__ __forceinline__ void stv(float* p, size_t i, float v) { p[i] = v; }
__device__ __forceinline__ void stv(u16* p, size_t i, float v)   { p[i] = f2bf(v); }
__device__ __forceinline__ float ldv(const float* p, size_t i) { return p[i]; }
__device__ __forceinline__ float ldv(const u16* p, size_t i)   { return bf2f(p[i]); }

__device__ __forceinline__ void async_cp16(const u16* g, u16* l) {
  __builtin_amdgcn_global_load_lds(
      (const __attribute__((address_space(1))) void*)g,
      (__attribute__((address_space(3))) void*)l, 16, 0, 0);
}

// 8x8 super-tile block swizzle for L2 locality. Requires gridDim.x%8==0,
// gridDim.y%8==0. 64 consecutive blocks -> 8 A-tiles + 8 B-tiles (~4MB).
__device__ __forceinline__ void swizzle8(int& bx, int& by) {
  int bid = blockIdx.y * gridDim.x + blockIdx.x;
  int gpr = gridDim.x >> 3;
  int grp = bid >> 6, rem = bid & 63;
  int gm = grp / gpr, gn = grp - gm * gpr;
  by = gm * 8 + (rem >> 3);
  bx = gn * 8 + (rem & 7);
}

// ---------------------------------------------------------------------------
// fp32 -> bf16 elementwise convert (n % 1024 == 0)
// ---------------------------------------------------------------------------
__global__ __launch_bounds__(256) void conv_x_kernel(
    const float* __restrict__ src, u16* __restrict__ dst)
{
  int i = (blockIdx.x * 256 + threadIdx.x) * 4;
  float4 v = *(const float4*)(src + i);
  u16 r[4] = { f2bf(v.x), f2bf(v.y), f2bf(v.z), f2bf(v.w) };
  *(uint2*)(dst + i) = *(const uint2*)r;
}

// ---------------------------------------------------------------------------
// Weight transpose+convert: src (K,N) fp32 -> dst (N,K) bf16. 64x64 tiles.
// ---------------------------------------------------------------------------
__global__ __launch_bounds__(256) void transpose_w_kernel(
    const float* __restrict__ src, u16* __restrict__ dst, int K, int N)
{
  __shared__ __align__(16) u16 T[64][72];
  const int tid = threadIdx.x;
  const int n0 = blockIdx.x * 64, k0 = blockIdx.y * 64;
#pragma unroll
  for (int t = 0; t < 4; t++) {
    int idx = tid + t * 256;           // 0..1023 float4s
    int r = idx >> 4, c4 = (idx & 15) * 4;
    float4 v = *(const float4*)(src + (size_t)(k0 + r) * N + n0 + c4);
    T[c4 + 0][r] = f2bf(v.x); T[c4 + 1][r] = f2bf(v.y);
    T[c4 + 2][r] = f2bf(v.z); T[c4 + 3][r] = f2bf(v.w);
  }
  __syncthreads();
#pragma unroll
  for (int t = 0; t < 2; t++) {
    int idx = tid + t * 256;           // 0..511 uint4s
    int r = idx >> 3, c8 = (idx & 7) * 8;
    *(uint4*)(dst + (size_t)(n0 + r) * K + k0 + c8) = *(const uint4*)(&T[r][c8]);
  }
}

// ---------------------------------------------------------------------------
// m97-style GEMM, BK=64, 8x8 L2 swizzle. C = A(Mr,K) @ BT(N,K)^T + bias.
// 128x128 tile, 4 waves (2x2), each wave 64x64 (4x4 MFMA), 32 MFMA/stage.
// EPI: 0 plain, 1 gelu(exact), 2 fused-qkv permute (N=3072, scale on q).
// ---------------------------------------------------------------------------
template<int EPI, typename TC>
__global__ __launch_bounds__(256) void gemm_bt(
    const u16* __restrict__ A, const u16* __restrict__ BT,
    const float* __restrict__ bias, TC* __restrict__ C,
    int N, int K, float scale)
{
  __shared__ __align__(16) u16 As[2][128 * 32];
  __shared__ __align__(16) u16 Bs[2][128 * 32];
  const int tid = threadIdx.x;
  const int wave = tid >> 6, lane = tid & 63;
  const int quad = lane >> 4, l16 = lane & 15;
  int bx, by; swizzle8(bx, by);
  const int m0 = by * 128, n0 = bx * 128;
  const int wm = (wave >> 1) * 64, wn = (wave & 1) * 64;
  const int srow = lane >> 2;          // 0..15 within slot
  const int skoff = (lane & 3) * 8;    // 0/8/16/24

  f32x4 acc[4][4] = {};

  for (int k0 = 0; k0 < K; k0 += 64) {
#pragma unroll
    for (int h = 0; h < 2; h++) {
#pragma unroll
      for (int t = 0; t < 2; t++) {
        int slot = wave * 2 + t;                   // 0..7 -> 16 rows each
        int row = slot * 16 + srow;
        const u16* ga = A  + (size_t)(m0 + row) * K + k0 + h * 32 + skoff;
        const u16* gb = BT + (size_t)(n0 + row) * K + k0 + h * 32 + skoff;
        async_cp16(ga, As[h] + slot * 512);        // lane i -> +16i bytes
        async_cp16(gb, Bs[h] + slot * 512);
      }
    }
    __syncthreads();

#pragma unroll
    for (int h = 0; h < 2; h++) {
      bf16x8 af[4], bfv[4];
#pragma unroll
      for (int i = 0; i < 4; i++)
        af[i] = *(const bf16x8*)(As[h] + (wm + i * 16 + l16) * 32 + quad * 8);
#pragma unroll
      for (int j = 0; j < 4; j++)
        bfv[j] = *(const bf16x8*)(Bs[h] + (wn + j * 16 + l16) * 32 + quad * 8);
#pragma unroll
      for (int i = 0; i < 4; i++)
#pragma unroll
        for (int j = 0; j < 4; j++)
          acc[i][j] = __builtin_amdgcn_mfma_f32_16x16x32_bf16(af[i], bfv[j], acc[i][j], 0, 0, 0);
    }
    __syncthreads();
  }

#pragma unroll
  for (int i = 0; i < 4; i++) {
#pragma unroll
    for (int j = 0; j < 4; j++) {
#pragma unroll
      for (int r = 0; r < 4; r++) {
        int row = m0 + wm + i * 16 + quad * 4 + r;
        int col = n0 + wn + j * 16 + l16;
        float val = acc[i][j][r] + bias[col];
        if (EPI == 1) {
          val = 0.5f * val * (1.0f + erff(val * 0.70710678118654752f));
        }
        if (EPI == 2) {
          int sel = col >> 10, c = col & 1023;       // D = 1024
          if (sel == 0) val *= scale;
          int bb = row >> 11, ss = row & 2047;       // S = 2048
          int hh = c >> 6,  ww = c & 63;             // W = 64
          u16* dst = (u16*)C + (size_t)sel * M * D;
          dst[(((size_t)(bb * H + hh) * S) + ss) * W + ww] = f2bf(val);
        } else {
          stv(C, (size_t)row * N + col, val);
        }
      }
    }
  }
}

// ---------------------------------------------------------------------------
// 128x64-tile GEMM (N=1024 matmuls), BK=64, 8x8 L2 swizzle.
// Waves 2x2; each wave 64(m) x 32(n) -> acc[4][2], 16 MFMA per stage.
// ---------------------------------------------------------------------------
template<typename TC>
__global__ __launch_bounds__(256) void gemm_bt_n64(
    const u16* __restrict__ A, const u16* __restrict__ BT,
    const float* __restrict__ bias, TC* __restrict__ C,
    int N, int K)
{
  __shared__ __align__(16) u16 As[2][128 * 32];
  __shared__ __align__(16) u16 Bs[2][64 * 32];
  const int tid = threadIdx.x;
  const int wave = tid >> 6, lane = tid & 63;
  const int quad = lane >> 4, l16 = lane & 15;
  int bx, by; swizzle8(bx, by);
  const int m0 = by * 128, n0 = bx * 64;
  const int wm = (wave >> 1) * 64, wn = (wave & 1) * 32;
  const int srow = lane >> 2;
  const int skoff = (lane & 3) * 8;

  f32x4 acc[4][2] = {};

  for (int k0 = 0; k0 < K; k0 += 64) {
#pragma unroll
    for (int h = 0; h < 2; h++) {
#pragma unroll
      for (int t = 0; t < 2; t++) {
        int slot = wave * 2 + t;
        int row = slot * 16 + srow;
        async_cp16(A + (size_t)(m0 + row) * K + k0 + h * 32 + skoff, As[h] + slot * 512);
      }
      int row = wave * 16 + srow;
      async_cp16(BT + (size_t)(n0 + row) * K + k0 + h * 32 + skoff, Bs[h] + wave * 512);
    }
    __syncthreads();

#pragma unroll
    for (int h = 0; h < 2; h++) {
      bf16x8 af[4], bfv[2];
#pragma unroll
      for (int i = 0; i < 4; i++)
        af[i] = *(const bf16x8*)(As[h] + (wm + i * 16 + l16) * 32 + quad * 8);
#pragma unroll
      for (int j = 0; j < 2; j++)
        bfv[j] = *(const bf16x8*)(Bs[h] + (wn + j * 16 + l16) * 32 + quad * 8);
#pragma unroll
      for (int i = 0; i < 4; i++)
#pragma unroll
        for (int j = 0; j < 2; j++)
          acc[i][j] = __builtin_amdgcn_mfma_f32_16x16x32_bf16(af[i], bfv[j], acc[i][j], 0, 0, 0);
    }
    __syncthreads();
  }

#pragma unroll
  for (int i = 0; i < 4; i++) {
#pragma unroll
    for (int j = 0; j < 2; j++) {
#pragma unroll
      for (int r = 0; r < 4; r++) {
        int row = m0 + wm + i * 16 + quad * 4 + r;
        int col = n0 + wn + j * 16 + l16;
        stv(C, (size_t)row * N + col, acc[i][j][r] + bias[col]);
      }
    }
  }
}

// ---------------------------------------------------------------------------
// V transpose: (BH, S, W) -> (BH, W, S), 64x64 tiles via LDS.
// ---------------------------------------------------------------------------
__global__ __launch_bounds__(256) void transpose_v_kernel(
    const u16* __restrict__ v, u16* __restrict__ vt)
{
  __shared__ __align__(16) u16 T[64][72];
  const int bh = blockIdx.y, k0 = blockIdx.x * 64, tid = threadIdx.x;
#pragma unroll
  for (int it = 0; it < 2; it++) {
    int vv = tid + it * 256;
    int key = vv >> 3, w0 = (vv & 7) * 8;
    union { uint4 q; u16 e[8]; } u;
    u.q = *(const uint4*)(v + ((size_t)bh * S + k0 + key) * W + w0);
#pragma unroll
    for (int j = 0; j < 8; j++) T[w0 + j][key] = u.e[j];
  }
  __syncthreads();
#pragma unroll
  for (int it = 0; it < 2; it++) {
    int vv = tid + it * 256;
    int w = vv >> 3, koff = (vv & 7) * 8;
    *(uint4*)(vt + ((size_t)bh * W + w) * S + k0 + koff) = *(const uint4*)(&T[w][koff]);
  }
}

// ---------------------------------------------------------------------------
// Flash attention (MFMA): block = 64 q-rows x one (b,h). 4 waves x 16 rows.
// LDS tiles in [2][64][32] plane layout, 16B-slot XOR-swizzled:
//   slot' = slot ^ ((row>>1)&3)
// applied on BOTH the staging ds_write_b128 and the fragment ds_read_b128
// (both-sides-or-neither; reg-staged so both sides are swizzlable).
// Fragment reads (row = base16 + l16, slot = quad) become per-lane constant
// slot' = quad ^ ((l16>>1)&3): an 8-lane b128 cycle-group (rows 0..7) now
// covers all 8 bank groups -> conflict-free (was ~8-way).
// No max-tracking: scores bounded; p = exp(s) directly; l via ones-column
// MFMA. Register prefetch pipeline for K/V tiles.
// ---------------------------------------------------------------------------
__global__ __launch_bounds__(256) void fattn_kernel(
    const u16* __restrict__ q, const u16* __restrict__ k,
    const u16* __restrict__ vt, const int* __restrict__ mask,
    u16* __restrict__ out)
{
  __shared__ __align__(16) u16 QP[2][64][32];   // Q staging, then P tiles
  __shared__ __align__(16) u16 Kl[2][64][32];   // K tile [key][w]
  __shared__ __align__(16) u16 Vl[2][64][32];   // V^T tile [w][key]
  __shared__ float msk[64];

  const int tid = threadIdx.x, wave = tid >> 6, lane = tid & 63;
  const int quad = lane >> 4, l16 = lane & 15;
  const int bh = blockIdx.y, b = bh >> 4, h = bh & 15;
  const int q0 = blockIdx.x * 64;
  const int w16 = wave * 16;
  // staging coords: rows sr and sr+32, global 16B chunk sg = tid&7
  const int sr  = tid >> 3;              // 0..31
  const int sg  = tid & 7;               // chunk along W: 0..7
  const int sp  = sg >> 2;               // plane (cols 0-31 / 32-63)
  const int sc0 = sg * 8;                // global col (u16 units)
  // swizzled in-plane col; note ((sr+32)>>1)&3 == (sr>>1)&3, so one value
  const int ssw = (((sg & 3) ^ ((sr >> 1) & 3)) << 3);
  // swizzled fragment-read col (u16): slot' = quad ^ ((l16>>1)&3)
  // (valid for any row = 16*t + l16 since (16*t>>1)&3 == 0)
  const int rq = ((quad ^ ((l16 >> 1) & 3)) << 3);

  // stage Q tile (swizzled)
  *(uint4*)(&QP[sp][sr     ][ssw]) = *(const uint4*)(q + ((size_t)bh * S + q0 + sr     ) * W + sc0);
  *(uint4*)(&QP[sp][sr + 32][ssw]) = *(const uint4*)(q + ((size_t)bh * S + q0 + sr + 32) * W + sc0);
  __syncthreads();
  bf16x8 aq[2];
#pragma unroll
  for (int kc = 0; kc < 2; kc++)
    aq[kc] = *(const bf16x8*)(&QP[kc][w16 + l16][rq]);

  // constant ones B-fragment: column 0 of a 16-wide tile = 1, rest 0
  bf16x8 ones;
  {
    u16 ov = (l16 == 0) ? (u16)0x3F80 : (u16)0;
#pragma unroll
    for (int j = 0; j < 8; j++) ones[j] = u2b(ov);
  }

  f32x4 o_acc[4] = {};
  f32x4 l_acc = {};

  // prefetch tile 0
  uint4 kr0, kr1, vr0, vr1;
  int mv = 0;
  kr0 = *(const uint4*)(k  + ((size_t)bh * S + sr     ) * W + sc0);
  kr1 = *(const uint4*)(k  + ((size_t)bh * S + sr + 32) * W + sc0);
  vr0 = *(const uint4*)(vt + ((size_t)bh * W + sr     ) * S + sc0);
  vr1 = *(const uint4*)(vt + ((size_t)bh * W + sr + 32) * S + sc0);
  if (tid < 64) mv = mask[b * S + tid];

  for (int kt = 0; kt < S / 64; kt++) {
    __syncthreads();   // prior-iteration LDS consumers done
    *(uint4*)(&Kl[sp][sr     ][ssw]) = kr0;
    *(uint4*)(&Kl[sp][sr + 32][ssw]) = kr1;
    *(uint4*)(&Vl[sp][sr     ][ssw]) = vr0;
    *(uint4*)(&Vl[sp][sr + 32][ssw]) = vr1;
    if (tid < 64) msk[tid] = -10000.0f * (1.0f - (float)mv);
    __syncthreads();

    // prefetch tile kt+1 (vmcnt consumed at next iteration's ds_write)
    if (kt + 1 < S / 64) {
      int kn = (kt + 1) * 64;
      kr0 = *(const uint4*)(k  + ((size_t)bh * S + kn + sr     ) * W + sc0);
      kr1 = *(const uint4*)(k  + ((size_t)bh * S + kn + sr + 32) * W + sc0);
      vr0 = *(const uint4*)(vt + ((size_t)bh * W + sr     ) * S + kn + sc0);
      vr1 = *(const uint4*)(vt + ((size_t)bh * W + sr + 32) * S + kn + sc0);
      if (tid < 64) mv = mask[b * S + kn + tid];
    }

    // QK^T
    f32x4 sc[4] = {};
#pragma unroll
    for (int tn = 0; tn < 4; tn++) {
#pragma unroll
      for (int kc = 0; kc < 2; kc++) {
        bf16x8 bk = *(const bf16x8*)(&Kl[kc][tn * 16 + l16][rq]);
        sc[tn] = __builtin_amdgcn_mfma_f32_16x16x32_bf16(aq[kc], bk, sc[tn], 0, 0, 0);
      }
    }
    // p = exp(s + mask) -> LDS (C->A layout), swizzled scalar stores.
    // write slot for col c=(tn&1)*16+l16, row=w16+quad*4+r:
    //   s' = ((tn&1)*2 + (l16>>3)) ^ ((quad*2 + (r>>1)) & 3)
#pragma unroll
    for (int tn = 0; tn < 4; tn++) {
      float mm = msk[tn * 16 + l16];
      int s0 = (tn & 1) * 2 + (l16 >> 3);
#pragma unroll
      for (int r = 0; r < 4; r++) {
        float pv = __expf(sc[tn][r] + mm);
        int xr = (quad * 2 + (r >> 1)) & 3;
        QP[tn >> 1][w16 + quad * 4 + r][((s0 ^ xr) << 3) | (l16 & 7)] = f2bf_cvt(pv);
      }
    }
    // no barrier: P slab is wave-private; same-wave DS ops are ordered

    // PV (+ ones column for the row sums)
#pragma unroll
    for (int kc = 0; kc < 2; kc++) {
      bf16x8 ap = *(const bf16x8*)(&QP[kc][w16 + l16][rq]);
#pragma unroll
      for (int tn = 0; tn < 4; tn++) {
        bf16x8 bv = *(const bf16x8*)(&Vl[kc][tn * 16 + l16][rq]);
        o_acc[tn] = __builtin_amdgcn_mfma_f32_16x16x32_bf16(ap, bv, o_acc[tn], 0, 0, 0);
      }
      l_acc = __builtin_amdgcn_mfma_f32_16x16x32_bf16(ap, ones, l_acc, 0, 0, 0);
    }
  }

  // epilogue: l lives in column 0 (lanes with l16==0); broadcast per quad
#pragma unroll
  for (int r = 0; r < 4; r++) {
    float lsum = __shfl(l_acc[r], lane & 0x30);
    float inv = 1.0f / lsum;
    int sg2 = q0 + w16 + quad * 4 + r;
#pragma unroll
    for (int tn = 0; tn < 4; tn++) {
      out[((size_t)b * S + sg2) * D + h * W + tn * 16 + l16] = f2bf_cvt(o_acc[tn][r] * inv);
    }
  }
}

// ---------------------------------------------------------------------------
// Fused residual + LayerNorm, one WAVE per row (no block barriers).
// grid = M/4 blocks of 256 threads.
// ---------------------------------------------------------------------------
template<typename TA, typename TR, typename TO>
__global__ __launch_bounds__(256) void ln_res_kernel(
    const TA* __restrict__ a, const TR* __restrict__ r,
    const float* __restrict__ g, const float* __restrict__ be,
    TO* __restrict__ out)
{
  const int tid = threadIdx.x, lane = tid & 63;
  const int row = blockIdx.x * 4 + (tid >> 6);
  const TA* ap = a + (size_t)row * D;
  const TR* rp = r + (size_t)row * D;
  float hv[16];
  float s = 0.f;
#pragma unroll
  for (int c = 0; c < 16; c++) {
    int d = c * 64 + lane;
    hv[c] = ldv(ap, d) + ldv(rp, d);
    s += hv[c];
  }
#pragma unroll
  for (int d = 1; d < 64; d <<= 1) s += __shfl_xor(s, d);
  float mean = s * (1.0f / D);
  float v = 0.f;
#pragma unroll
  for (int c = 0; c < 16; c++) { float t = hv[c] - mean; v += t * t; }
#pragma unroll
  for (int d = 1; d < 64; d <<= 1) v += __shfl_xor(v, d);
  float inv = rsqrtf(v * (1.0f / D) + 1e-12f);
#pragma unroll
  for (int c = 0; c < 16; c++) {
    int d = c * 64 + lane;
    stv(out, (size_t)row * D + d, g[d] * ((hv[c] - mean) * inv) + be[d]);
  }
}

// ---------------------------------------------------------------------------
extern "C" void kernel_launch(void* const* d_in, const int* in_sizes, int n_in,
                              void* d_out, int out_size, void* d_ws, size_t ws_size,
                              hipStream_t stream)
{
  const float* x  = (const float*)d_in[0];
  const int* mask = (const int*)d_in[1];
  const float* wq = (const float*)d_in[2];  const float* bq  = (const float*)d_in[3];
  const float* wk = (const float*)d_in[4];  const float* bk  = (const float*)d_in[5];
  const float* wv = (const float*)d_in[6];  const float* bv  = (const float*)d_in[7];
  const float* wo = (const float*)d_in[8];  const float* bo  = (const float*)d_in[9];
  const float* g1 = (const float*)d_in[10]; const float* b1  = (const float*)d_in[11];
  const float* w1 = (const float*)d_in[12]; const float* bf1 = (const float*)d_in[13];
  const float* w2 = (const float*)d_in[14]; const float* bf2 = (const float*)d_in[15];
  const float* g2 = (const float*)d_in[16]; const float* b2  = (const float*)d_in[17];

  // ws layout (peak 48 MB):
  //  A [0,8M):   wqkvT(6M)+woT(2M) -> w1T(8M) -> w2T(8M)    (JIT reuse)
  //  B [8,16M):  xb -> vt -> ff1[0:8M)
  //  C [16,24M): q  -> proj -> ff1[8:16M)
  //  D [24,32M): k  -> ff1[16:24M)
  //  E [32,40M): v  -> attn -> ff1[24:32M)
  //  F [40,48M): bqkv(12KB, dead by LN1) -> h1
  //  ff2 goes to d_out (fp32); LN2 runs in place on d_out.
  char* ws = (char*)d_ws;
  const size_t MB = 1024 * 1024;
  u16* wqkvT = (u16*)(ws + 0 * MB);          // (3072, 1024) bf16
  u16* woT   = (u16*)(ws + 6 * MB);          // (1024, 1024)
  u16* w1T   = (u16*)(ws + 0 * MB);          // (4096, 1024) after proj
  u16* w2T   = (u16*)(ws + 0 * MB);          // (1024, 4096) after ffn1
  u16* xb    = (u16*)(ws + 8 * MB);
  u16* vt    = (u16*)(ws + 8 * MB);
  u16* q     = (u16*)(ws + 16 * MB);
  u16* proj  = (u16*)(ws + 16 * MB);
  u16* kb    = (u16*)(ws + 24 * MB);
  u16* vb    = (u16*)(ws + 32 * MB);
  u16* attn  = (u16*)(ws + 32 * MB);
  u16* ff1   = (u16*)(ws + 8 * MB);          // 32 MB: [8,40)
  float* bqkv = (float*)(ws + 40 * MB);      // 12 KB
  u16* h1    = (u16*)(ws + 40 * MB);
  float* out = (float*)d_out;

  dim3 blk(256);

  // prep: x -> bf16; weights -> bf16 transposed; bias concat
  conv_x_kernel<<<dim3(M * D / 1024), blk, 0, stream>>>(x, xb);
  transpose_w_kernel<<<dim3(16, 16), blk, 0, stream>>>(wq, wqkvT,            D, D);
  transpose_w_kernel<<<dim3(16, 16), blk, 0, stream>>>(wk, wqkvT + 1024*1024, D, D);
  transpose_w_kernel<<<dim3(16, 16), blk, 0, stream>>>(wv, wqkvT + 2048*1024, D, D);
  transpose_w_kernel<<<dim3(16, 16), blk, 0, stream>>>(wo, woT,              D, D);
  hipMemcpyAsync(bqkv,        bq, D * sizeof(float), hipMemcpyDeviceToDevice, stream);
  hipMemcpyAsync(bqkv + 1024, bk, D * sizeof(float), hipMemcpyDeviceToDevice, stream);
  hipMemcpyAsync(bqkv + 2048, bv, D * sizeof(float), hipMemcpyDeviceToDevice, stream);

  // fused QKV GEMM: (M,1024) @ (1024,3072) -> q,k,v permuted (q scaled)
  gemm_bt<2, u16><<<dim3(3072 / 128, M / 128), blk, 0, stream>>>(
      xb, wqkvT, bqkv, q, 3072, D, 0.125f);

  transpose_v_kernel<<<dim3(S / 64, Bb * H), blk, 0, stream>>>(vb, vt);
  fattn_kernel<<<dim3(S / 64, Bb * H), blk, 0, stream>>>(q, kb, vt, mask, attn);

  // proj: N=1024 -> 128x64 tiles (512 blocks, 2/CU)
  gemm_bt_n64<u16><<<dim3(D / 64, M / 128), blk, 0, stream>>>(
      attn, woT, bo, proj, D, D);
  ln_res_kernel<float, u16, u16><<<dim3(M / 4), blk, 0, stream>>>(x, proj, g1, b1, h1);

  transpose_w_kernel<<<dim3(F / 64, D / 64), blk, 0, stream>>>(w1, w1T, D, F);
  gemm_bt<1, u16><<<dim3(F / 128, M / 128), blk, 0, stream>>>(
      h1, w1T, bf1, ff1, F, D, 1.0f);

  transpose_w_kernel<<<dim3(D / 64, F / 64), blk, 0, stream>>>(w2, w2T, F, D);
  // FFN2: N=1024 -> 128x64 tiles, fp32 out; LN2 in place on d_out
  gemm_bt_n64<float><<<dim3(D / 64, M / 128), blk, 0, stream>>>(
      ff1, w2T, bf2, out, D, F);
  ln_res_kernel<u16, float, float><<<dim3(M / 4), blk, 0, stream>>>(h1, out, g2, b2, out);
}

// Round 2
// 425.725 us; speedup vs baseline: 1.0120x; 1.0102x over previous
//
#include <hip/hip_runtime.h>
#include <cstdint>
#include <cstddef>

using u16 = unsigned short;
using u32 = unsigned int;

typedef __bf16 bf16x8 __attribute__((ext_vector_type(8)));
typedef float f32x4 __attribute__((ext_vector_type(4)));

static constexpr int Bb = 2, S = 2048, D = 1024, H = 16, W = 64, F = 4096;
static constexpr int M = Bb * S;   // 4096 rows

__device__ __forceinline__ float bf2f(u16 u) {
  union { u32 i; float f; } c; c.i = ((u32)u) << 16; return c.f;
}
__device__ __forceinline__ u16 f2bf(float f) {
  union { float f; u32 i; } c; c.f = f;
  u32 i = c.i;
  u32 r = (i + 0x7fffu + ((i >> 16) & 1u)) >> 16;
  return (u16)r;
}
__device__ __forceinline__ u16 f2bf_cvt(float f) {
  __bf16 b = (__bf16)f;
  union { __bf16 b; u16 u; } c; c.b = b; return c.u;
}
__device__ __forceinline__ __bf16 u2b(u16 x) {
  union { u16 u; __bf16 b; } c; c.u = x; return c.b;
}
__device__ __forceinline__ void stv(float* p, size_t i, float v) { p[i] = v; }
__device__ __forceinline__ void stv(u16* p, size_t i, float v)   { p[i] = f2bf(v); }
__device__ __forceinline__ float ldv(const float* p, size_t i) { return p[i]; }
__device__ __forceinline__ float ldv(const u16* p, size_t i)   { return bf2f(p[i]); }

__device__ __forceinline__ void async_cp16(const u16* g, u16* l) {
  __builtin_amdgcn_global_load_lds(
      (const __attribute__((address_space(1))) void*)g,
      (__attribute__((address_space(3))) void*)l, 16, 0, 0);
}

// 8x8 super-tile block swizzle for L2 locality. Requires gridDim.x%8==0,
// gridDim.y%8==0. 64 consecutive blocks -> 8 A-tiles + 8 B-tiles (~4MB).
__device__ __forceinline__ void swizzle8(int& bx, int& by) {
  int bid = blockIdx.y * gridDim.x + blockIdx.x;
  int gpr = gridDim.x >> 3;
  int grp = bid >> 6, rem = bid & 63;
  int gm = grp / gpr, gn = grp - gm * gpr;
  by = gm * 8 + (rem >> 3);
  bx = gn * 8 + (rem & 7);
}

// ---------------------------------------------------------------------------
// fp32 -> bf16 elementwise convert (n % 1024 == 0)
// ---------------------------------------------------------------------------
__global__ __launch_bounds__(256) void conv_x_kernel(
    const float* __restrict__ src, u16* __restrict__ dst)
{
  int i = (blockIdx.x * 256 + threadIdx.x) * 4;
  float4 v = *(const float4*)(src + i);
  u16 r[4] = { f2bf(v.x), f2bf(v.y), f2bf(v.z), f2bf(v.w) };
  *(uint2*)(dst + i) = *(const uint2*)r;
}

// ---------------------------------------------------------------------------
// Weight transpose+convert: src (K,N) fp32 -> dst (N,K) bf16. 64x64 tiles.
// ---------------------------------------------------------------------------
__global__ __launch_bounds__(256) void transpose_w_kernel(
    const float* __restrict__ src, u16* __restrict__ dst, int K, int N)
{
  __shared__ __align__(16) u16 T[64][72];
  const int tid = threadIdx.x;
  const int n0 = blockIdx.x * 64, k0 = blockIdx.y * 64;
#pragma unroll
  for (int t = 0; t < 4; t++) {
    int idx = tid + t * 256;           // 0..1023 float4s
    int r = idx >> 4, c4 = (idx & 15) * 4;
    float4 v = *(const float4*)(src + (size_t)(k0 + r) * N + n0 + c4);
    T[c4 + 0][r] = f2bf(v.x); T[c4 + 1][r] = f2bf(v.y);
    T[c4 + 2][r] = f2bf(v.z); T[c4 + 3][r] = f2bf(v.w);
  }
  __syncthreads();
#pragma unroll
  for (int t = 0; t < 2; t++) {
    int idx = tid + t * 256;           // 0..511 uint4s
    int r = idx >> 3, c8 = (idx & 7) * 8;
    *(uint4*)(dst + (size_t)(n0 + r) * K + k0 + c8) = *(const uint4*)(&T[r][c8]);
  }
}

// ---------------------------------------------------------------------------
// m97-style GEMM, BK=64, 8x8 L2 swizzle. C = A(Mr,K) @ BT(N,K)^T + bias.
// 128x128 tile, 4 waves (2x2), each wave 64x64 (4x4 MFMA), 32 MFMA/stage.
// EPI: 0 plain, 1 gelu(exact), 2 fused-qkv permute (N=3072, scale on q).
// ---------------------------------------------------------------------------
template<int EPI, typename TC>
__global__ __launch_bounds__(256) void gemm_bt(
    const u16* __restrict__ A, const u16* __restrict__ BT,
    const float* __restrict__ bias, TC* __restrict__ C,
    int N, int K, float scale)
{
  __shared__ __align__(16) u16 As[2][128 * 32];
  __shared__ __align__(16) u16 Bs[2][128 * 32];
  const int tid = threadIdx.x;
  const int wave = tid >> 6, lane = tid & 63;
  const int quad = lane >> 4, l16 = lane & 15;
  int bx, by; swizzle8(bx, by);
  const int m0 = by * 128, n0 = bx * 128;
  const int wm = (wave >> 1) * 64, wn = (wave & 1) * 64;
  const int srow = lane >> 2;          // 0..15 within slot
  const int skoff = (lane & 3) * 8;    // 0/8/16/24

  f32x4 acc[4][4] = {};

  for (int k0 = 0; k0 < K; k0 += 64) {
#pragma unroll
    for (int h = 0; h < 2; h++) {
#pragma unroll
      for (int t = 0; t < 2; t++) {
        int slot = wave * 2 + t;                   // 0..7 -> 16 rows each
        int row = slot * 16 + srow;
        const u16* ga = A  + (size_t)(m0 + row) * K + k0 + h * 32 + skoff;
        const u16* gb = BT + (size_t)(n0 + row) * K + k0 + h * 32 + skoff;
        async_cp16(ga, As[h] + slot * 512);        // lane i -> +16i bytes
        async_cp16(gb, Bs[h] + slot * 512);
      }
    }
    __syncthreads();

#pragma unroll
    for (int h = 0; h < 2; h++) {
      bf16x8 af[4], bfv[4];
#pragma unroll
      for (int i = 0; i < 4; i++)
        af[i] = *(const bf16x8*)(As[h] + (wm + i * 16 + l16) * 32 + quad * 8);
#pragma unroll
      for (int j = 0; j < 4; j++)
        bfv[j] = *(const bf16x8*)(Bs[h] + (wn + j * 16 + l16) * 32 + quad * 8);
#pragma unroll
      for (int i = 0; i < 4; i++)
#pragma unroll
        for (int j = 0; j < 4; j++)
          acc[i][j] = __builtin_amdgcn_mfma_f32_16x16x32_bf16(af[i], bfv[j], acc[i][j], 0, 0, 0);
    }
    __syncthreads();
  }

#pragma unroll
  for (int i = 0; i < 4; i++) {
#pragma unroll
    for (int j = 0; j < 4; j++) {
#pragma unroll
      for (int r = 0; r < 4; r++) {
        int row = m0 + wm + i * 16 + quad * 4 + r;
        int col = n0 + wn + j * 16 + l16;
        float val = acc[i][j][r] + bias[col];
        if (EPI == 1) {
          val = 0.5f * val * (1.0f + erff(val * 0.70710678118654752f));
        }
        if (EPI == 2) {
          int sel = col >> 10, c = col & 1023;       // D = 1024
          if (sel == 0) val *= scale;
          int bb = row >> 11, ss = row & 2047;       // S = 2048
          int hh = c >> 6,  ww = c & 63;             // W = 64
          u16* dst = (u16*)C + (size_t)sel * M * D;
          dst[(((size_t)(bb * H + hh) * S) + ss) * W + ww] = f2bf(val);
        } else {
          stv(C, (size_t)row * N + col, val);
        }
      }
    }
  }
}

// ---------------------------------------------------------------------------
// 128x64-tile GEMM (N=1024 matmuls), BK=64, 8x8 L2 swizzle.
// Waves 2x2; each wave 64(m) x 32(n) -> acc[4][2], 16 MFMA per stage.
// ---------------------------------------------------------------------------
template<typename TC>
__global__ __launch_bounds__(256) void gemm_bt_n64(
    const u16* __restrict__ A, const u16* __restrict__ BT,
    const float* __restrict__ bias, TC* __restrict__ C,
    int N, int K)
{
  __shared__ __align__(16) u16 As[2][128 * 32];
  __shared__ __align__(16) u16 Bs[2][64 * 32];
  const int tid = threadIdx.x;
  const int wave = tid >> 6, lane = tid & 63;
  const int quad = lane >> 4, l16 = lane & 15;
  int bx, by; swizzle8(bx, by);
  const int m0 = by * 128, n0 = bx * 64;
  const int wm = (wave >> 1) * 64, wn = (wave & 1) * 32;
  const int srow = lane >> 2;
  const int skoff = (lane & 3) * 8;

  f32x4 acc[4][2] = {};

  for (int k0 = 0; k0 < K; k0 += 64) {
#pragma unroll
    for (int h = 0; h < 2; h++) {
#pragma unroll
      for (int t = 0; t < 2; t++) {
        int slot = wave * 2 + t;
        int row = slot * 16 + srow;
        async_cp16(A + (size_t)(m0 + row) * K + k0 + h * 32 + skoff, As[h] + slot * 512);
      }
      int row = wave * 16 + srow;
      async_cp16(BT + (size_t)(n0 + row) * K + k0 + h * 32 + skoff, Bs[h] + wave * 512);
    }
    __syncthreads();

#pragma unroll
    for (int h = 0; h < 2; h++) {
      bf16x8 af[4], bfv[2];
#pragma unroll
      for (int i = 0; i < 4; i++)
        af[i] = *(const bf16x8*)(As[h] + (wm + i * 16 + l16) * 32 + quad * 8);
#pragma unroll
      for (int j = 0; j < 2; j++)
        bfv[j] = *(const bf16x8*)(Bs[h] + (wn + j * 16 + l16) * 32 + quad * 8);
#pragma unroll
      for (int i = 0; i < 4; i++)
#pragma unroll
        for (int j = 0; j < 2; j++)
          acc[i][j] = __builtin_amdgcn_mfma_f32_16x16x32_bf16(af[i], bfv[j], acc[i][j], 0, 0, 0);
    }
    __syncthreads();
  }

#pragma unroll
  for (int i = 0; i < 4; i++) {
#pragma unroll
    for (int j = 0; j < 2; j++) {
#pragma unroll
      for (int r = 0; r < 4; r++) {
        int row = m0 + wm + i * 16 + quad * 4 + r;
        int col = n0 + wn + j * 16 + l16;
        stv(C, (size_t)row * N + col, acc[i][j][r] + bias[col]);
      }
    }
  }
}

// ---------------------------------------------------------------------------
// V transpose: (BH, S, W) -> (BH, W, S), 64x64 tiles via LDS.
// ---------------------------------------------------------------------------
__global__ __launch_bounds__(256) void transpose_v_kernel(
    const u16* __restrict__ v, u16* __restrict__ vt)
{
  __shared__ __align__(16) u16 T[64][72];
  const int bh = blockIdx.y, k0 = blockIdx.x * 64, tid = threadIdx.x;
#pragma unroll
  for (int it = 0; it < 2; it++) {
    int vv = tid + it * 256;
    int key = vv >> 3, w0 = (vv & 7) * 8;
    union { uint4 q; u16 e[8]; } u;
    u.q = *(const uint4*)(v + ((size_t)bh * S + k0 + key) * W + w0);
#pragma unroll
    for (int j = 0; j < 8; j++) T[w0 + j][key] = u.e[j];
  }
  __syncthreads();
#pragma unroll
  for (int it = 0; it < 2; it++) {
    int vv = tid + it * 256;
    int w = vv >> 3, koff = (vv & 7) * 8;
    *(uint4*)(vt + ((size_t)bh * W + w) * S + k0 + koff) = *(const uint4*)(&T[w][koff]);
  }
}

// ---------------------------------------------------------------------------
// Flash attention (MFMA), KEY-SPLIT 2-way: grid (S/64, BH, 2). Block =
// 64 q-rows x one (b,h) x one key-half (1024 keys, 16 tiles). Grid 2048
// blocks -> 6 resident blocks/CU (LDS-capped; was grid-capped at 4) for
// latency hiding. Emits UN-NORMALIZED partial O (bf16) + partial l (f32);
// combine_attn sums halves and normalizes.
// LDS tiles [2][64][32] plane layout, 16B-slot XOR-swizzled
// (slot' = slot ^ ((row>>1)&3)) on both ds_write and ds_read.
// No max-tracking: scores bounded; p = exp(s) directly; l via ones-column
// MFMA. Register prefetch pipeline for K/V tiles.
// ---------------------------------------------------------------------------
__global__ __launch_bounds__(256) void fattn_kernel(
    const u16* __restrict__ q, const u16* __restrict__ k,
    const u16* __restrict__ vt, const int* __restrict__ mask,
    u16* __restrict__ o_parts, float* __restrict__ l_parts)
{
  __shared__ __align__(16) u16 QP[2][64][32];   // Q staging, then P tiles
  __shared__ __align__(16) u16 Kl[2][64][32];   // K tile [key][w]
  __shared__ __align__(16) u16 Vl[2][64][32];   // V^T tile [w][key]
  __shared__ float msk[64];

  const int tid = threadIdx.x, wave = tid >> 6, lane = tid & 63;
  const int quad = lane >> 4, l16 = lane & 15;
  const int bh = blockIdx.y, b = bh >> 4, h = bh & 15;
  const int q0 = blockIdx.x * 64;
  const int half = blockIdx.z;
  const int kbase = half * (S / 2);             // first key of this half
  const int w16 = wave * 16;
  // staging coords: rows sr and sr+32, global 16B chunk sg = tid&7
  const int sr  = tid >> 3;              // 0..31
  const int sg  = tid & 7;               // chunk along W: 0..7
  const int sp  = sg >> 2;               // plane (cols 0-31 / 32-63)
  const int sc0 = sg * 8;                // global col (u16 units)
  // swizzled in-plane col; note ((sr+32)>>1)&3 == (sr>>1)&3, so one value
  const int ssw = (((sg & 3) ^ ((sr >> 1) & 3)) << 3);
  // swizzled fragment-read col (u16): slot' = quad ^ ((l16>>1)&3)
  const int rq = ((quad ^ ((l16 >> 1) & 3)) << 3);

  // stage Q tile (swizzled)
  *(uint4*)(&QP[sp][sr     ][ssw]) = *(const uint4*)(q + ((size_t)bh * S + q0 + sr     ) * W + sc0);
  *(uint4*)(&QP[sp][sr + 32][ssw]) = *(const uint4*)(q + ((size_t)bh * S + q0 + sr + 32) * W + sc0);
  __syncthreads();
  bf16x8 aq[2];
#pragma unroll
  for (int kc = 0; kc < 2; kc++)
    aq[kc] = *(const bf16x8*)(&QP[kc][w16 + l16][rq]);

  // constant ones B-fragment: column 0 of a 16-wide tile = 1, rest 0
  bf16x8 ones;
  {
    u16 ov = (l16 == 0) ? (u16)0x3F80 : (u16)0;
#pragma unroll
    for (int j = 0; j < 8; j++) ones[j] = u2b(ov);
  }

  f32x4 o_acc[4] = {};
  f32x4 l_acc = {};

  // prefetch tile 0 of this half
  uint4 kr0, kr1, vr0, vr1;
  int mv = 0;
  kr0 = *(const uint4*)(k  + ((size_t)bh * S + kbase + sr     ) * W + sc0);
  kr1 = *(const uint4*)(k  + ((size_t)bh * S + kbase + sr + 32) * W + sc0);
  vr0 = *(const uint4*)(vt + ((size_t)bh * W + sr     ) * S + kbase + sc0);
  vr1 = *(const uint4*)(vt + ((size_t)bh * W + sr + 32) * S + kbase + sc0);
  if (tid < 64) mv = mask[b * S + kbase + tid];

  constexpr int NT = S / 128;   // 16 key tiles per half
  for (int kt = 0; kt < NT; kt++) {
    __syncthreads();   // prior-iteration LDS consumers done
    *(uint4*)(&Kl[sp][sr     ][ssw]) = kr0;
    *(uint4*)(&Kl[sp][sr + 32][ssw]) = kr1;
    *(uint4*)(&Vl[sp][sr     ][ssw]) = vr0;
    *(uint4*)(&Vl[sp][sr + 32][ssw]) = vr1;
    if (tid < 64) msk[tid] = -10000.0f * (1.0f - (float)mv);
    __syncthreads();

    // prefetch tile kt+1 (vmcnt consumed at next iteration's ds_write)
    if (kt + 1 < NT) {
      int kn = kbase + (kt + 1) * 64;
      kr0 = *(const uint4*)(k  + ((size_t)bh * S + kn + sr     ) * W + sc0);
      kr1 = *(const uint4*)(k  + ((size_t)bh * S + kn + sr + 32) * W + sc0);
      vr0 = *(const uint4*)(vt + ((size_t)bh * W + sr     ) * S + kn + sc0);
      vr1 = *(const uint4*)(vt + ((size_t)bh * W + sr + 32) * S + kn + sc0);
      if (tid < 64) mv = mask[b * S + kn + tid];
    }

    // QK^T
    f32x4 sc[4] = {};
#pragma unroll
    for (int tn = 0; tn < 4; tn++) {
#pragma unroll
      for (int kc = 0; kc < 2; kc++) {
        bf16x8 bk = *(const bf16x8*)(&Kl[kc][tn * 16 + l16][rq]);
        sc[tn] = __builtin_amdgcn_mfma_f32_16x16x32_bf16(aq[kc], bk, sc[tn], 0, 0, 0);
      }
    }
    // p = exp(s + mask) -> LDS (C->A layout), swizzled scalar stores.
#pragma unroll
    for (int tn = 0; tn < 4; tn++) {
      float mm = msk[tn * 16 + l16];
      int s0 = (tn & 1) * 2 + (l16 >> 3);
#pragma unroll
      for (int r = 0; r < 4; r++) {
        float pv = __expf(sc[tn][r] + mm);
        int xr = (quad * 2 + (r >> 1)) & 3;
        QP[tn >> 1][w16 + quad * 4 + r][((s0 ^ xr) << 3) | (l16 & 7)] = f2bf_cvt(pv);
      }
    }
    // no barrier: P slab is wave-private; same-wave DS ops are ordered

    // PV (+ ones column for the row sums)
#pragma unroll
    for (int kc = 0; kc < 2; kc++) {
      bf16x8 ap = *(const bf16x8*)(&QP[kc][w16 + l16][rq]);
#pragma unroll
      for (int tn = 0; tn < 4; tn++) {
        bf16x8 bv = *(const bf16x8*)(&Vl[kc][tn * 16 + l16][rq]);
        o_acc[tn] = __builtin_amdgcn_mfma_f32_16x16x32_bf16(ap, bv, o_acc[tn], 0, 0, 0);
      }
      l_acc = __builtin_amdgcn_mfma_f32_16x16x32_bf16(ap, ones, l_acc, 0, 0, 0);
    }
  }

  // epilogue: write un-normalized partial O (bf16) and partial l (f32).
  // l lives in column 0 (lanes with l16==0); broadcast per quad.
  u16* ob = o_parts + (size_t)half * M * D;
  float* lb = l_parts + (size_t)half * M * H;
#pragma unroll
  for (int r = 0; r < 4; r++) {
    float lsum = __shfl(l_acc[r], lane & 0x30);
    int sg2 = q0 + w16 + quad * 4 + r;
    if (l16 == 0) lb[((size_t)b * S + sg2) * H + h] = lsum;
#pragma unroll
    for (int tn = 0; tn < 4; tn++) {
      ob[((size_t)b * S + sg2) * D + h * W + tn * 16 + l16] = f2bf_cvt(o_acc[tn][r]);
    }
  }
}

// ---------------------------------------------------------------------------
// Combine key-split partials: attn = (o0 + o1) / (l0 + l1).
// attn aliases o_parts half 0 (elementwise in-place: each thread reads and
// writes the same 16B -> race-free). grid = M*D/2048 blocks of 256 threads.
// ---------------------------------------------------------------------------
__global__ __launch_bounds__(256) void combine_attn(
    const u16* __restrict__ o_parts, const float* __restrict__ l_parts,
    u16* __restrict__ attn)
{
  size_t idx = ((size_t)blockIdx.x * 256 + threadIdx.x) * 8;
  int row = (int)(idx >> 10);          // (b*S+s)
  int h = ((int)idx >> 6) & 15;        // head (8 elems stay in one head)
  float l = l_parts[(size_t)row * H + h] + l_parts[(size_t)M * H + (size_t)row * H + h];
  float inv = 1.0f / l;
  union { uint4 v; u16 e[8]; } a, bq, o;
  a.v  = *(const uint4*)(o_parts + idx);
  bq.v = *(const uint4*)(o_parts + (size_t)M * D + idx);
#pragma unroll
  for (int j = 0; j < 8; j++)
    o.e[j] = f2bf((bf2f(a.e[j]) + bf2f(bq.e[j])) * inv);
  *(uint4*)(attn + idx) = o.v;
}

// ---------------------------------------------------------------------------
// Fused residual + LayerNorm, one WAVE per row (no block barriers).
// grid = M/4 blocks of 256 threads.
// ---------------------------------------------------------------------------
template<typename TA, typename TR, typename TO>
__global__ __launch_bounds__(256) void ln_res_kernel(
    const TA* __restrict__ a, const TR* __restrict__ r,
    const float* __restrict__ g, const float* __restrict__ be,
    TO* __restrict__ out)
{
  const int tid = threadIdx.x, lane = tid & 63;
  const int row = blockIdx.x * 4 + (tid >> 6);
  const TA* ap = a + (size_t)row * D;
  const TR* rp = r + (size_t)row * D;
  float hv[16];
  float s = 0.f;
#pragma unroll
  for (int c = 0; c < 16; c++) {
    int d = c * 64 + lane;
    hv[c] = ldv(ap, d) + ldv(rp, d);
    s += hv[c];
  }
#pragma unroll
  for (int d = 1; d < 64; d <<= 1) s += __shfl_xor(s, d);
  float mean = s * (1.0f / D);
  float v = 0.f;
#pragma unroll
  for (int c = 0; c < 16; c++) { float t = hv[c] - mean; v += t * t; }
#pragma unroll
  for (int d = 1; d < 64; d <<= 1) v += __shfl_xor(v, d);
  float inv = rsqrtf(v * (1.0f / D) + 1e-12f);
#pragma unroll
  for (int c = 0; c < 16; c++) {
    int d = c * 64 + lane;
    stv(out, (size_t)row * D + d, g[d] * ((hv[c] - mean) * inv) + be[d]);
  }
}

// ---------------------------------------------------------------------------
extern "C" void kernel_launch(void* const* d_in, const int* in_sizes, int n_in,
                              void* d_out, int out_size, void* d_ws, size_t ws_size,
                              hipStream_t stream)
{
  const float* x  = (const float*)d_in[0];
  const int* mask = (const int*)d_in[1];
  const float* wq = (const float*)d_in[2];  const float* bq  = (const float*)d_in[3];
  const float* wk = (const float*)d_in[4];  const float* bk  = (const float*)d_in[5];
  const float* wv = (const float*)d_in[6];  const float* bv  = (const float*)d_in[7];
  const float* wo = (const float*)d_in[8];  const float* bo  = (const float*)d_in[9];
  const float* g1 = (const float*)d_in[10]; const float* b1  = (const float*)d_in[11];
  const float* w1 = (const float*)d_in[12]; const float* bf1 = (const float*)d_in[13];
  const float* w2 = (const float*)d_in[14]; const float* bf2 = (const float*)d_in[15];
  const float* g2 = (const float*)d_in[16]; const float* b2  = (const float*)d_in[17];

  // ws layout (peak 48 MB):
  //  A [0,8M):   wqkvT(6M)+woT(2M); wqkvT dead after QKV -> l_parts(512KB)
  //              lives at [0,0.5M) during fattn; then w1T(8M) -> w2T(8M)
  //  B [8,16M):  xb -> vt -> ff1[0:8M)
  //  C [16,24M): q  -> proj -> ff1[8:16M)
  //  D [24,32M): k  -> ff1[16:24M)
  //  E [32,48M): v(8M, dead after transpose_v) -> o_parts(16M); combine
  //              writes attn in-place over half 0 ([32,40M)) -> ff1[24:32M)
  //              only uses [8,40M), so o_parts half 1 ([40,48M)) is dead
  //              before h1 is written there.
  //  F [40,48M): bqkv(12KB, dead by fattn) -> o_parts half1 -> h1
  //  ff2 goes to d_out (fp32); LN2 runs in place on d_out.
  char* ws = (char*)d_ws;
  const size_t MB = 1024 * 1024;
  u16* wqkvT = (u16*)(ws + 0 * MB);          // (3072, 1024) bf16
  u16* woT   = (u16*)(ws + 6 * MB);          // (1024, 1024)
  u16* w1T   = (u16*)(ws + 0 * MB);          // (4096, 1024) after proj
  u16* w2T   = (u16*)(ws + 0 * MB);          // (1024, 4096) after ffn1
  u16* xb    = (u16*)(ws + 8 * MB);
  u16* vt    = (u16*)(ws + 8 * MB);
  u16* q     = (u16*)(ws + 16 * MB);
  u16* proj  = (u16*)(ws + 16 * MB);
  u16* kb    = (u16*)(ws + 24 * MB);
  u16* vb    = (u16*)(ws + 32 * MB);
  u16* oparts = (u16*)(ws + 32 * MB);        // 16 MB: 2 x (M,D) bf16 partials
  float* lparts = (float*)(ws + 0 * MB);     // 512 KB: 2 x (M,H) f32
  u16* attn  = (u16*)(ws + 32 * MB);         // combine output (aliases half0)
  u16* ff1   = (u16*)(ws + 8 * MB);          // 32 MB: [8,40)
  float* bqkv = (float*)(ws + 40 * MB);      // 12 KB
  u16* h1    = (u16*)(ws + 40 * MB);
  float* out = (float*)d_out;

  dim3 blk(256);

  // prep: x -> bf16; weights -> bf16 transposed; bias concat
  conv_x_kernel<<<dim3(M * D / 1024), blk, 0, stream>>>(x, xb);
  transpose_w_kernel<<<dim3(16, 16), blk, 0, stream>>>(wq, wqkvT,            D, D);
  transpose_w_kernel<<<dim3(16, 16), blk, 0, stream>>>(wk, wqkvT + 1024*1024, D, D);
  transpose_w_kernel<<<dim3(16, 16), blk, 0, stream>>>(wv, wqkvT + 2048*1024, D, D);
  transpose_w_kernel<<<dim3(16, 16), blk, 0, stream>>>(wo, woT,              D, D);
  hipMemcpyAsync(bqkv,        bq, D * sizeof(float), hipMemcpyDeviceToDevice, stream);
  hipMemcpyAsync(bqkv + 1024, bk, D * sizeof(float), hipMemcpyDeviceToDevice, stream);
  hipMemcpyAsync(bqkv + 2048, bv, D * sizeof(float), hipMemcpyDeviceToDevice, stream);

  // fused QKV GEMM: (M,1024) @ (1024,3072) -> q,k,v permuted (q scaled)
  gemm_bt<2, u16><<<dim3(3072 / 128, M / 128), blk, 0, stream>>>(
      xb, wqkvT, bqkv, q, 3072, D, 0.125f);

  transpose_v_kernel<<<dim3(S / 64, Bb * H), blk, 0, stream>>>(vb, vt);
  // key-split flash attention: 2048 blocks (6/CU resident), partials
  fattn_kernel<<<dim3(S / 64, Bb * H, 2), blk, 0, stream>>>(
      q, kb, vt, mask, oparts, lparts);
  combine_attn<<<dim3(M * D / 2048), blk, 0, stream>>>(oparts, lparts, attn);

  // proj: N=1024 -> 128x64 tiles (512 blocks, 2/CU)
  gemm_bt_n64<u16><<<dim3(D / 64, M / 128), blk, 0, stream>>>(
      attn, woT, bo, proj, D, D);
  ln_res_kernel<float, u16, u16><<<dim3(M / 4), blk, 0, stream>>>(x, proj, g1, b1, h1);

  transpose_w_kernel<<<dim3(F / 64, D / 64), blk, 0, stream>>>(w1, w1T, D, F);
  gemm_bt<1, u16><<<dim3(F / 128, M / 128), blk, 0, stream>>>(
      h1, w1T, bf1, ff1, F, D, 1.0f);

  transpose_w_kernel<<<dim3(D / 64, F / 64), blk, 0, stream>>>(w2, w2T, F, D);
  // FFN2: N=1024 -> 128x64 tiles, fp32 out; LN2 in place on d_out
  gemm_bt_n64<float><<<dim3(D / 64, M / 128), blk, 0, stream>>>(
      ff1, w2T, bf2, out, D, F);
  ln_res_kernel<u16, float, float><<<dim3(M / 4), blk, 0, stream>>>(h1, out, g2, b2, out);
}

// Round 3
// 416.383 us; speedup vs baseline: 1.0347x; 1.0224x over previous
//
#include <hip/hip_runtime.h>
#include <cstdint>
#include <cstddef>

using u16 = unsigned short;
using u32 = unsigned int;
using u64 = unsigned long long;

typedef __bf16 bf16x8 __attribute__((ext_vector_type(8)));
typedef float f32x4 __attribute__((ext_vector_type(4)));

static constexpr int Bb = 2, S = 2048, D = 1024, H = 16, W = 64, F = 4096;
static constexpr int M = Bb * S;   // 4096 rows

__device__ __forceinline__ float bf2f(u16 u) {
  union { u32 i; float f; } c; c.i = ((u32)u) << 16; return c.f;
}
__device__ __forceinline__ u16 f2bf(float f) {
  union { float f; u32 i; } c; c.f = f;
  u32 i = c.i;
  u32 r = (i + 0x7fffu + ((i >> 16) & 1u)) >> 16;
  return (u16)r;
}
__device__ __forceinline__ u16 f2bf_cvt(float f) {
  __bf16 b = (__bf16)f;
  union { __bf16 b; u16 u; } c; c.b = b; return c.u;
}
__device__ __forceinline__ __bf16 u2b(u16 x) {
  union { u16 u; __bf16 b; } c; c.u = x; return c.b;
}
__device__ __forceinline__ void stv(float* p, size_t i, float v) { p[i] = v; }
__device__ __forceinline__ void stv(u16* p, size_t i, float v)   { p[i] = f2bf(v); }
__device__ __forceinline__ float ldv(const float* p, size_t i) { return p[i]; }
__device__ __forceinline__ float ldv(const u16* p, size_t i)   { return bf2f(p[i]); }

__device__ __forceinline__ void async_cp16(const u16* g, u16* l) {
  __builtin_amdgcn_global_load_lds(
      (const __attribute__((address_space(1))) void*)g,
      (__attribute__((address_space(3))) void*)l, 16, 0, 0);
}

// 8x8 super-tile block swizzle for L2 locality. Requires gridDim.x%8==0,
// gridDim.y%8==0. 64 consecutive blocks -> 8 A-tiles + 8 B-tiles (~4MB).
__device__ __forceinline__ void swizzle8(int& bx, int& by) {
  int bid = blockIdx.y * gridDim.x + blockIdx.x;
  int gpr = gridDim.x >> 3;
  int grp = bid >> 6, rem = bid & 63;
  int gm = grp / gpr, gn = grp - gm * gpr;
  by = gm * 8 + (rem >> 3);
  bx = gn * 8 + (rem & 7);
}

// ---------------------------------------------------------------------------
// fp32 -> bf16 elementwise convert (n % 1024 == 0)
// ---------------------------------------------------------------------------
__global__ __launch_bounds__(256) void conv_x_kernel(
    const float* __restrict__ src, u16* __restrict__ dst)
{
  int i = (blockIdx.x * 256 + threadIdx.x) * 4;
  float4 v = *(const float4*)(src + i);
  u16 r[4] = { f2bf(v.x), f2bf(v.y), f2bf(v.z), f2bf(v.w) };
  *(uint2*)(dst + i) = *(const uint2*)r;
}

// ---------------------------------------------------------------------------
// Weight transpose+convert: src (K,N) fp32 -> dst (N,K) bf16. 64x64 tiles.
// ---------------------------------------------------------------------------
__global__ __launch_bounds__(256) void transpose_w_kernel(
    const float* __restrict__ src, u16* __restrict__ dst, int K, int N)
{
  __shared__ __align__(16) u16 T[64][72];
  const int tid = threadIdx.x;
  const int n0 = blockIdx.x * 64, k0 = blockIdx.y * 64;
#pragma unroll
  for (int t = 0; t < 4; t++) {
    int idx = tid + t * 256;           // 0..1023 float4s
    int r = idx >> 4, c4 = (idx & 15) * 4;
    float4 v = *(const float4*)(src + (size_t)(k0 + r) * N + n0 + c4);
    T[c4 + 0][r] = f2bf(v.x); T[c4 + 1][r] = f2bf(v.y);
    T[c4 + 2][r] = f2bf(v.z); T[c4 + 3][r] = f2bf(v.w);
  }
  __syncthreads();
#pragma unroll
  for (int t = 0; t < 2; t++) {
    int idx = tid + t * 256;           // 0..511 uint4s
    int r = idx >> 3, c8 = (idx & 7) * 8;
    *(uint4*)(dst + (size_t)(n0 + r) * K + k0 + c8) = *(const uint4*)(&T[r][c8]);
  }
}

// ---------------------------------------------------------------------------
// m97-style GEMM, BK=64, 8x8 L2 swizzle. C = A(Mr,K) @ BT(N,K)^T + bias.
// 128x128 tile, 4 waves (2x2), each wave 64x64 (4x4 MFMA), 32 MFMA/stage.
// EPI: 0 plain, 1 gelu(exact), 2 fused-qkv permute (N=3072, scale on q).
// ---------------------------------------------------------------------------
template<int EPI, typename TC>
__global__ __launch_bounds__(256) void gemm_bt(
    const u16* __restrict__ A, const u16* __restrict__ BT,
    const float* __restrict__ bias, TC* __restrict__ C,
    int N, int K, float scale)
{
  __shared__ __align__(16) u16 As[2][128 * 32];
  __shared__ __align__(16) u16 Bs[2][128 * 32];
  const int tid = threadIdx.x;
  const int wave = tid >> 6, lane = tid & 63;
  const int quad = lane >> 4, l16 = lane & 15;
  int bx, by; swizzle8(bx, by);
  const int m0 = by * 128, n0 = bx * 128;
  const int wm = (wave >> 1) * 64, wn = (wave & 1) * 64;
  const int srow = lane >> 2;          // 0..15 within slot
  const int skoff = (lane & 3) * 8;    // 0/8/16/24

  f32x4 acc[4][4] = {};

  for (int k0 = 0; k0 < K; k0 += 64) {
#pragma unroll
    for (int h = 0; h < 2; h++) {
#pragma unroll
      for (int t = 0; t < 2; t++) {
        int slot = wave * 2 + t;                   // 0..7 -> 16 rows each
        int row = slot * 16 + srow;
        const u16* ga = A  + (size_t)(m0 + row) * K + k0 + h * 32 + skoff;
        const u16* gb = BT + (size_t)(n0 + row) * K + k0 + h * 32 + skoff;
        async_cp16(ga, As[h] + slot * 512);        // lane i -> +16i bytes
        async_cp16(gb, Bs[h] + slot * 512);
      }
    }
    __syncthreads();

#pragma unroll
    for (int h = 0; h < 2; h++) {
      bf16x8 af[4], bfv[4];
#pragma unroll
      for (int i = 0; i < 4; i++)
        af[i] = *(const bf16x8*)(As[h] + (wm + i * 16 + l16) * 32 + quad * 8);
#pragma unroll
      for (int j = 0; j < 4; j++)
        bfv[j] = *(const bf16x8*)(Bs[h] + (wn + j * 16 + l16) * 32 + quad * 8);
#pragma unroll
      for (int i = 0; i < 4; i++)
#pragma unroll
        for (int j = 0; j < 4; j++)
          acc[i][j] = __builtin_amdgcn_mfma_f32_16x16x32_bf16(af[i], bfv[j], acc[i][j], 0, 0, 0);
    }
    __syncthreads();
  }

#pragma unroll
  for (int i = 0; i < 4; i++) {
#pragma unroll
    for (int j = 0; j < 4; j++) {
#pragma unroll
      for (int r = 0; r < 4; r++) {
        int row = m0 + wm + i * 16 + quad * 4 + r;
        int col = n0 + wn + j * 16 + l16;
        float val = acc[i][j][r] + bias[col];
        if (EPI == 1) {
          val = 0.5f * val * (1.0f + erff(val * 0.70710678118654752f));
        }
        if (EPI == 2) {
          int sel = col >> 10, c = col & 1023;       // D = 1024
          if (sel == 0) val *= scale;
          int bb = row >> 11, ss = row & 2047;       // S = 2048
          int hh = c >> 6,  ww = c & 63;             // W = 64
          u16* dst = (u16*)C + (size_t)sel * M * D;
          dst[(((size_t)(bb * H + hh) * S) + ss) * W + ww] = f2bf(val);
        } else {
          stv(C, (size_t)row * N + col, val);
        }
      }
    }
  }
}

// ---------------------------------------------------------------------------
// 128x64-tile GEMM (N=1024 matmuls), BK=64, 8x8 L2 swizzle.
// Waves 2x2; each wave 64(m) x 32(n) -> acc[4][2], 16 MFMA per stage.
// ---------------------------------------------------------------------------
template<typename TC>
__global__ __launch_bounds__(256) void gemm_bt_n64(
    const u16* __restrict__ A, const u16* __restrict__ BT,
    const float* __restrict__ bias, TC* __restrict__ C,
    int N, int K)
{
  __shared__ __align__(16) u16 As[2][128 * 32];
  __shared__ __align__(16) u16 Bs[2][64 * 32];
  const int tid = threadIdx.x;
  const int wave = tid >> 6, lane = tid & 63;
  const int quad = lane >> 4, l16 = lane & 15;
  int bx, by; swizzle8(bx, by);
  const int m0 = by * 128, n0 = bx * 64;
  const int wm = (wave >> 1) * 64, wn = (wave & 1) * 32;
  const int srow = lane >> 2;
  const int skoff = (lane & 3) * 8;

  f32x4 acc[4][2] = {};

  for (int k0 = 0; k0 < K; k0 += 64) {
#pragma unroll
    for (int h = 0; h < 2; h++) {
#pragma unroll
      for (int t = 0; t < 2; t++) {
        int slot = wave * 2 + t;
        int row = slot * 16 + srow;
        async_cp16(A + (size_t)(m0 + row) * K + k0 + h * 32 + skoff, As[h] + slot * 512);
      }
      int row = wave * 16 + srow;
      async_cp16(BT + (size_t)(n0 + row) * K + k0 + h * 32 + skoff, Bs[h] + wave * 512);
    }
    __syncthreads();

#pragma unroll
    for (int h = 0; h < 2; h++) {
      bf16x8 af[4], bfv[2];
#pragma unroll
      for (int i = 0; i < 4; i++)
        af[i] = *(const bf16x8*)(As[h] + (wm + i * 16 + l16) * 32 + quad * 8);
#pragma unroll
      for (int j = 0; j < 2; j++)
        bfv[j] = *(const bf16x8*)(Bs[h] + (wn + j * 16 + l16) * 32 + quad * 8);
#pragma unroll
      for (int i = 0; i < 4; i++)
#pragma unroll
        for (int j = 0; j < 2; j++)
          acc[i][j] = __builtin_amdgcn_mfma_f32_16x16x32_bf16(af[i], bfv[j], acc[i][j], 0, 0, 0);
    }
    __syncthreads();
  }

#pragma unroll
  for (int i = 0; i < 4; i++) {
#pragma unroll
    for (int j = 0; j < 2; j++) {
#pragma unroll
      for (int r = 0; r < 4; r++) {
        int row = m0 + wm + i * 16 + quad * 4 + r;
        int col = n0 + wn + j * 16 + l16;
        stv(C, (size_t)row * N + col, acc[i][j][r] + bias[col]);
      }
    }
  }
}

// ---------------------------------------------------------------------------
// V transpose: (BH, S, W) -> (BH, W, S), 64x64 tiles via LDS.
// ---------------------------------------------------------------------------
__global__ __launch_bounds__(256) void transpose_v_kernel(
    const u16* __restrict__ v, u16* __restrict__ vt)
{
  __shared__ __align__(16) u16 T[64][72];
  const int bh = blockIdx.y, k0 = blockIdx.x * 64, tid = threadIdx.x;
#pragma unroll
  for (int it = 0; it < 2; it++) {
    int vv = tid + it * 256;
    int key = vv >> 3, w0 = (vv & 7) * 8;
    union { uint4 q; u16 e[8]; } u;
    u.q = *(const uint4*)(v + ((size_t)bh * S + k0 + key) * W + w0);
#pragma unroll
    for (int j = 0; j < 8; j++) T[w0 + j][key] = u.e[j];
  }
  __syncthreads();
#pragma unroll
  for (int it = 0; it < 2; it++) {
    int vv = tid + it * 256;
    int w = vv >> 3, koff = (vv & 7) * 8;
    *(uint4*)(vt + ((size_t)bh * W + w) * S + k0 + koff) = *(const uint4*)(&T[w][koff]);
  }
}

// ---------------------------------------------------------------------------
// Flash attention (MFMA). LDS-issue-bound diagnosis (r2): DS instruction
// count is the kernel's floor, so this version amortizes it:
//  - QBLK=128: 4 waves x 32 q-rows (2 groups of 16); every K/V fragment
//    ds_read_b128 feeds 2 MFMAs -> K/V LDS reads per q-row halved.
//  - swapped QK^T (mfma(K,Q)): C rows = keys, cols = q, so a lane holds 4
//    CONSECUTIVE keys per quad -> P-store is ONE ds_write_b64 per (g,tn)
//    instead of 4 scalar b16 stores (and the b64 pattern is bank-balanced).
//  - mask via __ballot bit-test in registers: p = exp(s)*m (identical:
//    exp(s-10000) underflows to exactly 0). No msk[] LDS traffic.
// KEY-SPLIT 2-way kept: grid (S/128, BH, 2) = 1024 blocks, un-normalized
// partial O (bf16) + partial l (f32); combine_attn merges.
// LDS tiles [2][rows][32] plane layout, 16B-slot XOR-swizzled
// (slot' = slot ^ ((row>>1)&3)) on both write and read sides.
// No max-tracking: scores bounded; l via ones-column MFMA.
// ---------------------------------------------------------------------------
__global__ __launch_bounds__(256) void fattn_kernel(
    const u16* __restrict__ q, const u16* __restrict__ k,
    const u16* __restrict__ vt, const int* __restrict__ mask,
    u16* __restrict__ o_parts, float* __restrict__ l_parts)
{
  __shared__ __align__(16) u16 QP[2][128][32];  // Q staging, then P tiles
  __shared__ __align__(16) u16 Kl[2][64][32];   // K tile [key][w]
  __shared__ __align__(16) u16 Vl[2][64][32];   // V^T tile [w][key]

  const int tid = threadIdx.x, wave = tid >> 6, lane = tid & 63;
  const int quad = lane >> 4, l16 = lane & 15;
  const int bh = blockIdx.y, b = bh >> 4, h = bh & 15;
  const int q0 = blockIdx.x * 128;
  const int half = blockIdx.z;
  const int kbase = half * (S / 2);             // first key of this half
  const int wq0 = wave * 32;                    // wave's 32 q-rows
  // staging coords: rows sr (+32/+64/+96), global 16B chunk sg = tid&7
  const int sr  = tid >> 3;              // 0..31
  const int sg  = tid & 7;               // chunk along W: 0..7
  const int sp  = sg >> 2;               // plane (cols 0-31 / 32-63)
  const int sc0 = sg * 8;                // global col (u16 units)
  // swizzled in-plane col; rows differ by multiples of 32 -> same value
  const int ssw = (((sg & 3) ^ ((sr >> 1) & 3)) << 3);
  // fragment-read swizzle: row = 16*t + l16 -> (row>>1)&3 == (l16>>1)&3
  const int xr = (l16 >> 1) & 3;
  const int rq = ((quad ^ xr) << 3);

  // stage Q tile 128x64 (swizzled)
#pragma unroll
  for (int t = 0; t < 4; t++) {
    int row = sr + t * 32;
    *(uint4*)(&QP[sp][row][ssw]) =
        *(const uint4*)(q + ((size_t)bh * S + q0 + row) * W + sc0);
  }
  __syncthreads();
  // Q fragments held in registers for the whole kernel (B-operand of QK^T)
  bf16x8 aq[2][2];
#pragma unroll
  for (int g = 0; g < 2; g++)
#pragma unroll
    for (int kc = 0; kc < 2; kc++)
      aq[g][kc] = *(const bf16x8*)(&QP[kc][wq0 + g * 16 + l16][rq]);
  // (P writes below hit only this wave's rows, which only this wave read:
  //  intra-wave DS ordering suffices, no barrier needed.)

  // constant ones B-fragment: column 0 of a 16-wide tile = 1, rest 0
  bf16x8 ones;
  {
    u16 ov = (l16 == 0) ? (u16)0x3F80 : (u16)0;
#pragma unroll
    for (int j = 0; j < 8; j++) ones[j] = u2b(ov);
  }

  f32x4 o_acc[2][4] = {};
  f32x4 l_acc[2] = {};

  // prefetch tile 0 of this half (register double-buffering of K/V/mask)
  uint4 kr0, kr1, vr0, vr1;
  int mv;
  kr0 = *(const uint4*)(k  + ((size_t)bh * S + kbase + sr     ) * W + sc0);
  kr1 = *(const uint4*)(k  + ((size_t)bh * S + kbase + sr + 32) * W + sc0);
  vr0 = *(const uint4*)(vt + ((size_t)bh * W + sr     ) * S + kbase + sc0);
  vr1 = *(const uint4*)(vt + ((size_t)bh * W + sr + 32) * S + kbase + sc0);
  mv  = mask[b * S + kbase + lane];             // every wave: 64 key bits

  constexpr int NT = S / 128;   // 16 key tiles per half
  for (int kt = 0; kt < NT; kt++) {
    __syncthreads();   // prior-iteration LDS consumers done
    *(uint4*)(&Kl[sp][sr     ][ssw]) = kr0;
    *(uint4*)(&Kl[sp][sr + 32][ssw]) = kr1;
    *(uint4*)(&Vl[sp][sr     ][ssw]) = vr0;
    *(uint4*)(&Vl[sp][sr + 32][ssw]) = vr1;
    u64 km = __ballot(mv != 0);    // bit j = mask of key j of this tile
    __syncthreads();

    // prefetch tile kt+1
    if (kt + 1 < NT) {
      int kn = kbase + (kt + 1) * 64;
      kr0 = *(const uint4*)(k  + ((size_t)bh * S + kn + sr     ) * W + sc0);
      kr1 = *(const uint4*)(k  + ((size_t)bh * S + kn + sr + 32) * W + sc0);
      vr0 = *(const uint4*)(vt + ((size_t)bh * W + sr     ) * S + kn + sc0);
      vr1 = *(const uint4*)(vt + ((size_t)bh * W + sr + 32) * S + kn + sc0);
      mv  = mask[b * S + kn + lane];
    }

    // swapped QK^T: per key-tile tn, read K-frags once, use for both groups.
    // C rows = keys tn*16 + quad*4 + r, cols = q = l16 (group g).
#pragma unroll
    for (int tn = 0; tn < 4; tn++) {
      bf16x8 bk0 = *(const bf16x8*)(&Kl[0][tn * 16 + l16][rq]);
      bf16x8 bk1 = *(const bf16x8*)(&Kl[1][tn * 16 + l16][rq]);
      u32 nib = (u32)(km >> (tn * 16 + quad * 4)) & 0xFu;
      int slotp = (((tn & 1) * 2 + (quad >> 1)) ^ xr) * 8 + (quad & 1) * 4;
#pragma unroll
      for (int g = 0; g < 2; g++) {
        f32x4 s4 = {};
        s4 = __builtin_amdgcn_mfma_f32_16x16x32_bf16(bk0, aq[g][0], s4, 0, 0, 0);
        s4 = __builtin_amdgcn_mfma_f32_16x16x32_bf16(bk1, aq[g][1], s4, 0, 0, 0);
        // p = exp(s) * mask-bit; 4 consecutive keys -> one b64 store
        union { u64 u; u16 e[4]; } pw;
#pragma unroll
        for (int r = 0; r < 4; r++) {
          float pm = (float)((nib >> r) & 1u);
          pw.e[r] = f2bf_cvt(__expf(s4[r]) * pm);
        }
        *(u64*)(&QP[tn >> 1][wq0 + g * 16 + l16][slotp]) = pw.u;
      }
    }
    // no barrier: P slab is wave-private; same-wave DS ops are ordered

    // PV (+ ones column for the row sums): V-frags read once, used twice
#pragma unroll
    for (int kc = 0; kc < 2; kc++) {
      bf16x8 ap0 = *(const bf16x8*)(&QP[kc][wq0      + l16][rq]);
      bf16x8 ap1 = *(const bf16x8*)(&QP[kc][wq0 + 16 + l16][rq]);
#pragma unroll
      for (int tn = 0; tn < 4; tn++) {
        bf16x8 bv = *(const bf16x8*)(&Vl[kc][tn * 16 + l16][rq]);
        o_acc[0][tn] = __builtin_amdgcn_mfma_f32_16x16x32_bf16(ap0, bv, o_acc[0][tn], 0, 0, 0);
        o_acc[1][tn] = __builtin_amdgcn_mfma_f32_16x16x32_bf16(ap1, bv, o_acc[1][tn], 0, 0, 0);
      }
      l_acc[0] = __builtin_amdgcn_mfma_f32_16x16x32_bf16(ap0, ones, l_acc[0], 0, 0, 0);
      l_acc[1] = __builtin_amdgcn_mfma_f32_16x16x32_bf16(ap1, ones, l_acc[1], 0, 0, 0);
    }
  }

  // epilogue: write un-normalized partial O (bf16) and partial l (f32).
  // l lives in column 0 (lanes with l16==0); broadcast per quad.
  u16* ob = o_parts + (size_t)half * M * D;
  float* lb = l_parts + (size_t)half * M * H;
#pragma unroll
  for (int g = 0; g < 2; g++) {
#pragma unroll
    for (int r = 0; r < 4; r++) {
      float lsum = __shfl(l_acc[g][r], lane & 0x30);
      int sg2 = q0 + wq0 + g * 16 + quad * 4 + r;
      if (l16 == 0) lb[((size_t)b * S + sg2) * H + h] = lsum;
#pragma unroll
      for (int tn = 0; tn < 4; tn++) {
        ob[((size_t)b * S + sg2) * D + h * W + tn * 16 + l16] = f2bf_cvt(o_acc[g][tn][r]);
      }
    }
  }
}

// ---------------------------------------------------------------------------
// Combine key-split partials: attn = (o0 + o1) / (l0 + l1).
// attn aliases o_parts half 0 (elementwise in-place: each thread reads and
// writes the same 16B -> race-free). grid = M*D/2048 blocks of 256 threads.
// ---------------------------------------------------------------------------
__global__ __launch_bounds__(256) void combine_attn(
    const u16* __restrict__ o_parts, const float* __restrict__ l_parts,
    u16* __restrict__ attn)
{
  size_t idx = ((size_t)blockIdx.x * 256 + threadIdx.x) * 8;
  int row = (int)(idx >> 10);          // (b*S+s)
  int h = ((int)idx >> 6) & 15;        // head (8 elems stay in one head)
  float l = l_parts[(size_t)row * H + h] + l_parts[(size_t)M * H + (size_t)row * H + h];
  float inv = 1.0f / l;
  union { uint4 v; u16 e[8]; } a, bq, o;
  a.v  = *(const uint4*)(o_parts + idx);
  bq.v = *(const uint4*)(o_parts + (size_t)M * D + idx);
#pragma unroll
  for (int j = 0; j < 8; j++)
    o.e[j] = f2bf((bf2f(a.e[j]) + bf2f(bq.e[j])) * inv);
  *(uint4*)(attn + idx) = o.v;
}

// ---------------------------------------------------------------------------
// Fused residual + LayerNorm, one WAVE per row (no block barriers).
// grid = M/4 blocks of 256 threads.
// ---------------------------------------------------------------------------
template<typename TA, typename TR, typename TO>
__global__ __launch_bounds__(256) void ln_res_kernel(
    const TA* __restrict__ a, const TR* __restrict__ r,
    const float* __restrict__ g, const float* __restrict__ be,
    TO* __restrict__ out)
{
  const int tid = threadIdx.x, lane = tid & 63;
  const int row = blockIdx.x * 4 + (tid >> 6);
  const TA* ap = a + (size_t)row * D;
  const TR* rp = r + (size_t)row * D;
  float hv[16];
  float s = 0.f;
#pragma unroll
  for (int c = 0; c < 16; c++) {
    int d = c * 64 + lane;
    hv[c] = ldv(ap, d) + ldv(rp, d);
    s += hv[c];
  }
#pragma unroll
  for (int d = 1; d < 64; d <<= 1) s += __shfl_xor(s, d);
  float mean = s * (1.0f / D);
  float v = 0.f;
#pragma unroll
  for (int c = 0; c < 16; c++) { float t = hv[c] - mean; v += t * t; }
#pragma unroll
  for (int d = 1; d < 64; d <<= 1) v += __shfl_xor(v, d);
  float inv = rsqrtf(v * (1.0f / D) + 1e-12f);
#pragma unroll
  for (int c = 0; c < 16; c++) {
    int d = c * 64 + lane;
    stv(out, (size_t)row * D + d, g[d] * ((hv[c] - mean) * inv) + be[d]);
  }
}

// ---------------------------------------------------------------------------
extern "C" void kernel_launch(void* const* d_in, const int* in_sizes, int n_in,
                              void* d_out, int out_size, void* d_ws, size_t ws_size,
                              hipStream_t stream)
{
  const float* x  = (const float*)d_in[0];
  const int* mask = (const int*)d_in[1];
  const float* wq = (const float*)d_in[2];  const float* bq  = (const float*)d_in[3];
  const float* wk = (const float*)d_in[4];  const float* bk  = (const float*)d_in[5];
  const float* wv = (const float*)d_in[6];  const float* bv  = (const float*)d_in[7];
  const float* wo = (const float*)d_in[8];  const float* bo  = (const float*)d_in[9];
  const float* g1 = (const float*)d_in[10]; const float* b1  = (const float*)d_in[11];
  const float* w1 = (const float*)d_in[12]; const float* bf1 = (const float*)d_in[13];
  const float* w2 = (const float*)d_in[14]; const float* bf2 = (const float*)d_in[15];
  const float* g2 = (const float*)d_in[16]; const float* b2  = (const float*)d_in[17];

  // ws layout (peak 48 MB):
  //  A [0,8M):   wqkvT(6M)+woT(2M); wqkvT dead after QKV -> l_parts(512KB)
  //              lives at [0,0.5M) during fattn; then w1T(8M) -> w2T(8M)
  //  B [8,16M):  xb -> vt -> ff1[0:8M)
  //  C [16,24M): q  -> proj -> ff1[8:16M)
  //  D [24,32M): k  -> ff1[16:24M)
  //  E [32,48M): v(8M, dead after transpose_v) -> o_parts(16M); combine
  //              writes attn in-place over half 0 ([32,40M)) -> ff1[24:32M)
  //  F [40,48M): bqkv(12KB, dead by fattn) -> o_parts half1 -> h1
  //  ff2 goes to d_out (fp32); LN2 runs in place on d_out.
  char* ws = (char*)d_ws;
  const size_t MB = 1024 * 1024;
  u16* wqkvT = (u16*)(ws + 0 * MB);          // (3072, 1024) bf16
  u16* woT   = (u16*)(ws + 6 * MB);          // (1024, 1024)
  u16* w1T   = (u16*)(ws + 0 * MB);          // (4096, 1024) after proj
  u16* w2T   = (u16*)(ws + 0 * MB);          // (1024, 4096) after ffn1
  u16* xb    = (u16*)(ws + 8 * MB);
  u16* vt    = (u16*)(ws + 8 * MB);
  u16* q     = (u16*)(ws + 16 * MB);
  u16* proj  = (u16*)(ws + 16 * MB);
  u16* kb    = (u16*)(ws + 24 * MB);
  u16* vb    = (u16*)(ws + 32 * MB);
  u16* oparts = (u16*)(ws + 32 * MB);        // 16 MB: 2 x (M,D) bf16 partials
  float* lparts = (float*)(ws + 0 * MB);     // 512 KB: 2 x (M,H) f32
  u16* attn  = (u16*)(ws + 32 * MB);         // combine output (aliases half0)
  u16* ff1   = (u16*)(ws + 8 * MB);          // 32 MB: [8,40)
  float* bqkv = (float*)(ws + 40 * MB);      // 12 KB
  u16* h1    = (u16*)(ws + 40 * MB);
  float* out = (float*)d_out;

  dim3 blk(256);

  // prep: x -> bf16; weights -> bf16 transposed; bias concat
  conv_x_kernel<<<dim3(M * D / 1024), blk, 0, stream>>>(x, xb);
  transpose_w_kernel<<<dim3(16, 16), blk, 0, stream>>>(wq, wqkvT,            D, D);
  transpose_w_kernel<<<dim3(16, 16), blk, 0, stream>>>(wk, wqkvT + 1024*1024, D, D);
  transpose_w_kernel<<<dim3(16, 16), blk, 0, stream>>>(wv, wqkvT + 2048*1024, D, D);
  transpose_w_kernel<<<dim3(16, 16), blk, 0, stream>>>(wo, woT,              D, D);
  hipMemcpyAsync(bqkv,        bq, D * sizeof(float), hipMemcpyDeviceToDevice, stream);
  hipMemcpyAsync(bqkv + 1024, bk, D * sizeof(float), hipMemcpyDeviceToDevice, stream);
  hipMemcpyAsync(bqkv + 2048, bv, D * sizeof(float), hipMemcpyDeviceToDevice, stream);

  // fused QKV GEMM: (M,1024) @ (1024,3072) -> q,k,v permuted (q scaled)
  gemm_bt<2, u16><<<dim3(3072 / 128, M / 128), blk, 0, stream>>>(
      xb, wqkvT, bqkv, q, 3072, D, 0.125f);

  transpose_v_kernel<<<dim3(S / 64, Bb * H), blk, 0, stream>>>(vb, vt);
  // key-split flash attention: QBLK=128, 1024 blocks, partials
  fattn_kernel<<<dim3(S / 128, Bb * H, 2), blk, 0, stream>>>(
      q, kb, vt, mask, oparts, lparts);
  combine_attn<<<dim3(M * D / 2048), blk, 0, stream>>>(oparts, lparts, attn);

  // proj: N=1024 -> 128x64 tiles (512 blocks, 2/CU)
  gemm_bt_n64<u16><<<dim3(D / 64, M / 128), blk, 0, stream>>>(
      attn, woT, bo, proj, D, D);
  ln_res_kernel<float, u16, u16><<<dim3(M / 4), blk, 0, stream>>>(x, proj, g1, b1, h1);

  transpose_w_kernel<<<dim3(F / 64, D / 64), blk, 0, stream>>>(w1, w1T, D, F);
  gemm_bt<1, u16><<<dim3(F / 128, M / 128), blk, 0, stream>>>(
      h1, w1T, bf1, ff1, F, D, 1.0f);

  transpose_w_kernel<<<dim3(D / 64, F / 64), blk, 0, stream>>>(w2, w2T, F, D);
  // FFN2: N=1024 -> 128x64 tiles, fp32 out; LN2 in place on d_out
  gemm_bt_n64<float><<<dim3(D / 64, M / 128), blk, 0, stream>>>(
      ff1, w2T, bf2, out, D, F);
  ln_res_kernel<u16, float, float><<<dim3(M / 4), blk, 0, stream>>>(h1, out, g2, b2, out);
}

// Round 4
// 401.881 us; speedup vs baseline: 1.0721x; 1.0361x over previous
//
#include <hip/hip_runtime.h>
#include <cstdint>
#include <cstddef>

using u16 = unsigned short;
using u32 = unsigned int;
using u64 = unsigned long long;

typedef __bf16 bf16x8 __attribute__((ext_vector_type(8)));
typedef float f32x4 __attribute__((ext_vector_type(4)));

static constexpr int Bb = 2, S = 2048, D = 1024, H = 16, W = 64, F = 4096;
static constexpr int M = Bb * S;   // 4096 rows

__device__ __forceinline__ float bf2f(u16 u) {
  union { u32 i; float f; } c; c.i = ((u32)u) << 16; return c.f;
}
__device__ __forceinline__ u16 f2bf(float f) {
  union { float f; u32 i; } c; c.f = f;
  u32 i = c.i;
  u32 r = (i + 0x7fffu + ((i >> 16) & 1u)) >> 16;
  return (u16)r;
}
__device__ __forceinline__ u16 f2bf_cvt(float f) {
  __bf16 b = (__bf16)f;
  union { __bf16 b; u16 u; } c; c.b = b; return c.u;
}
__device__ __forceinline__ __bf16 u2b(u16 x) {
  union { u16 u; __bf16 b; } c; c.u = x; return c.b;
}
__device__ __forceinline__ void stv(float* p, size_t i, float v) { p[i] = v; }
__device__ __forceinline__ void stv(u16* p, size_t i, float v)   { p[i] = f2bf(v); }
__device__ __forceinline__ float ldv(const float* p, size_t i) { return p[i]; }
__device__ __forceinline__ float ldv(const u16* p, size_t i)   { return bf2f(p[i]); }

__device__ __forceinline__ void async_cp16(const u16* g, u16* l) {
  __builtin_amdgcn_global_load_lds(
      (const __attribute__((address_space(1))) void*)g,
      (__attribute__((address_space(3))) void*)l, 16, 0, 0);
}

// 8x8 super-tile block swizzle for L2 locality. Requires gridDim.x%8==0,
// gridDim.y%8==0. 64 consecutive blocks -> 8 A-tiles + 8 B-tiles (~4MB).
__device__ __forceinline__ void swizzle8(int& bx, int& by) {
  int bid = blockIdx.y * gridDim.x + blockIdx.x;
  int gpr = gridDim.x >> 3;
  int grp = bid >> 6, rem = bid & 63;
  int gm = grp / gpr, gn = grp - gm * gpr;
  by = gm * 8 + (rem >> 3);
  bx = gn * 8 + (rem & 7);
}

// ---------------------------------------------------------------------------
// fp32 -> bf16 elementwise convert (n % 1024 == 0)
// ---------------------------------------------------------------------------
__global__ __launch_bounds__(256) void conv_x_kernel(
    const float* __restrict__ src, u16* __restrict__ dst)
{
  int i = (blockIdx.x * 256 + threadIdx.x) * 4;
  float4 v = *(const float4*)(src + i);
  u16 r[4] = { f2bf(v.x), f2bf(v.y), f2bf(v.z), f2bf(v.w) };
  *(uint2*)(dst + i) = *(const uint2*)r;
}

// ---------------------------------------------------------------------------
// Weight transpose+convert: src (K,N) fp32 -> dst (N,K) bf16. 64x64 tiles.
// ---------------------------------------------------------------------------
__global__ __launch_bounds__(256) void transpose_w_kernel(
    const float* __restrict__ src, u16* __restrict__ dst, int K, int N)
{
  __shared__ __align__(16) u16 T[64][72];
  const int tid = threadIdx.x;
  const int n0 = blockIdx.x * 64, k0 = blockIdx.y * 64;
#pragma unroll
  for (int t = 0; t < 4; t++) {
    int idx = tid + t * 256;           // 0..1023 float4s
    int r = idx >> 4, c4 = (idx & 15) * 4;
    float4 v = *(const float4*)(src + (size_t)(k0 + r) * N + n0 + c4);
    T[c4 + 0][r] = f2bf(v.x); T[c4 + 1][r] = f2bf(v.y);
    T[c4 + 2][r] = f2bf(v.z); T[c4 + 3][r] = f2bf(v.w);
  }
  __syncthreads();
#pragma unroll
  for (int t = 0; t < 2; t++) {
    int idx = tid + t * 256;           // 0..511 uint4s
    int r = idx >> 3, c8 = (idx & 7) * 8;
    *(uint4*)(dst + (size_t)(n0 + r) * K + k0 + c8) = *(const uint4*)(&T[r][c8]);
  }
}

// ---------------------------------------------------------------------------
// m97-style GEMM, BK=64, 8x8 L2 swizzle. C = A(Mr,K) @ BT(N,K)^T + bias.
// 128x128 tile, 4 waves (2x2), each wave 64x64 (4x4 MFMA), 32 MFMA/stage.
// EPI: 0 plain, 2 fused-qkv permute (N=3072, scale on q).
// ---------------------------------------------------------------------------
template<int EPI, typename TC>
__global__ __launch_bounds__(256) void gemm_bt(
    const u16* __restrict__ A, const u16* __restrict__ BT,
    const float* __restrict__ bias, TC* __restrict__ C,
    int N, int K, float scale)
{
  __shared__ __align__(16) u16 As[2][128 * 32];
  __shared__ __align__(16) u16 Bs[2][128 * 32];
  const int tid = threadIdx.x;
  const int wave = tid >> 6, lane = tid & 63;
  const int quad = lane >> 4, l16 = lane & 15;
  int bx, by; swizzle8(bx, by);
  const int m0 = by * 128, n0 = bx * 128;
  const int wm = (wave >> 1) * 64, wn = (wave & 1) * 64;
  const int srow = lane >> 2;          // 0..15 within slot
  const int skoff = (lane & 3) * 8;    // 0/8/16/24

  f32x4 acc[4][4] = {};

  for (int k0 = 0; k0 < K; k0 += 64) {
#pragma unroll
    for (int h = 0; h < 2; h++) {
#pragma unroll
      for (int t = 0; t < 2; t++) {
        int slot = wave * 2 + t;                   // 0..7 -> 16 rows each
        int row = slot * 16 + srow;
        const u16* ga = A  + (size_t)(m0 + row) * K + k0 + h * 32 + skoff;
        const u16* gb = BT + (size_t)(n0 + row) * K + k0 + h * 32 + skoff;
        async_cp16(ga, As[h] + slot * 512);        // lane i -> +16i bytes
        async_cp16(gb, Bs[h] + slot * 512);
      }
    }
    __syncthreads();

#pragma unroll
    for (int h = 0; h < 2; h++) {
      bf16x8 af[4], bfv[4];
#pragma unroll
      for (int i = 0; i < 4; i++)
        af[i] = *(const bf16x8*)(As[h] + (wm + i * 16 + l16) * 32 + quad * 8);
#pragma unroll
      for (int j = 0; j < 4; j++)
        bfv[j] = *(const bf16x8*)(Bs[h] + (wn + j * 16 + l16) * 32 + quad * 8);
#pragma unroll
      for (int i = 0; i < 4; i++)
#pragma unroll
        for (int j = 0; j < 4; j++)
          acc[i][j] = __builtin_amdgcn_mfma_f32_16x16x32_bf16(af[i], bfv[j], acc[i][j], 0, 0, 0);
    }
    __syncthreads();
  }

#pragma unroll
  for (int i = 0; i < 4; i++) {
#pragma unroll
    for (int j = 0; j < 4; j++) {
#pragma unroll
      for (int r = 0; r < 4; r++) {
        int row = m0 + wm + i * 16 + quad * 4 + r;
        int col = n0 + wn + j * 16 + l16;
        float val = acc[i][j][r] + bias[col];
        if (EPI == 2) {
          int sel = col >> 10, c = col & 1023;       // D = 1024
          if (sel == 0) val *= scale;
          int bb = row >> 11, ss = row & 2047;       // S = 2048
          int hh = c >> 6,  ww = c & 63;             // W = 64
          u16* dst = (u16*)C + (size_t)sel * M * D;
          dst[(((size_t)(bb * H + hh) * S) + ss) * W + ww] = f2bf(val);
        } else {
          stv(C, (size_t)row * N + col, val);
        }
      }
    }
  }
}

// ---------------------------------------------------------------------------
// 256x256-tile 8-phase GEMM (HK-style schedule, plain HIP) for FFN1:
// C = gelu(A(M,K) @ BT(N,K)^T + bias), bf16 out. K=1024 (NT=16 K-tiles).
// 512 threads = 8 waves (2m x 4n); per-wave 128x64 out = 8x4 16x16 frags.
// LDS 128 KB: A,B each [2 dbuf][2 half][128 rows][64 k] bf16.
// T2 swizzle (rule #21, both-sides): 16B slot' = slot ^ (row&7), realized by
// pre-swizzling the GLOBAL source (linear global_load_lds dest) and XORing
// the ds_read byte col; read lanes (16 rows @ fixed slot) spread over all 8
// slots -> 2-way max (free, m136).
// Schedule per K-tile t (buf = t&1), 4 phases, each:
//   {ds-reads; stage-issue; s_barrier; setprio(1); 16 MFMA; setprio(0);
//    [s_waitcnt vmcnt(4) @p3]; s_barrier}
//  p0: Q(mh0,nh0) read A[mh0](8 b128) B[nh0](4); stage A(t+1)->buf^1 (4 iss)
//  p1: Q(mh0,nh1) read B[nh1](4)
//  p2: Q(mh1,nh1) read A[mh1](8);               stage Bh0(t+2)->buf (2 iss)
//  p3: Q(mh1,nh0) no reads (af, bf0 in regs);   stage Bh1(t+2)->buf (2 iss)
// Ledger: A(T) staged T-1 p0; B(T) staged T-2 p2/p3. Boundary vmcnt(4)
// leaves only B(t+2)'s 4 issues in flight -> A(t+1),B(t+1) landed before
// tile t+1 p0 reads. Region-free: Bh* dead after p1, Ah* after p2; every
// stage targets a region retired >=1 barrier earlier. Prologue stages
// A(0),B(0),B(1) (12 issues) then vmcnt(4) (tile 0's 8 landed).
// Ring-clamp (t+1)&15 / (t+2)&15 keeps the count ledger uniform at the tail.
// ---------------------------------------------------------------------------
__global__ __launch_bounds__(512, 2) void gemm256_gelu(
    const u16* __restrict__ A, const u16* __restrict__ BT,
    const float* __restrict__ bias, u16* __restrict__ C)
{
  constexpr int GN = F, GK = D, NT = GK / 64;
  __shared__ __align__(16) u16 AL[2][2][128 * 64];
  __shared__ __align__(16) u16 BL[2][2][128 * 64];
  const int tid = threadIdx.x;
  const int wave = tid >> 6, lane = tid & 63;
  const int quad = lane >> 4, l16 = lane & 15;
  const int wm = wave >> 2, wn = wave & 3;
  int bx, by; swizzle8(bx, by);
  const int m0 = by * 256, n0 = bx * 256;
  // staging per-lane constants: dest row sub = lane>>3, slot = lane&7;
  // global k-chunk = slot ^ (row&7)  (inverse swizzle at the source)
  const int lr = lane >> 3;
  const int kc8 = ((lane & 7) ^ lr) * 8;          // u16 units
  // fragment-read constants: byte XOR for slot swizzle (row&7 == l16&7)
  const int xb = (l16 & 7) * 16;
  const int brow0 = (wn & 1) * 64;                // B row base within half
  const char* abase = (const char*)&AL[0][wm][0];
  const char* bbase = (const char*)&BL[0][wn >> 1][0];
  constexpr int BUFB = 2 * 128 * 64 * 2;          // byte stride AL[1]-AL[0]

  f32x4 acc[8][4] = {};

  auto stA = [&](int t, int buf) {                // A(t) both halves, 4 issues
#pragma unroll
    for (int half = 0; half < 2; half++)
#pragma unroll
      for (int j = 0; j < 2; j++) {
        const u16* g = A + (size_t)(m0 + half * 128 + (j * 8 + wave) * 8 + lr) * GK
                         + t * 64 + kc8;
        async_cp16(g, &AL[buf][half][(j * 8 + wave) * 512]);
      }
  };
  auto stB = [&](int t, int buf, int half) {      // B(t) one half, 2 issues
#pragma unroll
    for (int j = 0; j < 2; j++) {
      const u16* g = BT + (size_t)(n0 + half * 128 + (j * 8 + wave) * 8 + lr) * GK
                        + t * 64 + kc8;
      async_cp16(g, &BL[buf][half][(j * 8 + wave) * 512]);
    }
  };

  // prologue: A(0)->buf0, B(0)->buf0, B(1)->buf1 (12 issues), tile 0 landed
  stA(0, 0);
  stB(0, 0, 0); stB(0, 0, 1);
  stB(1, 1, 0); stB(1, 1, 1);
  asm volatile("s_waitcnt vmcnt(4)" ::: "memory");
  __builtin_amdgcn_s_barrier();

  bf16x8 af[4][2], bf0[2][2], bf1v[2][2];

#pragma unroll 2
  for (int t = 0; t < NT; t++) {
    const int buf = t & 1;
    const char* ab = abase + buf * BUFB;
    const char* bb = bbase + buf * BUFB;

    // ---- phase 0: Q(0,0) ----
#pragma unroll
    for (int i = 0; i < 4; i++)
#pragma unroll
      for (int s = 0; s < 2; s++)
        af[i][s] = *(const bf16x8*)(ab + (i * 16 + l16) * 128 + (((s * 4 + quad) * 16) ^ xb));
#pragma unroll
    for (int j = 0; j < 2; j++)
#pragma unroll
      for (int s = 0; s < 2; s++)
        bf0[j][s] = *(const bf16x8*)(bb + (brow0 + j * 16 + l16) * 128 + (((s * 4 + quad) * 16) ^ xb));
    stA((t + 1) & (NT - 1), buf ^ 1);
    __builtin_amdgcn_s_barrier();
    __builtin_amdgcn_s_setprio(1);
#pragma unroll
    for (int i = 0; i < 4; i++)
#pragma unroll
      for (int j = 0; j < 2; j++)
#pragma unroll
        for (int s = 0; s < 2; s++)
          acc[i][j] = __builtin_amdgcn_mfma_f32_16x16x32_bf16(af[i][s], bf0[j][s], acc[i][j], 0, 0, 0);
    __builtin_amdgcn_s_setprio(0);
    __builtin_amdgcn_s_barrier();

    // ---- phase 1: Q(0,1) ----
#pragma unroll
    for (int j = 0; j < 2; j++)
#pragma unroll
      for (int s = 0; s < 2; s++)
        bf1v[j][s] = *(const bf16x8*)(bb + (brow0 + 32 + j * 16 + l16) * 128 + (((s * 4 + quad) * 16) ^ xb));
    __builtin_amdgcn_s_barrier();
    __builtin_amdgcn_s_setprio(1);
#pragma unroll
    for (int i = 0; i < 4; i++)
#pragma unroll
      for (int j = 0; j < 2; j++)
#pragma unroll
        for (int s = 0; s < 2; s++)
          acc[i][2 + j] = __builtin_amdgcn_mfma_f32_16x16x32_bf16(af[i][s], bf1v[j][s], acc[i][2 + j], 0, 0, 0);
    __builtin_amdgcn_s_setprio(0);
    __builtin_amdgcn_s_barrier();

    // ---- phase 2: Q(1,1) ----
#pragma unroll
    for (int i = 0; i < 4; i++)
#pragma unroll
      for (int s = 0; s < 2; s++)
        af[i][s] = *(const bf16x8*)(ab + (64 + i * 16 + l16) * 128 + (((s * 4 + quad) * 16) ^ xb));
    stB((t + 2) & (NT - 1), buf, 0);
    __builtin_amdgcn_s_barrier();
    __builtin_amdgcn_s_setprio(1);
#pragma unroll
    for (int i = 0; i < 4; i++)
#pragma unroll
      for (int j = 0; j < 2; j++)
#pragma unroll
        for (int s = 0; s < 2; s++)
          acc[4 + i][2 + j] = __builtin_amdgcn_mfma_f32_16x16x32_bf16(af[i][s], bf1v[j][s], acc[4 + i][2 + j], 0, 0, 0);
    __builtin_amdgcn_s_setprio(0);
    __builtin_amdgcn_s_barrier();

    // ---- phase 3: Q(1,0) ----
    stB((t + 2) & (NT - 1), buf, 1);
    __builtin_amdgcn_s_barrier();
    __builtin_amdgcn_s_setprio(1);
#pragma unroll
    for (int i = 0; i < 4; i++)
#pragma unroll
      for (int j = 0; j < 2; j++)
#pragma unroll
        for (int s = 0; s < 2; s++)
          acc[4 + i][j] = __builtin_amdgcn_mfma_f32_16x16x32_bf16(af[i][s], bf0[j][s], acc[4 + i][j], 0, 0, 0);
    __builtin_amdgcn_s_setprio(0);
    asm volatile("s_waitcnt vmcnt(4)" ::: "memory");
    __builtin_amdgcn_s_barrier();
  }

  asm volatile("s_waitcnt vmcnt(0)" ::: "memory");

  // epilogue: bias + exact gelu + bf16 store
#pragma unroll
  for (int i = 0; i < 8; i++) {
#pragma unroll
    for (int j = 0; j < 4; j++) {
#pragma unroll
      for (int r = 0; r < 4; r++) {
        int row = m0 + wm * 128 + i * 16 + quad * 4 + r;
        int col = n0 + wn * 64 + j * 16 + l16;
        float val = acc[i][j][r] + bias[col];
        val = 0.5f * val * (1.0f + erff(val * 0.70710678118654752f));
        C[(size_t)row * GN + col] = f2bf(val);
      }
    }
  }
}

// ---------------------------------------------------------------------------
// 128x64-tile GEMM (N=1024 matmuls), BK=64, 8x8 L2 swizzle.
// Waves 2x2; each wave 64(m) x 32(n) -> acc[4][2], 16 MFMA per stage.
// ---------------------------------------------------------------------------
template<typename TC>
__global__ __launch_bounds__(256) void gemm_bt_n64(
    const u16* __restrict__ A, const u16* __restrict__ BT,
    const float* __restrict__ bias, TC* __restrict__ C,
    int N, int K)
{
  __shared__ __align__(16) u16 As[2][128 * 32];
  __shared__ __align__(16) u16 Bs[2][64 * 32];
  const int tid = threadIdx.x;
  const int wave = tid >> 6, lane = tid & 63;
  const int quad = lane >> 4, l16 = lane & 15;
  int bx, by; swizzle8(bx, by);
  const int m0 = by * 128, n0 = bx * 64;
  const int wm = (wave >> 1) * 64, wn = (wave & 1) * 32;
  const int srow = lane >> 2;
  const int skoff = (lane & 3) * 8;

  f32x4 acc[4][2] = {};

  for (int k0 = 0; k0 < K; k0 += 64) {
#pragma unroll
    for (int h = 0; h < 2; h++) {
#pragma unroll
      for (int t = 0; t < 2; t++) {
        int slot = wave * 2 + t;
        int row = slot * 16 + srow;
        async_cp16(A + (size_t)(m0 + row) * K + k0 + h * 32 + skoff, As[h] + slot * 512);
      }
      int row = wave * 16 + srow;
      async_cp16(BT + (size_t)(n0 + row) * K + k0 + h * 32 + skoff, Bs[h] + wave * 512);
    }
    __syncthreads();

#pragma unroll
    for (int h = 0; h < 2; h++) {
      bf16x8 af[4], bfv[2];
#pragma unroll
      for (int i = 0; i < 4; i++)
        af[i] = *(const bf16x8*)(As[h] + (wm + i * 16 + l16) * 32 + quad * 8);
#pragma unroll
      for (int j = 0; j < 2; j++)
        bfv[j] = *(const bf16x8*)(Bs[h] + (wn + j * 16 + l16) * 32 + quad * 8);
#pragma unroll
      for (int i = 0; i < 4; i++)
#pragma unroll
        for (int j = 0; j < 2; j++)
          acc[i][j] = __builtin_amdgcn_mfma_f32_16x16x32_bf16(af[i], bfv[j], acc[i][j], 0, 0, 0);
    }
    __syncthreads();
  }

#pragma unroll
  for (int i = 0; i < 4; i++) {
#pragma unroll
    for (int j = 0; j < 2; j++) {
#pragma unroll
      for (int r = 0; r < 4; r++) {
        int row = m0 + wm + i * 16 + quad * 4 + r;
        int col = n0 + wn + j * 16 + l16;
        stv(C, (size_t)row * N + col, acc[i][j][r] + bias[col]);
      }
    }
  }
}

// ---------------------------------------------------------------------------
// V transpose: (BH, S, W) -> (BH, W, S), 64x64 tiles via LDS.
// ---------------------------------------------------------------------------
__global__ __launch_bounds__(256) void transpose_v_kernel(
    const u16* __restrict__ v, u16* __restrict__ vt)
{
  __shared__ __align__(16) u16 T[64][72];
  const int bh = blockIdx.y, k0 = blockIdx.x * 64, tid = threadIdx.x;
#pragma unroll
  for (int it = 0; it < 2; it++) {
    int vv = tid + it * 256;
    int key = vv >> 3, w0 = (vv & 7) * 8;
    union { uint4 q; u16 e[8]; } u;
    u.q = *(const uint4*)(v + ((size_t)bh * S + k0 + key) * W + w0);
#pragma unroll
    for (int j = 0; j < 8; j++) T[w0 + j][key] = u.e[j];
  }
  __syncthreads();
#pragma unroll
  for (int it = 0; it < 2; it++) {
    int vv = tid + it * 256;
    int w = vv >> 3, koff = (vv & 7) * 8;
    *(uint4*)(vt + ((size_t)bh * W + w) * S + k0 + koff) = *(const uint4*)(&T[w][koff]);
  }
}

// ---------------------------------------------------------------------------
// Flash attention (MFMA). QBLK=128 (4 waves x 32 q-rows), swapped QK^T,
// ballot mask, b64 P-stores, key-split 2-way, XOR-swizzled LDS.
// ---------------------------------------------------------------------------
__global__ __launch_bounds__(256) void fattn_kernel(
    const u16* __restrict__ q, const u16* __restrict__ k,
    const u16* __restrict__ vt, const int* __restrict__ mask,
    u16* __restrict__ o_parts, float* __restrict__ l_parts)
{
  __shared__ __align__(16) u16 QP[2][128][32];  // Q staging, then P tiles
  __shared__ __align__(16) u16 Kl[2][64][32];   // K tile [key][w]
  __shared__ __align__(16) u16 Vl[2][64][32];   // V^T tile [w][key]

  const int tid = threadIdx.x, wave = tid >> 6, lane = tid & 63;
  const int quad = lane >> 4, l16 = lane & 15;
  const int bh = blockIdx.y, b = bh >> 4, h = bh & 15;
  const int q0 = blockIdx.x * 128;
  const int half = blockIdx.z;
  const int kbase = half * (S / 2);             // first key of this half
  const int wq0 = wave * 32;                    // wave's 32 q-rows
  const int sr  = tid >> 3;              // 0..31
  const int sg  = tid & 7;               // chunk along W: 0..7
  const int sp  = sg >> 2;               // plane (cols 0-31 / 32-63)
  const int sc0 = sg * 8;                // global col (u16 units)
  const int ssw = (((sg & 3) ^ ((sr >> 1) & 3)) << 3);
  const int xr = (l16 >> 1) & 3;
  const int rq = ((quad ^ xr) << 3);

  // stage Q tile 128x64 (swizzled)
#pragma unroll
  for (int t = 0; t < 4; t++) {
    int row = sr + t * 32;
    *(uint4*)(&QP[sp][row][ssw]) =
        *(const uint4*)(q + ((size_t)bh * S + q0 + row) * W + sc0);
  }
  __syncthreads();
  bf16x8 aq[2][2];
#pragma unroll
  for (int g = 0; g < 2; g++)
#pragma unroll
    for (int kc = 0; kc < 2; kc++)
      aq[g][kc] = *(const bf16x8*)(&QP[kc][wq0 + g * 16 + l16][rq]);

  bf16x8 ones;
  {
    u16 ov = (l16 == 0) ? (u16)0x3F80 : (u16)0;
#pragma unroll
    for (int j = 0; j < 8; j++) ones[j] = u2b(ov);
  }

  f32x4 o_acc[2][4] = {};
  f32x4 l_acc[2] = {};

  uint4 kr0, kr1, vr0, vr1;
  int mv;
  kr0 = *(const uint4*)(k  + ((size_t)bh * S + kbase + sr     ) * W + sc0);
  kr1 = *(const uint4*)(k  + ((size_t)bh * S + kbase + sr + 32) * W + sc0);
  vr0 = *(const uint4*)(vt + ((size_t)bh * W + sr     ) * S + kbase + sc0);
  vr1 = *(const uint4*)(vt + ((size_t)bh * W + sr + 32) * S + kbase + sc0);
  mv  = mask[b * S + kbase + lane];

  constexpr int NT = S / 128;   // 16 key tiles per half
  for (int kt = 0; kt < NT; kt++) {
    __syncthreads();
    *(uint4*)(&Kl[sp][sr     ][ssw]) = kr0;
    *(uint4*)(&Kl[sp][sr + 32][ssw]) = kr1;
    *(uint4*)(&Vl[sp][sr     ][ssw]) = vr0;
    *(uint4*)(&Vl[sp][sr + 32][ssw]) = vr1;
    u64 km = __ballot(mv != 0);
    __syncthreads();

    if (kt + 1 < NT) {
      int kn = kbase + (kt + 1) * 64;
      kr0 = *(const uint4*)(k  + ((size_t)bh * S + kn + sr     ) * W + sc0);
      kr1 = *(const uint4*)(k  + ((size_t)bh * S + kn + sr + 32) * W + sc0);
      vr0 = *(const uint4*)(vt + ((size_t)bh * W + sr     ) * S + kn + sc0);
      vr1 = *(const uint4*)(vt + ((size_t)bh * W + sr + 32) * S + kn + sc0);
      mv  = mask[b * S + kn + lane];
    }

#pragma unroll
    for (int tn = 0; tn < 4; tn++) {
      bf16x8 bk0 = *(const bf16x8*)(&Kl[0][tn * 16 + l16][rq]);
      bf16x8 bk1 = *(const bf16x8*)(&Kl[1][tn * 16 + l16][rq]);
      u32 nib = (u32)(km >> (tn * 16 + quad * 4)) & 0xFu;
      int slotp = (((tn & 1) * 2 + (quad >> 1)) ^ xr) * 8 + (quad & 1) * 4;
#pragma unroll
      for (int g = 0; g < 2; g++) {
        f32x4 s4 = {};
        s4 = __builtin_amdgcn_mfma_f32_16x16x32_bf16(bk0, aq[g][0], s4, 0, 0, 0);
        s4 = __builtin_amdgcn_mfma_f32_16x16x32_bf16(bk1, aq[g][1], s4, 0, 0, 0);
        union { u64 u; u16 e[4]; } pw;
#pragma unroll
        for (int r = 0; r < 4; r++) {
          float pm = (float)((nib >> r) & 1u);
          pw.e[r] = f2bf_cvt(__expf(s4[r]) * pm);
        }
        *(u64*)(&QP[tn >> 1][wq0 + g * 16 + l16][slotp]) = pw.u;
      }
    }

#pragma unroll
    for (int kc = 0; kc < 2; kc++) {
      bf16x8 ap0 = *(const bf16x8*)(&QP[kc][wq0      + l16][rq]);
      bf16x8 ap1 = *(const bf16x8*)(&QP[kc][wq0 + 16 + l16][rq]);
#pragma unroll
      for (int tn = 0; tn < 4; tn++) {
        bf16x8 bv = *(const bf16x8*)(&Vl[kc][tn * 16 + l16][rq]);
        o_acc[0][tn] = __builtin_amdgcn_mfma_f32_16x16x32_bf16(ap0, bv, o_acc[0][tn], 0, 0, 0);
        o_acc[1][tn] = __builtin_amdgcn_mfma_f32_16x16x32_bf16(ap1, bv, o_acc[1][tn], 0, 0, 0);
      }
      l_acc[0] = __builtin_amdgcn_mfma_f32_16x16x32_bf16(ap0, ones, l_acc[0], 0, 0, 0);
      l_acc[1] = __builtin_amdgcn_mfma_f32_16x16x32_bf16(ap1, ones, l_acc[1], 0, 0, 0);
    }
  }

  u16* ob = o_parts + (size_t)half * M * D;
  float* lb = l_parts + (size_t)half * M * H;
#pragma unroll
  for (int g = 0; g < 2; g++) {
#pragma unroll
    for (int r = 0; r < 4; r++) {
      float lsum = __shfl(l_acc[g][r], lane & 0x30);
      int sg2 = q0 + wq0 + g * 16 + quad * 4 + r;
      if (l16 == 0) lb[((size_t)b * S + sg2) * H + h] = lsum;
#pragma unroll
      for (int tn = 0; tn < 4; tn++) {
        ob[((size_t)b * S + sg2) * D + h * W + tn * 16 + l16] = f2bf_cvt(o_acc[g][tn][r]);
      }
    }
  }
}

// ---------------------------------------------------------------------------
// Combine key-split partials: attn = (o0 + o1) / (l0 + l1). In-place on
// half 0 (same-address elementwise -> race-free).
// ---------------------------------------------------------------------------
__global__ __launch_bounds__(256) void combine_attn(
    const u16* __restrict__ o_parts, const float* __restrict__ l_parts,
    u16* __restrict__ attn)
{
  size_t idx = ((size_t)blockIdx.x * 256 + threadIdx.x) * 8;
  int row = (int)(idx >> 10);          // (b*S+s)
  int h = ((int)idx >> 6) & 15;        // head (8 elems stay in one head)
  float l = l_parts[(size_t)row * H + h] + l_parts[(size_t)M * H + (size_t)row * H + h];
  float inv = 1.0f / l;
  union { uint4 v; u16 e[8]; } a, bq, o;
  a.v  = *(const uint4*)(o_parts + idx);
  bq.v = *(const uint4*)(o_parts + (size_t)M * D + idx);
#pragma unroll
  for (int j = 0; j < 8; j++)
    o.e[j] = f2bf((bf2f(a.e[j]) + bf2f(bq.e[j])) * inv);
  *(uint4*)(attn + idx) = o.v;
}

// ---------------------------------------------------------------------------
// Fused residual + LayerNorm, one WAVE per row (no block barriers).
// grid = M/4 blocks of 256 threads.
// ---------------------------------------------------------------------------
template<typename TA, typename TR, typename TO>
__global__ __launch_bounds__(256) void ln_res_kernel(
    const TA* __restrict__ a, const TR* __restrict__ r,
    const float* __restrict__ g, const float* __restrict__ be,
    TO* __restrict__ out)
{
  const int tid = threadIdx.x, lane = tid & 63;
  const int row = blockIdx.x * 4 + (tid >> 6);
  const TA* ap = a + (size_t)row * D;
  const TR* rp = r + (size_t)row * D;
  float hv[16];
  float s = 0.f;
#pragma unroll
  for (int c = 0; c < 16; c++) {
    int d = c * 64 + lane;
    hv[c] = ldv(ap, d) + ldv(rp, d);
    s += hv[c];
  }
#pragma unroll
  for (int d = 1; d < 64; d <<= 1) s += __shfl_xor(s, d);
  float mean = s * (1.0f / D);
  float v = 0.f;
#pragma unroll
  for (int c = 0; c < 16; c++) { float t = hv[c] - mean; v += t * t; }
#pragma unroll
  for (int d = 1; d < 64; d <<= 1) v += __shfl_xor(v, d);
  float inv = rsqrtf(v * (1.0f / D) + 1e-12f);
#pragma unroll
  for (int c = 0; c < 16; c++) {
    int d = c * 64 + lane;
    stv(out, (size_t)row * D + d, g[d] * ((hv[c] - mean) * inv) + be[d]);
  }
}

// ---------------------------------------------------------------------------
extern "C" void kernel_launch(void* const* d_in, const int* in_sizes, int n_in,
                              void* d_out, int out_size, void* d_ws, size_t ws_size,
                              hipStream_t stream)
{
  const float* x  = (const float*)d_in[0];
  const int* mask = (const int*)d_in[1];
  const float* wq = (const float*)d_in[2];  const float* bq  = (const float*)d_in[3];
  const float* wk = (const float*)d_in[4];  const float* bk  = (const float*)d_in[5];
  const float* wv = (const float*)d_in[6];  const float* bv  = (const float*)d_in[7];
  const float* wo = (const float*)d_in[8];  const float* bo  = (const float*)d_in[9];
  const float* g1 = (const float*)d_in[10]; const float* b1  = (const float*)d_in[11];
  const float* w1 = (const float*)d_in[12]; const float* bf1 = (const float*)d_in[13];
  const float* w2 = (const float*)d_in[14]; const float* bf2 = (const float*)d_in[15];
  const float* g2 = (const float*)d_in[16]; const float* b2  = (const float*)d_in[17];

  // ws layout (peak 48 MB):
  //  A [0,8M):   wqkvT(6M)+woT(2M); wqkvT dead after QKV -> l_parts(512KB)
  //              lives at [0,0.5M) during fattn; then w1T(8M) -> w2T(8M)
  //  B [8,16M):  xb -> vt -> ff1[0:8M)
  //  C [16,24M): q  -> proj -> ff1[8:16M)
  //  D [24,32M): k  -> ff1[16:24M)
  //  E [32,48M): v(8M, dead after transpose_v) -> o_parts(16M); combine
  //              writes attn in-place over half 0 ([32,40M)) -> ff1[24:32M)
  //  F [40,48M): bqkv(12KB, dead by fattn) -> o_parts half1 -> h1
  //  ff2 goes to d_out (fp32); LN2 runs in place on d_out.
  char* ws = (char*)d_ws;
  const size_t MB = 1024 * 1024;
  u16* wqkvT = (u16*)(ws + 0 * MB);          // (3072, 1024) bf16
  u16* woT   = (u16*)(ws + 6 * MB);          // (1024, 1024)
  u16* w1T   = (u16*)(ws + 0 * MB);          // (4096, 1024) after proj
  u16* w2T   = (u16*)(ws + 0 * MB);          // (1024, 4096) after ffn1
  u16* xb    = (u16*)(ws + 8 * MB);
  u16* vt    = (u16*)(ws + 8 * MB);
  u16* q     = (u16*)(ws + 16 * MB);
  u16* proj  = (u16*)(ws + 16 * MB);
  u16* kb    = (u16*)(ws + 24 * MB);
  u16* vb    = (u16*)(ws + 32 * MB);
  u16* oparts = (u16*)(ws + 32 * MB);        // 16 MB: 2 x (M,D) bf16 partials
  float* lparts = (float*)(ws + 0 * MB);     // 512 KB: 2 x (M,H) f32
  u16* attn  = (u16*)(ws + 32 * MB);         // combine output (aliases half0)
  u16* ff1   = (u16*)(ws + 8 * MB);          // 32 MB: [8,40)
  float* bqkv = (float*)(ws + 40 * MB);      // 12 KB
  u16* h1    = (u16*)(ws + 40 * MB);
  float* out = (float*)d_out;

  dim3 blk(256);

  // prep: x -> bf16; weights -> bf16 transposed; bias concat
  conv_x_kernel<<<dim3(M * D / 1024), blk, 0, stream>>>(x, xb);
  transpose_w_kernel<<<dim3(16, 16), blk, 0, stream>>>(wq, wqkvT,            D, D);
  transpose_w_kernel<<<dim3(16, 16), blk, 0, stream>>>(wk, wqkvT + 1024*1024, D, D);
  transpose_w_kernel<<<dim3(16, 16), blk, 0, stream>>>(wv, wqkvT + 2048*1024, D, D);
  transpose_w_kernel<<<dim3(16, 16), blk, 0, stream>>>(wo, woT,              D, D);
  hipMemcpyAsync(bqkv,        bq, D * sizeof(float), hipMemcpyDeviceToDevice, stream);
  hipMemcpyAsync(bqkv + 1024, bk, D * sizeof(float), hipMemcpyDeviceToDevice, stream);
  hipMemcpyAsync(bqkv + 2048, bv, D * sizeof(float), hipMemcpyDeviceToDevice, stream);

  // fused QKV GEMM: (M,1024) @ (1024,3072) -> q,k,v permuted (q scaled)
  gemm_bt<2, u16><<<dim3(3072 / 128, M / 128), blk, 0, stream>>>(
      xb, wqkvT, bqkv, q, 3072, D, 0.125f);

  transpose_v_kernel<<<dim3(S / 64, Bb * H), blk, 0, stream>>>(vb, vt);
  // key-split flash attention: QBLK=128, 1024 blocks, partials
  fattn_kernel<<<dim3(S / 128, Bb * H, 2), blk, 0, stream>>>(
      q, kb, vt, mask, oparts, lparts);
  combine_attn<<<dim3(M * D / 2048), blk, 0, stream>>>(oparts, lparts, attn);

  // proj: N=1024 -> 128x64 tiles (512 blocks, 2/CU)
  gemm_bt_n64<u16><<<dim3(D / 64, M / 128), blk, 0, stream>>>(
      attn, woT, bo, proj, D, D);
  ln_res_kernel<float, u16, u16><<<dim3(M / 4), blk, 0, stream>>>(x, proj, g1, b1, h1);

  transpose_w_kernel<<<dim3(F / 64, D / 64), blk, 0, stream>>>(w1, w1T, D, F);
  // FFN1: 256^2 8-phase GEMM (T2+T3+T4+T5), 256 blocks of 512 thr = 1/CU
  gemm256_gelu<<<dim3(F / 256, M / 256), dim3(512), 0, stream>>>(
      h1, w1T, bf1, ff1);

  transpose_w_kernel<<<dim3(D / 64, F / 64), blk, 0, stream>>>(w2, w2T, F, D);
  // FFN2: N=1024 -> 128x64 tiles, fp32 out; LN2 in place on d_out
  gemm_bt_n64<float><<<dim3(D / 64, M / 128), blk, 0, stream>>>(
      ff1, w2T, bf2, out, D, F);
  ln_res_kernel<u16, float, float><<<dim3(M / 4), blk, 0, stream>>>(h1, out, g2, b2, out);
}

// Round 5
// 401.233 us; speedup vs baseline: 1.0738x; 1.0016x over previous
//
#include <hip/hip_runtime.h>
#include <cstdint>
#include <cstddef>

using u16 = unsigned short;
using u32 = unsigned int;
using u64 = unsigned long long;

typedef __bf16 bf16x8 __attribute__((ext_vector_type(8)));
typedef float f32x4 __attribute__((ext_vector_type(4)));

static constexpr int Bb = 2, S = 2048, D = 1024, H = 16, W = 64, F = 4096;
static constexpr int M = Bb * S;   // 4096 rows

__device__ __forceinline__ float bf2f(u16 u) {
  union { u32 i; float f; } c; c.i = ((u32)u) << 16; return c.f;
}
__device__ __forceinline__ u16 f2bf(float f) {
  union { float f; u32 i; } c; c.f = f;
  u32 i = c.i;
  u32 r = (i + 0x7fffu + ((i >> 16) & 1u)) >> 16;
  return (u16)r;
}
__device__ __forceinline__ u16 f2bf_cvt(float f) {
  __bf16 b = (__bf16)f;
  union { __bf16 b; u16 u; } c; c.b = b; return c.u;
}
__device__ __forceinline__ __bf16 u2b(u16 x) {
  union { u16 u; __bf16 b; } c; c.u = x; return c.b;
}
__device__ __forceinline__ void stv(float* p, size_t i, float v) { p[i] = v; }
__device__ __forceinline__ void stv(u16* p, size_t i, float v)   { p[i] = f2bf(v); }
__device__ __forceinline__ float ldv(const float* p, size_t i) { return p[i]; }
__device__ __forceinline__ float ldv(const u16* p, size_t i)   { return bf2f(p[i]); }

__device__ __forceinline__ void async_cp16(const u16* g, u16* l) {
  __builtin_amdgcn_global_load_lds(
      (const __attribute__((address_space(1))) void*)g,
      (__attribute__((address_space(3))) void*)l, 16, 0, 0);
}

// 8x8 super-tile block swizzle for L2 locality. Requires gridDim.x%8==0,
// gridDim.y%8==0. 64 consecutive blocks -> 8 A-tiles + 8 B-tiles (~4MB).
__device__ __forceinline__ void swizzle8(int& bx, int& by) {
  int bid = blockIdx.y * gridDim.x + blockIdx.x;
  int gpr = gridDim.x >> 3;
  int grp = bid >> 6, rem = bid & 63;
  int gm = grp / gpr, gn = grp - gm * gpr;
  by = gm * 8 + (rem >> 3);
  bx = gn * 8 + (rem & 7);
}

// ---------------------------------------------------------------------------
// fp32 -> bf16 elementwise convert (n % 1024 == 0)
// ---------------------------------------------------------------------------
__global__ __launch_bounds__(256) void conv_x_kernel(
    const float* __restrict__ src, u16* __restrict__ dst)
{
  int i = (blockIdx.x * 256 + threadIdx.x) * 4;
  float4 v = *(const float4*)(src + i);
  u16 r[4] = { f2bf(v.x), f2bf(v.y), f2bf(v.z), f2bf(v.w) };
  *(uint2*)(dst + i) = *(const uint2*)r;
}

// ---------------------------------------------------------------------------
// Weight transpose+convert: src (K,N) fp32 -> dst (N,K) bf16. 64x64 tiles.
// ---------------------------------------------------------------------------
__global__ __launch_bounds__(256) void transpose_w_kernel(
    const float* __restrict__ src, u16* __restrict__ dst, int K, int N)
{
  __shared__ __align__(16) u16 T[64][72];
  const int tid = threadIdx.x;
  const int n0 = blockIdx.x * 64, k0 = blockIdx.y * 64;
#pragma unroll
  for (int t = 0; t < 4; t++) {
    int idx = tid + t * 256;           // 0..1023 float4s
    int r = idx >> 4, c4 = (idx & 15) * 4;
    float4 v = *(const float4*)(src + (size_t)(k0 + r) * N + n0 + c4);
    T[c4 + 0][r] = f2bf(v.x); T[c4 + 1][r] = f2bf(v.y);
    T[c4 + 2][r] = f2bf(v.z); T[c4 + 3][r] = f2bf(v.w);
  }
  __syncthreads();
#pragma unroll
  for (int t = 0; t < 2; t++) {
    int idx = tid + t * 256;           // 0..511 uint4s
    int r = idx >> 3, c8 = (idx & 7) * 8;
    *(uint4*)(dst + (size_t)(n0 + r) * K + k0 + c8) = *(const uint4*)(&T[r][c8]);
  }
}

// ---------------------------------------------------------------------------
// m97-style GEMM, BK=64, 8x8 L2 swizzle. C = A(Mr,K) @ BT(N,K)^T + bias.
// 128x128 tile, 4 waves (2x2), each wave 64x64 (4x4 MFMA), 32 MFMA/stage.
// EPI: 0 plain, 2 fused-qkv permute (N=3072, scale on q).
// ---------------------------------------------------------------------------
template<int EPI, typename TC>
__global__ __launch_bounds__(256) void gemm_bt(
    const u16* __restrict__ A, const u16* __restrict__ BT,
    const float* __restrict__ bias, TC* __restrict__ C,
    int N, int K, float scale)
{
  __shared__ __align__(16) u16 As[2][128 * 32];
  __shared__ __align__(16) u16 Bs[2][128 * 32];
  const int tid = threadIdx.x;
  const int wave = tid >> 6, lane = tid & 63;
  const int quad = lane >> 4, l16 = lane & 15;
  int bx, by; swizzle8(bx, by);
  const int m0 = by * 128, n0 = bx * 128;
  const int wm = (wave >> 1) * 64, wn = (wave & 1) * 64;
  const int srow = lane >> 2;          // 0..15 within slot
  const int skoff = (lane & 3) * 8;    // 0/8/16/24

  f32x4 acc[4][4] = {};

  for (int k0 = 0; k0 < K; k0 += 64) {
#pragma unroll
    for (int h = 0; h < 2; h++) {
#pragma unroll
      for (int t = 0; t < 2; t++) {
        int slot = wave * 2 + t;                   // 0..7 -> 16 rows each
        int row = slot * 16 + srow;
        const u16* ga = A  + (size_t)(m0 + row) * K + k0 + h * 32 + skoff;
        const u16* gb = BT + (size_t)(n0 + row) * K + k0 + h * 32 + skoff;
        async_cp16(ga, As[h] + slot * 512);        // lane i -> +16i bytes
        async_cp16(gb, Bs[h] + slot * 512);
      }
    }
    __syncthreads();

#pragma unroll
    for (int h = 0; h < 2; h++) {
      bf16x8 af[4], bfv[4];
#pragma unroll
      for (int i = 0; i < 4; i++)
        af[i] = *(const bf16x8*)(As[h] + (wm + i * 16 + l16) * 32 + quad * 8);
#pragma unroll
      for (int j = 0; j < 4; j++)
        bfv[j] = *(const bf16x8*)(Bs[h] + (wn + j * 16 + l16) * 32 + quad * 8);
#pragma unroll
      for (int i = 0; i < 4; i++)
#pragma unroll
        for (int j = 0; j < 4; j++)
          acc[i][j] = __builtin_amdgcn_mfma_f32_16x16x32_bf16(af[i], bfv[j], acc[i][j], 0, 0, 0);
    }
    __syncthreads();
  }

#pragma unroll
  for (int i = 0; i < 4; i++) {
#pragma unroll
    for (int j = 0; j < 4; j++) {
#pragma unroll
      for (int r = 0; r < 4; r++) {
        int row = m0 + wm + i * 16 + quad * 4 + r;
        int col = n0 + wn + j * 16 + l16;
        float val = acc[i][j][r] + bias[col];
        if (EPI == 2) {
          int sel = col >> 10, c = col & 1023;       // D = 1024
          if (sel == 0) val *= scale;
          int bb = row >> 11, ss = row & 2047;       // S = 2048
          int hh = c >> 6,  ww = c & 63;             // W = 64
          u16* dst = (u16*)C + (size_t)sel * M * D;
          dst[(((size_t)(bb * H + hh) * S) + ss) * W + ww] = f2bf(val);
        } else {
          stv(C, (size_t)row * N + col, val);
        }
      }
    }
  }
}

// ---------------------------------------------------------------------------
// 256x256-tile 8-phase GEMM (HK-style schedule, plain HIP) for FFN1:
// C = gelu(A(M,K) @ BT(N,K)^T + bias), bf16 out. K=1024 (NT=16 K-tiles).
// (See round-4 comments for the full phase/vmcnt ledger.)
// ---------------------------------------------------------------------------
__global__ __launch_bounds__(512, 2) void gemm256_gelu(
    const u16* __restrict__ A, const u16* __restrict__ BT,
    const float* __restrict__ bias, u16* __restrict__ C)
{
  constexpr int GN = F, GK = D, NT = GK / 64;
  __shared__ __align__(16) u16 AL[2][2][128 * 64];
  __shared__ __align__(16) u16 BL[2][2][128 * 64];
  const int tid = threadIdx.x;
  const int wave = tid >> 6, lane = tid & 63;
  const int quad = lane >> 4, l16 = lane & 15;
  const int wm = wave >> 2, wn = wave & 3;
  int bx, by; swizzle8(bx, by);
  const int m0 = by * 256, n0 = bx * 256;
  const int lr = lane >> 3;
  const int kc8 = ((lane & 7) ^ lr) * 8;          // u16 units
  const int xb = (l16 & 7) * 16;
  const int brow0 = (wn & 1) * 64;                // B row base within half
  const char* abase = (const char*)&AL[0][wm][0];
  const char* bbase = (const char*)&BL[0][wn >> 1][0];
  constexpr int BUFB = 2 * 128 * 64 * 2;          // byte stride AL[1]-AL[0]

  f32x4 acc[8][4] = {};

  auto stA = [&](int t, int buf) {                // A(t) both halves, 4 issues
#pragma unroll
    for (int half = 0; half < 2; half++)
#pragma unroll
      for (int j = 0; j < 2; j++) {
        const u16* g = A + (size_t)(m0 + half * 128 + (j * 8 + wave) * 8 + lr) * GK
                         + t * 64 + kc8;
        async_cp16(g, &AL[buf][half][(j * 8 + wave) * 512]);
      }
  };
  auto stB = [&](int t, int buf, int half) {      // B(t) one half, 2 issues
#pragma unroll
    for (int j = 0; j < 2; j++) {
      const u16* g = BT + (size_t)(n0 + half * 128 + (j * 8 + wave) * 8 + lr) * GK
                        + t * 64 + kc8;
      async_cp16(g, &BL[buf][half][(j * 8 + wave) * 512]);
    }
  };

  stA(0, 0);
  stB(0, 0, 0); stB(0, 0, 1);
  stB(1, 1, 0); stB(1, 1, 1);
  asm volatile("s_waitcnt vmcnt(4)" ::: "memory");
  __builtin_amdgcn_s_barrier();

  bf16x8 af[4][2], bf0[2][2], bf1v[2][2];

#pragma unroll 2
  for (int t = 0; t < NT; t++) {
    const int buf = t & 1;
    const char* ab = abase + buf * BUFB;
    const char* bb = bbase + buf * BUFB;

    // ---- phase 0: Q(0,0) ----
#pragma unroll
    for (int i = 0; i < 4; i++)
#pragma unroll
      for (int s = 0; s < 2; s++)
        af[i][s] = *(const bf16x8*)(ab + (i * 16 + l16) * 128 + (((s * 4 + quad) * 16) ^ xb));
#pragma unroll
    for (int j = 0; j < 2; j++)
#pragma unroll
      for (int s = 0; s < 2; s++)
        bf0[j][s] = *(const bf16x8*)(bb + (brow0 + j * 16 + l16) * 128 + (((s * 4 + quad) * 16) ^ xb));
    stA((t + 1) & (NT - 1), buf ^ 1);
    __builtin_amdgcn_s_barrier();
    __builtin_amdgcn_s_setprio(1);
#pragma unroll
    for (int i = 0; i < 4; i++)
#pragma unroll
      for (int j = 0; j < 2; j++)
#pragma unroll
        for (int s = 0; s < 2; s++)
          acc[i][j] = __builtin_amdgcn_mfma_f32_16x16x32_bf16(af[i][s], bf0[j][s], acc[i][j], 0, 0, 0);
    __builtin_amdgcn_s_setprio(0);
    __builtin_amdgcn_s_barrier();

    // ---- phase 1: Q(0,1) ----
#pragma unroll
    for (int j = 0; j < 2; j++)
#pragma unroll
      for (int s = 0; s < 2; s++)
        bf1v[j][s] = *(const bf16x8*)(bb + (brow0 + 32 + j * 16 + l16) * 128 + (((s * 4 + quad) * 16) ^ xb));
    __builtin_amdgcn_s_barrier();
    __builtin_amdgcn_s_setprio(1);
#pragma unroll
    for (int i = 0; i < 4; i++)
#pragma unroll
      for (int j = 0; j < 2; j++)
#pragma unroll
        for (int s = 0; s < 2; s++)
          acc[i][2 + j] = __builtin_amdgcn_mfma_f32_16x16x32_bf16(af[i][s], bf1v[j][s], acc[i][2 + j], 0, 0, 0);
    __builtin_amdgcn_s_setprio(0);
    __builtin_amdgcn_s_barrier();

    // ---- phase 2: Q(1,1) ----
#pragma unroll
    for (int i = 0; i < 4; i++)
#pragma unroll
      for (int s = 0; s < 2; s++)
        af[i][s] = *(const bf16x8*)(ab + (64 + i * 16 + l16) * 128 + (((s * 4 + quad) * 16) ^ xb));
    stB((t + 2) & (NT - 1), buf, 0);
    __builtin_amdgcn_s_barrier();
    __builtin_amdgcn_s_setprio(1);
#pragma unroll
    for (int i = 0; i < 4; i++)
#pragma unroll
      for (int j = 0; j < 2; j++)
#pragma unroll
        for (int s = 0; s < 2; s++)
          acc[4 + i][2 + j] = __builtin_amdgcn_mfma_f32_16x16x32_bf16(af[i][s], bf1v[j][s], acc[4 + i][2 + j], 0, 0, 0);
    __builtin_amdgcn_s_setprio(0);
    __builtin_amdgcn_s_barrier();

    // ---- phase 3: Q(1,0) ----
    stB((t + 2) & (NT - 1), buf, 1);
    __builtin_amdgcn_s_barrier();
    __builtin_amdgcn_s_setprio(1);
#pragma unroll
    for (int i = 0; i < 4; i++)
#pragma unroll
      for (int j = 0; j < 2; j++)
#pragma unroll
        for (int s = 0; s < 2; s++)
          acc[4 + i][j] = __builtin_amdgcn_mfma_f32_16x16x32_bf16(af[i][s], bf0[j][s], acc[4 + i][j], 0, 0, 0);
    __builtin_amdgcn_s_setprio(0);
    asm volatile("s_waitcnt vmcnt(4)" ::: "memory");
    __builtin_amdgcn_s_barrier();
  }

  asm volatile("s_waitcnt vmcnt(0)" ::: "memory");

#pragma unroll
  for (int i = 0; i < 8; i++) {
#pragma unroll
    for (int j = 0; j < 4; j++) {
#pragma unroll
      for (int r = 0; r < 4; r++) {
        int row = m0 + wm * 128 + i * 16 + quad * 4 + r;
        int col = n0 + wn * 64 + j * 16 + l16;
        float val = acc[i][j][r] + bias[col];
        val = 0.5f * val * (1.0f + erff(val * 0.70710678118654752f));
        C[(size_t)row * GN + col] = f2bf(val);
      }
    }
  }
}

// ---------------------------------------------------------------------------
// FFN2 256x128-tile 8-phase split-K GEMM. Grid (D/128, M/256, 2) = 256
// blocks (1/CU). Each block: BM=256 x BN=128, K range [kz*2048,(kz+1)*2048)
// (NT=32 BK=64 tiles). Partial fp32 out (no bias; LN2 adds it): kz=0 -> P0,
// kz=1 -> P1. 8 waves as 4m x 2n; per-wave 64x64 out = acc[4][4], 32
// MFMA/K-tile. LDS 96 KB: AL[2 dbuf][2 mhalf][128*64], BL[2 dbuf][128*64].
// T2 both-sides swizzle identical to gemm256_gelu (pre-swizzled global src,
// XOR'd ds_read col). Staging: A = 4 issue-rounds/tile, B = 2.
// Schedule per K-tile t (buf=t&1), 4 phases:
//  p0: read A i01(4 b128) + B j01(4); stage A(t+1) rds 0-1 -> buf^1;
//      bar; prio1; MFMA i01xj01 (8); prio0; bar
//  p1: read B j23(4);                 stage A(t+1) rds 2-3 -> buf^1; ...MFMA i01xj23
//  p2: read A i23(4);                 stage B(t+2) rd 0 -> buf;     ...MFMA i23xj23
//  p3: regs only;                     stage B(t+2) rd 1 -> buf;     ...MFMA i23xj01;
//      vmcnt(2); bar
// Ledger (6 issues/lane/tile): at p3 queue = [B(t+1)(2) A(t+1)(4) B(t+2)(2)];
// vmcnt(2) leaves only B(t+2) in flight -> tile t+1 p0's operands landed.
// B(t+2)->BL[buf] is issued at p2, after p1's closing barrier retired all
// reads of BL[buf] (compiler waits ds_read->MFMA; MFMA precedes barrier).
// Prologue: A(0)(4), B(0)(2), B(1)(2) = 8 issues; vmcnt(2) -> tile 0 landed.
// Ring-clamp (t+1)&31/(t+2)&31 keeps the ledger uniform at the tail.
// ---------------------------------------------------------------------------
__global__ __launch_bounds__(512, 2) void gemm_ffn2_splitk(
    const u16* __restrict__ A, const u16* __restrict__ BT,
    float* __restrict__ P0, float* __restrict__ P1)
{
  constexpr int GK = F, NT = 32;
  __shared__ __align__(16) u16 AL[2][2][128 * 64];   // 64 KB
  __shared__ __align__(16) u16 BL[2][128 * 64];      // 32 KB
  const int tid = threadIdx.x;
  const int wave = tid >> 6, lane = tid & 63;
  const int quad = lane >> 4, l16 = lane & 15;
  const int wm = wave >> 1, wn = wave & 1;           // 4m x 2n
  int bx, by; swizzle8(bx, by);
  const int m0 = by * 256, n0 = bx * 128;
  const int kbase = blockIdx.z * (F / 2);
  const int lr = lane >> 3;
  const int kc8 = ((lane & 7) ^ lr) * 8;             // u16 units
  const int xb = (l16 & 7) * 16;
  const int arow0 = (wm & 1) * 64;                   // row base within mhalf
  const int brow0 = wn * 64;
  const char* abase = (const char*)&AL[0][wm >> 1][0];
  const char* bbase = (const char*)&BL[0][0];
  constexpr int ABUF = 2 * 128 * 64 * 2;             // AL[1]-AL[0] bytes
  constexpr int BBUF = 128 * 64 * 2;                 // BL[1]-BL[0] bytes

  f32x4 acc[4][4] = {};

  auto stA2 = [&](int t, int buf, int rp) {          // rounds rp*2..rp*2+1
#pragma unroll
    for (int rr = 0; rr < 2; rr++) {
      int rd = rp * 2 + rr;
      const u16* g = A + (size_t)(m0 + rd * 64 + wave * 8 + lr) * GK
                       + kbase + t * 64 + kc8;
      async_cp16(g, &AL[buf][rd >> 1][((rd & 1) * 8 + wave) * 512]);
    }
  };
  auto stB1 = [&](int t, int buf, int rd) {          // one round
    const u16* g = BT + (size_t)(n0 + rd * 64 + wave * 8 + lr) * GK
                      + kbase + t * 64 + kc8;
    async_cp16(g, &BL[buf][(rd * 8 + wave) * 512]);
  };

  // prologue
  stA2(0, 0, 0); stA2(0, 0, 1);
  stB1(0, 0, 0); stB1(0, 0, 1);
  stB1(1, 1, 0); stB1(1, 1, 1);
  asm volatile("s_waitcnt vmcnt(2)" ::: "memory");
  __builtin_amdgcn_s_barrier();

  bf16x8 af[2][2], bf0[2][2], bf1v[2][2];

#pragma unroll 2
  for (int t = 0; t < NT; t++) {
    const int buf = t & 1;
    const char* ab = abase + buf * ABUF;
    const char* bb = bbase + buf * BBUF;

    // ---- phase 0: i01 x j01 ----
#pragma unroll
    for (int i = 0; i < 2; i++)
#pragma unroll
      for (int s = 0; s < 2; s++)
        af[i][s] = *(const bf16x8*)(ab + (arow0 + i * 16 + l16) * 128 + (((s * 4 + quad) * 16) ^ xb));
#pragma unroll
    for (int j = 0; j < 2; j++)
#pragma unroll
      for (int s = 0; s < 2; s++)
        bf0[j][s] = *(const bf16x8*)(bb + (brow0 + j * 16 + l16) * 128 + (((s * 4 + quad) * 16) ^ xb));
    stA2((t + 1) & (NT - 1), buf ^ 1, 0);
    __builtin_amdgcn_s_barrier();
    __builtin_amdgcn_s_setprio(1);
#pragma unroll
    for (int i = 0; i < 2; i++)
#pragma unroll
      for (int j = 0; j < 2; j++)
#pragma unroll
        for (int s = 0; s < 2; s++)
          acc[i][j] = __builtin_amdgcn_mfma_f32_16x16x32_bf16(af[i][s], bf0[j][s], acc[i][j], 0, 0, 0);
    __builtin_amdgcn_s_setprio(0);
    __builtin_amdgcn_s_barrier();

    // ---- phase 1: i01 x j23 ----
#pragma unroll
    for (int j = 0; j < 2; j++)
#pragma unroll
      for (int s = 0; s < 2; s++)
        bf1v[j][s] = *(const bf16x8*)(bb + (brow0 + 32 + j * 16 + l16) * 128 + (((s * 4 + quad) * 16) ^ xb));
    stA2((t + 1) & (NT - 1), buf ^ 1, 1);
    __builtin_amdgcn_s_barrier();
    __builtin_amdgcn_s_setprio(1);
#pragma unroll
    for (int i = 0; i < 2; i++)
#pragma unroll
      for (int j = 0; j < 2; j++)
#pragma unroll
        for (int s = 0; s < 2; s++)
          acc[i][2 + j] = __builtin_amdgcn_mfma_f32_16x16x32_bf16(af[i][s], bf1v[j][s], acc[i][2 + j], 0, 0, 0);
    __builtin_amdgcn_s_setprio(0);
    __builtin_amdgcn_s_barrier();

    // ---- phase 2: i23 x j23 ----
#pragma unroll
    for (int i = 0; i < 2; i++)
#pragma unroll
      for (int s = 0; s < 2; s++)
        af[i][s] = *(const bf16x8*)(ab + (arow0 + 32 + i * 16 + l16) * 128 + (((s * 4 + quad) * 16) ^ xb));
    stB1((t + 2) & (NT - 1), buf, 0);
    __builtin_amdgcn_s_barrier();
    __builtin_amdgcn_s_setprio(1);
#pragma unroll
    for (int i = 0; i < 2; i++)
#pragma unroll
      for (int j = 0; j < 2; j++)
#pragma unroll
        for (int s = 0; s < 2; s++)
          acc[2 + i][2 + j] = __builtin_amdgcn_mfma_f32_16x16x32_bf16(af[i][s], bf1v[j][s], acc[2 + i][2 + j], 0, 0, 0);
    __builtin_amdgcn_s_setprio(0);
    __builtin_amdgcn_s_barrier();

    // ---- phase 3: i23 x j01 ----
    stB1((t + 2) & (NT - 1), buf, 1);
    __builtin_amdgcn_s_barrier();
    __builtin_amdgcn_s_setprio(1);
#pragma unroll
    for (int i = 0; i < 2; i++)
#pragma unroll
      for (int j = 0; j < 2; j++)
#pragma unroll
        for (int s = 0; s < 2; s++)
          acc[2 + i][j] = __builtin_amdgcn_mfma_f32_16x16x32_bf16(af[i][s], bf0[j][s], acc[2 + i][j], 0, 0, 0);
    __builtin_amdgcn_s_setprio(0);
    asm volatile("s_waitcnt vmcnt(2)" ::: "memory");
    __builtin_amdgcn_s_barrier();
  }

  asm volatile("s_waitcnt vmcnt(0)" ::: "memory");

  float* P = blockIdx.z ? P1 : P0;
#pragma unroll
  for (int i = 0; i < 4; i++) {
#pragma unroll
    for (int j = 0; j < 4; j++) {
#pragma unroll
      for (int r = 0; r < 4; r++) {
        int row = m0 + wm * 64 + i * 16 + quad * 4 + r;
        int col = n0 + wn * 64 + j * 16 + l16;
        P[(size_t)row * D + col] = acc[i][j][r];
      }
    }
  }
}

// ---------------------------------------------------------------------------
// 128x64-tile GEMM (N=1024 matmuls), BK=64, 8x8 L2 swizzle.
// Waves 2x2; each wave 64(m) x 32(n) -> acc[4][2], 16 MFMA per stage.
// ---------------------------------------------------------------------------
template<typename TC>
__global__ __launch_bounds__(256) void gemm_bt_n64(
    const u16* __restrict__ A, const u16* __restrict__ BT,
    const float* __restrict__ bias, TC* __restrict__ C,
    int N, int K)
{
  __shared__ __align__(16) u16 As[2][128 * 32];
  __shared__ __align__(16) u16 Bs[2][64 * 32];
  const int tid = threadIdx.x;
  const int wave = tid >> 6, lane = tid & 63;
  const int quad = lane >> 4, l16 = lane & 15;
  int bx, by; swizzle8(bx, by);
  const int m0 = by * 128, n0 = bx * 64;
  const int wm = (wave >> 1) * 64, wn = (wave & 1) * 32;
  const int srow = lane >> 2;
  const int skoff = (lane & 3) * 8;

  f32x4 acc[4][2] = {};

  for (int k0 = 0; k0 < K; k0 += 64) {
#pragma unroll
    for (int h = 0; h < 2; h++) {
#pragma unroll
      for (int t = 0; t < 2; t++) {
        int slot = wave * 2 + t;
        int row = slot * 16 + srow;
        async_cp16(A + (size_t)(m0 + row) * K + k0 + h * 32 + skoff, As[h] + slot * 512);
      }
      int row = wave * 16 + srow;
      async_cp16(BT + (size_t)(n0 + row) * K + k0 + h * 32 + skoff, Bs[h] + wave * 512);
    }
    __syncthreads();

#pragma unroll
    for (int h = 0; h < 2; h++) {
      bf16x8 af[4], bfv[2];
#pragma unroll
      for (int i = 0; i < 4; i++)
        af[i] = *(const bf16x8*)(As[h] + (wm + i * 16 + l16) * 32 + quad * 8);
#pragma unroll
      for (int j = 0; j < 2; j++)
        bfv[j] = *(const bf16x8*)(Bs[h] + (wn + j * 16 + l16) * 32 + quad * 8);
#pragma unroll
      for (int i = 0; i < 4; i++)
#pragma unroll
        for (int j = 0; j < 2; j++)
          acc[i][j] = __builtin_amdgcn_mfma_f32_16x16x32_bf16(af[i], bfv[j], acc[i][j], 0, 0, 0);
    }
    __syncthreads();
  }

#pragma unroll
  for (int i = 0; i < 4; i++) {
#pragma unroll
    for (int j = 0; j < 2; j++) {
#pragma unroll
      for (int r = 0; r < 4; r++) {
        int row = m0 + wm + i * 16 + quad * 4 + r;
        int col = n0 + wn + j * 16 + l16;
        stv(C, (size_t)row * N + col, acc[i][j][r] + bias[col]);
      }
    }
  }
}

// ---------------------------------------------------------------------------
// V transpose: (BH, S, W) -> (BH, W, S), 64x64 tiles via LDS.
// ---------------------------------------------------------------------------
__global__ __launch_bounds__(256) void transpose_v_kernel(
    const u16* __restrict__ v, u16* __restrict__ vt)
{
  __shared__ __align__(16) u16 T[64][72];
  const int bh = blockIdx.y, k0 = blockIdx.x * 64, tid = threadIdx.x;
#pragma unroll
  for (int it = 0; it < 2; it++) {
    int vv = tid + it * 256;
    int key = vv >> 3, w0 = (vv & 7) * 8;
    union { uint4 q; u16 e[8]; } u;
    u.q = *(const uint4*)(v + ((size_t)bh * S + k0 + key) * W + w0);
#pragma unroll
    for (int j = 0; j < 8; j++) T[w0 + j][key] = u.e[j];
  }
  __syncthreads();
#pragma unroll
  for (int it = 0; it < 2; it++) {
    int vv = tid + it * 256;
    int w = vv >> 3, koff = (vv & 7) * 8;
    *(uint4*)(vt + ((size_t)bh * W + w) * S + k0 + koff) = *(const uint4*)(&T[w][koff]);
  }
}

// ---------------------------------------------------------------------------
// Flash attention (MFMA). QBLK=128 (4 waves x 32 q-rows), swapped QK^T,
// ballot mask, b64 P-stores, key-split 2-way, XOR-swizzled LDS.
// ---------------------------------------------------------------------------
__global__ __launch_bounds__(256) void fattn_kernel(
    const u16* __restrict__ q, const u16* __restrict__ k,
    const u16* __restrict__ vt, const int* __restrict__ mask,
    u16* __restrict__ o_parts, float* __restrict__ l_parts)
{
  __shared__ __align__(16) u16 QP[2][128][32];  // Q staging, then P tiles
  __shared__ __align__(16) u16 Kl[2][64][32];   // K tile [key][w]
  __shared__ __align__(16) u16 Vl[2][64][32];   // V^T tile [w][key]

  const int tid = threadIdx.x, wave = tid >> 6, lane = tid & 63;
  const int quad = lane >> 4, l16 = lane & 15;
  const int bh = blockIdx.y, b = bh >> 4, h = bh & 15;
  const int q0 = blockIdx.x * 128;
  const int half = blockIdx.z;
  const int kbase = half * (S / 2);             // first key of this half
  const int wq0 = wave * 32;                    // wave's 32 q-rows
  const int sr  = tid >> 3;              // 0..31
  const int sg  = tid & 7;               // chunk along W: 0..7
  const int sp  = sg >> 2;               // plane (cols 0-31 / 32-63)
  const int sc0 = sg * 8;                // global col (u16 units)
  const int ssw = (((sg & 3) ^ ((sr >> 1) & 3)) << 3);
  const int xr = (l16 >> 1) & 3;
  const int rq = ((quad ^ xr) << 3);

  // stage Q tile 128x64 (swizzled)
#pragma unroll
  for (int t = 0; t < 4; t++) {
    int row = sr + t * 32;
    *(uint4*)(&QP[sp][row][ssw]) =
        *(const uint4*)(q + ((size_t)bh * S + q0 + row) * W + sc0);
  }
  __syncthreads();
  bf16x8 aq[2][2];
#pragma unroll
  for (int g = 0; g < 2; g++)
#pragma unroll
    for (int kc = 0; kc < 2; kc++)
      aq[g][kc] = *(const bf16x8*)(&QP[kc][wq0 + g * 16 + l16][rq]);

  bf16x8 ones;
  {
    u16 ov = (l16 == 0) ? (u16)0x3F80 : (u16)0;
#pragma unroll
    for (int j = 0; j < 8; j++) ones[j] = u2b(ov);
  }

  f32x4 o_acc[2][4] = {};
  f32x4 l_acc[2] = {};

  uint4 kr0, kr1, vr0, vr1;
  int mv;
  kr0 = *(const uint4*)(k  + ((size_t)bh * S + kbase + sr     ) * W + sc0);
  kr1 = *(const uint4*)(k  + ((size_t)bh * S + kbase + sr + 32) * W + sc0);
  vr0 = *(const uint4*)(vt + ((size_t)bh * W + sr     ) * S + kbase + sc0);
  vr1 = *(const uint4*)(vt + ((size_t)bh * W + sr + 32) * S + kbase + sc0);
  mv  = mask[b * S + kbase + lane];

  constexpr int NT = S / 128;   // 16 key tiles per half
  for (int kt = 0; kt < NT; kt++) {
    __syncthreads();
    *(uint4*)(&Kl[sp][sr     ][ssw]) = kr0;
    *(uint4*)(&Kl[sp][sr + 32][ssw]) = kr1;
    *(uint4*)(&Vl[sp][sr     ][ssw]) = vr0;
    *(uint4*)(&Vl[sp][sr + 32][ssw]) = vr1;
    u64 km = __ballot(mv != 0);
    __syncthreads();

    if (kt + 1 < NT) {
      int kn = kbase + (kt + 1) * 64;
      kr0 = *(const uint4*)(k  + ((size_t)bh * S + kn + sr     ) * W + sc0);
      kr1 = *(const uint4*)(k  + ((size_t)bh * S + kn + sr + 32) * W + sc0);
      vr0 = *(const uint4*)(vt + ((size_t)bh * W + sr     ) * S + kn + sc0);
      vr1 = *(const uint4*)(vt + ((size_t)bh * W + sr + 32) * S + kn + sc0);
      mv  = mask[b * S + kn + lane];
    }

#pragma unroll
    for (int tn = 0; tn < 4; tn++) {
      bf16x8 bk0 = *(const bf16x8*)(&Kl[0][tn * 16 + l16][rq]);
      bf16x8 bk1 = *(const bf16x8*)(&Kl[1][tn * 16 + l16][rq]);
      u32 nib = (u32)(km >> (tn * 16 + quad * 4)) & 0xFu;
      int slotp = (((tn & 1) * 2 + (quad >> 1)) ^ xr) * 8 + (quad & 1) * 4;
#pragma unroll
      for (int g = 0; g < 2; g++) {
        f32x4 s4 = {};
        s4 = __builtin_amdgcn_mfma_f32_16x16x32_bf16(bk0, aq[g][0], s4, 0, 0, 0);
        s4 = __builtin_amdgcn_mfma_f32_16x16x32_bf16(bk1, aq[g][1], s4, 0, 0, 0);
        union { u64 u; u16 e[4]; } pw;
#pragma unroll
        for (int r = 0; r < 4; r++) {
          float pm = (float)((nib >> r) & 1u);
          pw.e[r] = f2bf_cvt(__expf(s4[r]) * pm);
        }
        *(u64*)(&QP[tn >> 1][wq0 + g * 16 + l16][slotp]) = pw.u;
      }
    }

#pragma unroll
    for (int kc = 0; kc < 2; kc++) {
      bf16x8 ap0 = *(const bf16x8*)(&QP[kc][wq0      + l16][rq]);
      bf16x8 ap1 = *(const bf16x8*)(&QP[kc][wq0 + 16 + l16][rq]);
#pragma unroll
      for (int tn = 0; tn < 4; tn++) {
        bf16x8 bv = *(const bf16x8*)(&Vl[kc][tn * 16 + l16][rq]);
        o_acc[0][tn] = __builtin_amdgcn_mfma_f32_16x16x32_bf16(ap0, bv, o_acc[0][tn], 0, 0, 0);
        o_acc[1][tn] = __builtin_amdgcn_mfma_f32_16x16x32_bf16(ap1, bv, o_acc[1][tn], 0, 0, 0);
      }
      l_acc[0] = __builtin_amdgcn_mfma_f32_16x16x32_bf16(ap0, ones, l_acc[0], 0, 0, 0);
      l_acc[1] = __builtin_amdgcn_mfma_f32_16x16x32_bf16(ap1, ones, l_acc[1], 0, 0, 0);
    }
  }

  u16* ob = o_parts + (size_t)half * M * D;
  float* lb = l_parts + (size_t)half * M * H;
#pragma unroll
  for (int g = 0; g < 2; g++) {
#pragma unroll
    for (int r = 0; r < 4; r++) {
      float lsum = __shfl(l_acc[g][r], lane & 0x30);
      int sg2 = q0 + wq0 + g * 16 + quad * 4 + r;
      if (l16 == 0) lb[((size_t)b * S + sg2) * H + h] = lsum;
#pragma unroll
      for (int tn = 0; tn < 4; tn++) {
        ob[((size_t)b * S + sg2) * D + h * W + tn * 16 + l16] = f2bf_cvt(o_acc[g][tn][r]);
      }
    }
  }
}

// ---------------------------------------------------------------------------
// Combine key-split partials: attn = (o0 + o1) / (l0 + l1). In-place on
// half 0 (same-address elementwise -> race-free).
// ---------------------------------------------------------------------------
__global__ __launch_bounds__(256) void combine_attn(
    const u16* __restrict__ o_parts, const float* __restrict__ l_parts,
    u16* __restrict__ attn)
{
  size_t idx = ((size_t)blockIdx.x * 256 + threadIdx.x) * 8;
  int row = (int)(idx >> 10);          // (b*S+s)
  int h = ((int)idx >> 6) & 15;        // head (8 elems stay in one head)
  float l = l_parts[(size_t)row * H + h] + l_parts[(size_t)M * H + (size_t)row * H + h];
  float inv = 1.0f / l;
  union { uint4 v; u16 e[8]; } a, bq, o;
  a.v  = *(const uint4*)(o_parts + idx);
  bq.v = *(const uint4*)(o_parts + (size_t)M * D + idx);
#pragma unroll
  for (int j = 0; j < 8; j++)
    o.e[j] = f2bf((bf2f(a.e[j]) + bf2f(bq.e[j])) * inv);
  *(uint4*)(attn + idx) = o.v;
}

// ---------------------------------------------------------------------------
// Fused residual + LayerNorm, one WAVE per row (no block barriers).
// grid = M/4 blocks of 256 threads.
// ---------------------------------------------------------------------------
template<typename TA, typename TR, typename TO>
__global__ __launch_bounds__(256) void ln_res_kernel(
    const TA* __restrict__ a, const TR* __restrict__ r,
    const float* __restrict__ g, const float* __restrict__ be,
    TO* __restrict__ out)
{
  const int tid = threadIdx.x, lane = tid & 63;
  const int row = blockIdx.x * 4 + (tid >> 6);
  const TA* ap = a + (size_t)row * D;
  const TR* rp = r + (size_t)row * D;
  float hv[16];
  float s = 0.f;
#pragma unroll
  for (int c = 0; c < 16; c++) {
    int d = c * 64 + lane;
    hv[c] = ldv(ap, d) + ldv(rp, d);
    s += hv[c];
  }
#pragma unroll
  for (int d = 1; d < 64; d <<= 1) s += __shfl_xor(s, d);
  float mean = s * (1.0f / D);
  float v = 0.f;
#pragma unroll
  for (int c = 0; c < 16; c++) { float t = hv[c] - mean; v += t * t; }
#pragma unroll
  for (int d = 1; d < 64; d <<= 1) v += __shfl_xor(v, d);
  float inv = rsqrtf(v * (1.0f / D) + 1e-12f);
#pragma unroll
  for (int c = 0; c < 16; c++) {
    int d = c * 64 + lane;
    stv(out, (size_t)row * D + d, g[d] * ((hv[c] - mean) * inv) + be[d]);
  }
}

// ---------------------------------------------------------------------------
// LN2 with split-K FFN2 partials: out = LN(a + p0 + p1 + bias). In-place
// safe when out == p0 (per-thread same-address read/write).
// ---------------------------------------------------------------------------
__global__ __launch_bounds__(256) void ln_res3_kernel(
    const u16* __restrict__ a, const float* __restrict__ p0,
    const float* __restrict__ p1, const float* __restrict__ bias,
    const float* __restrict__ g, const float* __restrict__ be,
    float* __restrict__ out)
{
  const int tid = threadIdx.x, lane = tid & 63;
  const int row = blockIdx.x * 4 + (tid >> 6);
  const u16* ap = a + (size_t)row * D;
  const float* q0 = p0 + (size_t)row * D;
  const float* q1 = p1 + (size_t)row * D;
  float hv[16];
  float s = 0.f;
#pragma unroll
  for (int c = 0; c < 16; c++) {
    int d = c * 64 + lane;
    hv[c] = bf2f(ap[d]) + q0[d] + q1[d] + bias[d];
    s += hv[c];
  }
#pragma unroll
  for (int d = 1; d < 64; d <<= 1) s += __shfl_xor(s, d);
  float mean = s * (1.0f / D);
  float v = 0.f;
#pragma unroll
  for (int c = 0; c < 16; c++) { float t = hv[c] - mean; v += t * t; }
#pragma unroll
  for (int d = 1; d < 64; d <<= 1) v += __shfl_xor(v, d);
  float inv = rsqrtf(v * (1.0f / D) + 1e-12f);
#pragma unroll
  for (int c = 0; c < 16; c++) {
    int d = c * 64 + lane;
    out[(size_t)row * D + d] = g[d] * ((hv[c] - mean) * inv) + be[d];
  }
}

// ---------------------------------------------------------------------------
extern "C" void kernel_launch(void* const* d_in, const int* in_sizes, int n_in,
                              void* d_out, int out_size, void* d_ws, size_t ws_size,
                              hipStream_t stream)
{
  const float* x  = (const float*)d_in[0];
  const int* mask = (const int*)d_in[1];
  const float* wq = (const float*)d_in[2];  const float* bq  = (const float*)d_in[3];
  const float* wk = (const float*)d_in[4];  const float* bk  = (const float*)d_in[5];
  const float* wv = (const float*)d_in[6];  const float* bv  = (const float*)d_in[7];
  const float* wo = (const float*)d_in[8];  const float* bo  = (const float*)d_in[9];
  const float* g1 = (const float*)d_in[10]; const float* b1  = (const float*)d_in[11];
  const float* w1 = (const float*)d_in[12]; const float* bf1 = (const float*)d_in[13];
  const float* w2 = (const float*)d_in[14]; const float* bf2 = (const float*)d_in[15];
  const float* g2 = (const float*)d_in[16]; const float* b2  = (const float*)d_in[17];

  // ws layout (base 48 MB; split-K FFN2 uses [48,64M) when available):
  //  A [0,8M):   wqkvT(6M)+woT(2M); wqkvT dead after QKV -> l_parts(512KB)
  //              lives at [0,0.5M) during fattn; then w1T(8M) -> w2T(8M)
  //  B [8,16M):  xb -> vt -> ff1[0:8M)
  //  C [16,24M): q  -> proj -> ff1[8:16M)
  //  D [24,32M): k  -> ff1[16:24M)
  //  E [32,48M): v(8M, dead after transpose_v) -> o_parts(16M); combine
  //              writes attn in-place over half 0 ([32,40M)) -> ff1[24:32M)
  //  F [40,48M): bqkv(12KB, dead by fattn) -> o_parts half1 -> h1
  //  G [48,64M): FFN2 split-K partial1 (fp32, 16M) -- only if ws_size allows
  //  ff2 partial0 -> d_out; LN2 in place on d_out.
  char* ws = (char*)d_ws;
  const size_t MB = 1024 * 1024;
  u16* wqkvT = (u16*)(ws + 0 * MB);          // (3072, 1024) bf16
  u16* woT   = (u16*)(ws + 6 * MB);          // (1024, 1024)
  u16* w1T   = (u16*)(ws + 0 * MB);          // (4096, 1024) after proj
  u16* w2T   = (u16*)(ws + 0 * MB);          // (1024, 4096) after ffn1
  u16* xb    = (u16*)(ws + 8 * MB);
  u16* vt    = (u16*)(ws + 8 * MB);
  u16* q     = (u16*)(ws + 16 * MB);
  u16* proj  = (u16*)(ws + 16 * MB);
  u16* kb    = (u16*)(ws + 24 * MB);
  u16* vb    = (u16*)(ws + 32 * MB);
  u16* oparts = (u16*)(ws + 32 * MB);        // 16 MB: 2 x (M,D) bf16 partials
  float* lparts = (float*)(ws + 0 * MB);     // 512 KB: 2 x (M,H) f32
  u16* attn  = (u16*)(ws + 32 * MB);         // combine output (aliases half0)
  u16* ff1   = (u16*)(ws + 8 * MB);          // 32 MB: [8,40)
  float* bqkv = (float*)(ws + 40 * MB);      // 12 KB
  u16* h1    = (u16*)(ws + 40 * MB);
  float* part1 = (float*)(ws + 48 * MB);     // 16 MB (gated on ws_size)
  float* out = (float*)d_out;

  const bool bigws = ws_size >= (size_t)64 * MB;

  dim3 blk(256);

  // prep: x -> bf16; weights -> bf16 transposed; bias concat
  conv_x_kernel<<<dim3(M * D / 1024), blk, 0, stream>>>(x, xb);
  transpose_w_kernel<<<dim3(16, 16), blk, 0, stream>>>(wq, wqkvT,            D, D);
  transpose_w_kernel<<<dim3(16, 16), blk, 0, stream>>>(wk, wqkvT + 1024*1024, D, D);
  transpose_w_kernel<<<dim3(16, 16), blk, 0, stream>>>(wv, wqkvT + 2048*1024, D, D);
  transpose_w_kernel<<<dim3(16, 16), blk, 0, stream>>>(wo, woT,              D, D);
  hipMemcpyAsync(bqkv,        bq, D * sizeof(float), hipMemcpyDeviceToDevice, stream);
  hipMemcpyAsync(bqkv + 1024, bk, D * sizeof(float), hipMemcpyDeviceToDevice, stream);
  hipMemcpyAsync(bqkv + 2048, bv, D * sizeof(float), hipMemcpyDeviceToDevice, stream);

  // fused QKV GEMM: (M,1024) @ (1024,3072) -> q,k,v permuted (q scaled)
  gemm_bt<2, u16><<<dim3(3072 / 128, M / 128), blk, 0, stream>>>(
      xb, wqkvT, bqkv, q, 3072, D, 0.125f);

  transpose_v_kernel<<<dim3(S / 64, Bb * H), blk, 0, stream>>>(vb, vt);
  // key-split flash attention: QBLK=128, 1024 blocks, partials
  fattn_kernel<<<dim3(S / 128, Bb * H, 2), blk, 0, stream>>>(
      q, kb, vt, mask, oparts, lparts);
  combine_attn<<<dim3(M * D / 2048), blk, 0, stream>>>(oparts, lparts, attn);

  // proj: N=1024 -> 128x64 tiles (512 blocks, 2/CU)
  gemm_bt_n64<u16><<<dim3(D / 64, M / 128), blk, 0, stream>>>(
      attn, woT, bo, proj, D, D);
  ln_res_kernel<float, u16, u16><<<dim3(M / 4), blk, 0, stream>>>(x, proj, g1, b1, h1);

  transpose_w_kernel<<<dim3(F / 64, D / 64), blk, 0, stream>>>(w1, w1T, D, F);
  // FFN1: 256^2 8-phase GEMM (T2+T3+T4+T5), 256 blocks of 512 thr = 1/CU
  gemm256_gelu<<<dim3(F / 256, M / 256), dim3(512), 0, stream>>>(
      h1, w1T, bf1, ff1);

  transpose_w_kernel<<<dim3(D / 64, F / 64), blk, 0, stream>>>(w2, w2T, F, D);
  if (bigws) {
    // FFN2: 256x128-tile 8-phase split-K (256 blocks = 1/CU), fp32 partials;
    // LN2 fuses the combine: out = LN(h1 + p0 + p1 + bf2)
    gemm_ffn2_splitk<<<dim3(D / 128, M / 256, 2), dim3(512), 0, stream>>>(
        ff1, w2T, out, part1);
    ln_res3_kernel<<<dim3(M / 4), blk, 0, stream>>>(h1, out, part1, bf2, g2, b2, out);
  } else {
    // fallback (small workspace): 2-phase 128x64 FFN2 + 2-input LN2
    gemm_bt_n64<float><<<dim3(D / 64, M / 128), blk, 0, stream>>>(
        ff1, w2T, bf2, out, D, F);
    ln_res_kernel<u16, float, float><<<dim3(M / 4), blk, 0, stream>>>(h1, out, g2, b2, out);
  }
}

// Round 6
// 390.910 us; speedup vs baseline: 1.1022x; 1.0264x over previous
//
#include <hip/hip_runtime.h>
#include <cstdint>
#include <cstddef>

using u16 = unsigned short;
using u32 = unsigned int;
using u64 = unsigned long long;

typedef __bf16 bf16x8 __attribute__((ext_vector_type(8)));
typedef float f32x4 __attribute__((ext_vector_type(4)));

static constexpr int Bb = 2, S = 2048, D = 1024, H = 16, W = 64, F = 4096;
static constexpr int M = Bb * S;   // 4096 rows

__device__ __forceinline__ float bf2f(u16 u) {
  union { u32 i; float f; } c; c.i = ((u32)u) << 16; return c.f;
}
__device__ __forceinline__ u16 f2bf(float f) {
  union { float f; u32 i; } c; c.f = f;
  u32 i = c.i;
  u32 r = (i + 0x7fffu + ((i >> 16) & 1u)) >> 16;
  return (u16)r;
}
__device__ __forceinline__ u16 f2bf_cvt(float f) {
  __bf16 b = (__bf16)f;
  union { __bf16 b; u16 u; } c; c.b = b; return c.u;
}
__device__ __forceinline__ __bf16 u2b(u16 x) {
  union { u16 u; __bf16 b; } c; c.u = x; return c.b;
}
__device__ __forceinline__ void stv(float* p, size_t i, float v) { p[i] = v; }
__device__ __forceinline__ void stv(u16* p, size_t i, float v)   { p[i] = f2bf(v); }
__device__ __forceinline__ float ldv(const float* p, size_t i) { return p[i]; }
__device__ __forceinline__ float ldv(const u16* p, size_t i)   { return bf2f(p[i]); }

__device__ __forceinline__ void async_cp16(const u16* g, u16* l) {
  __builtin_amdgcn_global_load_lds(
      (const __attribute__((address_space(1))) void*)g,
      (__attribute__((address_space(3))) void*)l, 16, 0, 0);
}

// 8x8 super-tile block swizzle for L2 locality. Requires gridDim.x%8==0,
// gridDim.y%8==0. 64 consecutive blocks -> 8 A-tiles + 8 B-tiles (~4MB).
__device__ __forceinline__ void swizzle8(int& bx, int& by) {
  int bid = blockIdx.y * gridDim.x + blockIdx.x;
  int gpr = gridDim.x >> 3;
  int grp = bid >> 6, rem = bid & 63;
  int gm = grp / gpr, gn = grp - gm * gpr;
  by = gm * 8 + (rem >> 3);
  bx = gn * 8 + (rem & 7);
}

// ---------------------------------------------------------------------------
// fp32 -> bf16 elementwise convert (n % 1024 == 0)
// ---------------------------------------------------------------------------
__global__ __launch_bounds__(256) void conv_x_kernel(
    const float* __restrict__ src, u16* __restrict__ dst)
{
  int i = (blockIdx.x * 256 + threadIdx.x) * 4;
  float4 v = *(const float4*)(src + i);
  u16 r[4] = { f2bf(v.x), f2bf(v.y), f2bf(v.z), f2bf(v.w) };
  *(uint2*)(dst + i) = *(const uint2*)r;
}

// ---------------------------------------------------------------------------
// Weight transpose+convert: src (K,N) fp32 -> dst (N,K) bf16. 64x64 tiles.
// ---------------------------------------------------------------------------
__global__ __launch_bounds__(256) void transpose_w_kernel(
    const float* __restrict__ src, u16* __restrict__ dst, int K, int N)
{
  __shared__ __align__(16) u16 T[64][72];
  const int tid = threadIdx.x;
  const int n0 = blockIdx.x * 64, k0 = blockIdx.y * 64;
#pragma unroll
  for (int t = 0; t < 4; t++) {
    int idx = tid + t * 256;           // 0..1023 float4s
    int r = idx >> 4, c4 = (idx & 15) * 4;
    float4 v = *(const float4*)(src + (size_t)(k0 + r) * N + n0 + c4);
    T[c4 + 0][r] = f2bf(v.x); T[c4 + 1][r] = f2bf(v.y);
    T[c4 + 2][r] = f2bf(v.z); T[c4 + 3][r] = f2bf(v.w);
  }
  __syncthreads();
#pragma unroll
  for (int t = 0; t < 2; t++) {
    int idx = tid + t * 256;           // 0..511 uint4s
    int r = idx >> 3, c8 = (idx & 7) * 8;
    *(uint4*)(dst + (size_t)(n0 + r) * K + k0 + c8) = *(const uint4*)(&T[r][c8]);
  }
}

// ---------------------------------------------------------------------------
// 256x256-tile 8-phase GEMM template (HK-style schedule, plain HIP).
// C = epi(A(M,GK) @ BT(GN,GK)^T + bias), bf16 out. NT = GK/64 K-tiles.
// 512 threads = 8 waves (2m x 4n); per-wave 128x64 out = 8x4 16x16 frags.
// LDS 128 KB: A,B each [2 dbuf][2 half][128 rows][64 k] bf16.
// T2 swizzle (rule #21, both-sides): 16B slot' = slot ^ (row&7), realized by
// pre-swizzling the GLOBAL source (linear global_load_lds dest) and XORing
// the ds_read byte col.
// Schedule per K-tile t (buf = t&1), 4 phases, each:
//   {ds-reads; stage-issue; s_barrier; setprio(1); 16 MFMA; setprio(0);
//    [s_waitcnt vmcnt(4) @p3]; s_barrier}
//  p0: Q(mh0,nh0) read A[mh0](8 b128) B[nh0](4); stage A(t+1)->buf^1 (4 iss)
//  p1: Q(mh0,nh1) read B[nh1](4)
//  p2: Q(mh1,nh1) read A[mh1](8);               stage Bh0(t+2)->buf (2 iss)
//  p3: Q(mh1,nh0) regs only;                    stage Bh1(t+2)->buf (2 iss)
// Ledger: A(T) staged T-1 p0; B(T) staged T-2 p2/p3. Boundary vmcnt(4)
// leaves only B(t+2)'s 4 issues in flight. Prologue 12 issues + vmcnt(4).
// EPI: 1 = exact gelu -> C[row*GN+col]; 2 = qkv permute (sel/c, q scaled).
// SWZ: use swizzle8 (requires gridDim.x%8==0) else identity mapping.
// ---------------------------------------------------------------------------
template<int GN, int GK, int EPI, bool SWZ>
__global__ __launch_bounds__(512, 2) void gemm256(
    const u16* __restrict__ A, const u16* __restrict__ BT,
    const float* __restrict__ bias, u16* __restrict__ C, float scale)
{
  constexpr int NT = GK / 64;
  __shared__ __align__(16) u16 AL[2][2][128 * 64];
  __shared__ __align__(16) u16 BL[2][2][128 * 64];
  const int tid = threadIdx.x;
  const int wave = tid >> 6, lane = tid & 63;
  const int quad = lane >> 4, l16 = lane & 15;
  const int wm = wave >> 2, wn = wave & 3;
  int bx, by;
  if (SWZ) { swizzle8(bx, by); } else { bx = blockIdx.x; by = blockIdx.y; }
  const int m0 = by * 256, n0 = bx * 256;
  const int lr = lane >> 3;
  const int kc8 = ((lane & 7) ^ lr) * 8;          // u16 units
  const int xb = (l16 & 7) * 16;
  const int brow0 = (wn & 1) * 64;                // B row base within half
  const char* abase = (const char*)&AL[0][wm][0];
  const char* bbase = (const char*)&BL[0][wn >> 1][0];
  constexpr int BUFB = 2 * 128 * 64 * 2;          // byte stride AL[1]-AL[0]

  f32x4 acc[8][4] = {};

  auto stA = [&](int t, int buf) {                // A(t) both halves, 4 issues
#pragma unroll
    for (int half = 0; half < 2; half++)
#pragma unroll
      for (int j = 0; j < 2; j++) {
        const u16* g = A + (size_t)(m0 + half * 128 + (j * 8 + wave) * 8 + lr) * GK
                         + t * 64 + kc8;
        async_cp16(g, &AL[buf][half][(j * 8 + wave) * 512]);
      }
  };
  auto stB = [&](int t, int buf, int half) {      // B(t) one half, 2 issues
#pragma unroll
    for (int j = 0; j < 2; j++) {
      const u16* g = BT + (size_t)(n0 + half * 128 + (j * 8 + wave) * 8 + lr) * GK
                        + t * 64 + kc8;
      async_cp16(g, &BL[buf][half][(j * 8 + wave) * 512]);
    }
  };

  stA(0, 0);
  stB(0, 0, 0); stB(0, 0, 1);
  stB(1, 1, 0); stB(1, 1, 1);
  asm volatile("s_waitcnt vmcnt(4)" ::: "memory");
  __builtin_amdgcn_s_barrier();

  bf16x8 af[4][2], bf0[2][2], bf1v[2][2];

#pragma unroll 2
  for (int t = 0; t < NT; t++) {
    const int buf = t & 1;
    const char* ab = abase + buf * BUFB;
    const char* bb = bbase + buf * BUFB;

    // ---- phase 0: Q(0,0) ----
#pragma unroll
    for (int i = 0; i < 4; i++)
#pragma unroll
      for (int s = 0; s < 2; s++)
        af[i][s] = *(const bf16x8*)(ab + (i * 16 + l16) * 128 + (((s * 4 + quad) * 16) ^ xb));
#pragma unroll
    for (int j = 0; j < 2; j++)
#pragma unroll
      for (int s = 0; s < 2; s++)
        bf0[j][s] = *(const bf16x8*)(bb + (brow0 + j * 16 + l16) * 128 + (((s * 4 + quad) * 16) ^ xb));
    stA((t + 1) & (NT - 1), buf ^ 1);
    __builtin_amdgcn_s_barrier();
    __builtin_amdgcn_s_setprio(1);
#pragma unroll
    for (int i = 0; i < 4; i++)
#pragma unroll
      for (int j = 0; j < 2; j++)
#pragma unroll
        for (int s = 0; s < 2; s++)
          acc[i][j] = __builtin_amdgcn_mfma_f32_16x16x32_bf16(af[i][s], bf0[j][s], acc[i][j], 0, 0, 0);
    __builtin_amdgcn_s_setprio(0);
    __builtin_amdgcn_s_barrier();

    // ---- phase 1: Q(0,1) ----
#pragma unroll
    for (int j = 0; j < 2; j++)
#pragma unroll
      for (int s = 0; s < 2; s++)
        bf1v[j][s] = *(const bf16x8*)(bb + (brow0 + 32 + j * 16 + l16) * 128 + (((s * 4 + quad) * 16) ^ xb));
    __builtin_amdgcn_s_barrier();
    __builtin_amdgcn_s_setprio(1);
#pragma unroll
    for (int i = 0; i < 4; i++)
#pragma unroll
      for (int j = 0; j < 2; j++)
#pragma unroll
        for (int s = 0; s < 2; s++)
          acc[i][2 + j] = __builtin_amdgcn_mfma_f32_16x16x32_bf16(af[i][s], bf1v[j][s], acc[i][2 + j], 0, 0, 0);
    __builtin_amdgcn_s_setprio(0);
    __builtin_amdgcn_s_barrier();

    // ---- phase 2: Q(1,1) ----
#pragma unroll
    for (int i = 0; i < 4; i++)
#pragma unroll
      for (int s = 0; s < 2; s++)
        af[i][s] = *(const bf16x8*)(ab + (64 + i * 16 + l16) * 128 + (((s * 4 + quad) * 16) ^ xb));
    stB((t + 2) & (NT - 1), buf, 0);
    __builtin_amdgcn_s_barrier();
    __builtin_amdgcn_s_setprio(1);
#pragma unroll
    for (int i = 0; i < 4; i++)
#pragma unroll
      for (int j = 0; j < 2; j++)
#pragma unroll
        for (int s = 0; s < 2; s++)
          acc[4 + i][2 + j] = __builtin_amdgcn_mfma_f32_16x16x32_bf16(af[i][s], bf1v[j][s], acc[4 + i][2 + j], 0, 0, 0);
    __builtin_amdgcn_s_setprio(0);
    __builtin_amdgcn_s_barrier();

    // ---- phase 3: Q(1,0) ----
    stB((t + 2) & (NT - 1), buf, 1);
    __builtin_amdgcn_s_barrier();
    __builtin_amdgcn_s_setprio(1);
#pragma unroll
    for (int i = 0; i < 4; i++)
#pragma unroll
      for (int j = 0; j < 2; j++)
#pragma unroll
        for (int s = 0; s < 2; s++)
          acc[4 + i][j] = __builtin_amdgcn_mfma_f32_16x16x32_bf16(af[i][s], bf0[j][s], acc[4 + i][j], 0, 0, 0);
    __builtin_amdgcn_s_setprio(0);
    asm volatile("s_waitcnt vmcnt(4)" ::: "memory");
    __builtin_amdgcn_s_barrier();
  }

  asm volatile("s_waitcnt vmcnt(0)" ::: "memory");

  // epilogue
#pragma unroll
  for (int i = 0; i < 8; i++) {
#pragma unroll
    for (int j = 0; j < 4; j++) {
#pragma unroll
      for (int r = 0; r < 4; r++) {
        int row = m0 + wm * 128 + i * 16 + quad * 4 + r;
        int col = n0 + wn * 64 + j * 16 + l16;
        float val = acc[i][j][r] + bias[col];
        if (EPI == 1) {
          val = 0.5f * val * (1.0f + erff(val * 0.70710678118654752f));
          C[(size_t)row * GN + col] = f2bf(val);
        } else {  // EPI == 2: fused qkv permute, scale on q
          int sel = col >> 10, c = col & 1023;       // D = 1024
          if (sel == 0) val *= scale;
          int bb2 = row >> 11, ss = row & 2047;      // S = 2048
          int hh = c >> 6,  ww = c & 63;             // W = 64
          u16* dst = C + (size_t)sel * M * D;
          dst[(((size_t)(bb2 * H + hh) * S) + ss) * W + ww] = f2bf(val);
        }
      }
    }
  }
}

// ---------------------------------------------------------------------------
// FFN2 256x128-tile 8-phase split-K GEMM. Grid (D/128, M/256, 2) = 256
// blocks (1/CU). See round-5 comments for the phase/vmcnt ledger.
// ---------------------------------------------------------------------------
__global__ __launch_bounds__(512, 2) void gemm_ffn2_splitk(
    const u16* __restrict__ A, const u16* __restrict__ BT,
    float* __restrict__ P0, float* __restrict__ P1)
{
  constexpr int GK = F, NT = 32;
  __shared__ __align__(16) u16 AL[2][2][128 * 64];   // 64 KB
  __shared__ __align__(16) u16 BL[2][128 * 64];      // 32 KB
  const int tid = threadIdx.x;
  const int wave = tid >> 6, lane = tid & 63;
  const int quad = lane >> 4, l16 = lane & 15;
  const int wm = wave >> 1, wn = wave & 1;           // 4m x 2n
  int bx, by; swizzle8(bx, by);
  const int m0 = by * 256, n0 = bx * 128;
  const int kbase = blockIdx.z * (F / 2);
  const int lr = lane >> 3;
  const int kc8 = ((lane & 7) ^ lr) * 8;             // u16 units
  const int xb = (l16 & 7) * 16;
  const int arow0 = (wm & 1) * 64;                   // row base within mhalf
  const int brow0 = wn * 64;
  const char* abase = (const char*)&AL[0][wm >> 1][0];
  const char* bbase = (const char*)&BL[0][0];
  constexpr int ABUF = 2 * 128 * 64 * 2;             // AL[1]-AL[0] bytes
  constexpr int BBUF = 128 * 64 * 2;                 // BL[1]-BL[0] bytes

  f32x4 acc[4][4] = {};

  auto stA2 = [&](int t, int buf, int rp) {          // rounds rp*2..rp*2+1
#pragma unroll
    for (int rr = 0; rr < 2; rr++) {
      int rd = rp * 2 + rr;
      const u16* g = A + (size_t)(m0 + rd * 64 + wave * 8 + lr) * GK
                       + kbase + t * 64 + kc8;
      async_cp16(g, &AL[buf][rd >> 1][((rd & 1) * 8 + wave) * 512]);
    }
  };
  auto stB1 = [&](int t, int buf, int rd) {          // one round
    const u16* g = BT + (size_t)(n0 + rd * 64 + wave * 8 + lr) * GK
                      + kbase + t * 64 + kc8;
    async_cp16(g, &BL[buf][(rd * 8 + wave) * 512]);
  };

  // prologue
  stA2(0, 0, 0); stA2(0, 0, 1);
  stB1(0, 0, 0); stB1(0, 0, 1);
  stB1(1, 1, 0); stB1(1, 1, 1);
  asm volatile("s_waitcnt vmcnt(2)" ::: "memory");
  __builtin_amdgcn_s_barrier();

  bf16x8 af[2][2], bf0[2][2], bf1v[2][2];

#pragma unroll 2
  for (int t = 0; t < NT; t++) {
    const int buf = t & 1;
    const char* ab = abase + buf * ABUF;
    const char* bb = bbase + buf * BBUF;

    // ---- phase 0: i01 x j01 ----
#pragma unroll
    for (int i = 0; i < 2; i++)
#pragma unroll
      for (int s = 0; s < 2; s++)
        af[i][s] = *(const bf16x8*)(ab + (arow0 + i * 16 + l16) * 128 + (((s * 4 + quad) * 16) ^ xb));
#pragma unroll
    for (int j = 0; j < 2; j++)
#pragma unroll
      for (int s = 0; s < 2; s++)
        bf0[j][s] = *(const bf16x8*)(bb + (brow0 + j * 16 + l16) * 128 + (((s * 4 + quad) * 16) ^ xb));
    stA2((t + 1) & (NT - 1), buf ^ 1, 0);
    __builtin_amdgcn_s_barrier();
    __builtin_amdgcn_s_setprio(1);
#pragma unroll
    for (int i = 0; i < 2; i++)
#pragma unroll
      for (int j = 0; j < 2; j++)
#pragma unroll
        for (int s = 0; s < 2; s++)
          acc[i][j] = __builtin_amdgcn_mfma_f32_16x16x32_bf16(af[i][s], bf0[j][s], acc[i][j], 0, 0, 0);
    __builtin_amdgcn_s_setprio(0);
    __builtin_amdgcn_s_barrier();

    // ---- phase 1: i01 x j23 ----
#pragma unroll
    for (int j = 0; j < 2; j++)
#pragma unroll
      for (int s = 0; s < 2; s++)
        bf1v[j][s] = *(const bf16x8*)(bb + (brow0 + 32 + j * 16 + l16) * 128 + (((s * 4 + quad) * 16) ^ xb));
    stA2((t + 1) & (NT - 1), buf ^ 1, 1);
    __builtin_amdgcn_s_barrier();
    __builtin_amdgcn_s_setprio(1);
#pragma unroll
    for (int i = 0; i < 2; i++)
#pragma unroll
      for (int j = 0; j < 2; j++)
#pragma unroll
        for (int s = 0; s < 2; s++)
          acc[i][2 + j] = __builtin_amdgcn_mfma_f32_16x16x32_bf16(af[i][s], bf1v[j][s], acc[i][2 + j], 0, 0, 0);
    __builtin_amdgcn_s_setprio(0);
    __builtin_amdgcn_s_barrier();

    // ---- phase 2: i23 x j23 ----
#pragma unroll
    for (int i = 0; i < 2; i++)
#pragma unroll
      for (int s = 0; s < 2; s++)
        af[i][s] = *(const bf16x8*)(ab + (arow0 + 32 + i * 16 + l16) * 128 + (((s * 4 + quad) * 16) ^ xb));
    stB1((t + 2) & (NT - 1), buf, 0);
    __builtin_amdgcn_s_barrier();
    __builtin_amdgcn_s_setprio(1);
#pragma unroll
    for (int i = 0; i < 2; i++)
#pragma unroll
      for (int j = 0; j < 2; j++)
#pragma unroll
        for (int s = 0; s < 2; s++)
          acc[2 + i][2 + j] = __builtin_amdgcn_mfma_f32_16x16x32_bf16(af[i][s], bf1v[j][s], acc[2 + i][2 + j], 0, 0, 0);
    __builtin_amdgcn_s_setprio(0);
    __builtin_amdgcn_s_barrier();

    // ---- phase 3: i23 x j01 ----
    stB1((t + 2) & (NT - 1), buf, 1);
    __builtin_amdgcn_s_barrier();
    __builtin_amdgcn_s_setprio(1);
#pragma unroll
    for (int i = 0; i < 2; i++)
#pragma unroll
      for (int j = 0; j < 2; j++)
#pragma unroll
        for (int s = 0; s < 2; s++)
          acc[2 + i][j] = __builtin_amdgcn_mfma_f32_16x16x32_bf16(af[i][s], bf0[j][s], acc[2 + i][j], 0, 0, 0);
    __builtin_amdgcn_s_setprio(0);
    asm volatile("s_waitcnt vmcnt(2)" ::: "memory");
    __builtin_amdgcn_s_barrier();
  }

  asm volatile("s_waitcnt vmcnt(0)" ::: "memory");

  float* P = blockIdx.z ? P1 : P0;
#pragma unroll
  for (int i = 0; i < 4; i++) {
#pragma unroll
    for (int j = 0; j < 4; j++) {
#pragma unroll
      for (int r = 0; r < 4; r++) {
        int row = m0 + wm * 64 + i * 16 + quad * 4 + r;
        int col = n0 + wn * 64 + j * 16 + l16;
        P[(size_t)row * D + col] = acc[i][j][r];
      }
    }
  }
}

// ---------------------------------------------------------------------------
// 128x64-tile GEMM (N=1024 matmuls), BK=64, 8x8 L2 swizzle.
// Waves 2x2; each wave 64(m) x 32(n) -> acc[4][2], 16 MFMA per stage.
// ---------------------------------------------------------------------------
template<typename TC>
__global__ __launch_bounds__(256) void gemm_bt_n64(
    const u16* __restrict__ A, const u16* __restrict__ BT,
    const float* __restrict__ bias, TC* __restrict__ C,
    int N, int K)
{
  __shared__ __align__(16) u16 As[2][128 * 32];
  __shared__ __align__(16) u16 Bs[2][64 * 32];
  const int tid = threadIdx.x;
  const int wave = tid >> 6, lane = tid & 63;
  const int quad = lane >> 4, l16 = lane & 15;
  int bx, by; swizzle8(bx, by);
  const int m0 = by * 128, n0 = bx * 64;
  const int wm = (wave >> 1) * 64, wn = (wave & 1) * 32;
  const int srow = lane >> 2;
  const int skoff = (lane & 3) * 8;

  f32x4 acc[4][2] = {};

  for (int k0 = 0; k0 < K; k0 += 64) {
#pragma unroll
    for (int h = 0; h < 2; h++) {
#pragma unroll
      for (int t = 0; t < 2; t++) {
        int slot = wave * 2 + t;
        int row = slot * 16 + srow;
        async_cp16(A + (size_t)(m0 + row) * K + k0 + h * 32 + skoff, As[h] + slot * 512);
      }
      int row = wave * 16 + srow;
      async_cp16(BT + (size_t)(n0 + row) * K + k0 + h * 32 + skoff, Bs[h] + wave * 512);
    }
    __syncthreads();

#pragma unroll
    for (int h = 0; h < 2; h++) {
      bf16x8 af[4], bfv[2];
#pragma unroll
      for (int i = 0; i < 4; i++)
        af[i] = *(const bf16x8*)(As[h] + (wm + i * 16 + l16) * 32 + quad * 8);
#pragma unroll
      for (int j = 0; j < 2; j++)
        bfv[j] = *(const bf16x8*)(Bs[h] + (wn + j * 16 + l16) * 32 + quad * 8);
#pragma unroll
      for (int i = 0; i < 4; i++)
#pragma unroll
        for (int j = 0; j < 2; j++)
          acc[i][j] = __builtin_amdgcn_mfma_f32_16x16x32_bf16(af[i], bfv[j], acc[i][j], 0, 0, 0);
    }
    __syncthreads();
  }

#pragma unroll
  for (int i = 0; i < 4; i++) {
#pragma unroll
    for (int j = 0; j < 2; j++) {
#pragma unroll
      for (int r = 0; r < 4; r++) {
        int row = m0 + wm + i * 16 + quad * 4 + r;
        int col = n0 + wn + j * 16 + l16;
        stv(C, (size_t)row * N + col, acc[i][j][r] + bias[col]);
      }
    }
  }
}

// ---------------------------------------------------------------------------
// V transpose: (BH, S, W) -> (BH, W, S), 64x64 tiles via LDS.
// ---------------------------------------------------------------------------
__global__ __launch_bounds__(256) void transpose_v_kernel(
    const u16* __restrict__ v, u16* __restrict__ vt)
{
  __shared__ __align__(16) u16 T[64][72];
  const int bh = blockIdx.y, k0 = blockIdx.x * 64, tid = threadIdx.x;
#pragma unroll
  for (int it = 0; it < 2; it++) {
    int vv = tid + it * 256;
    int key = vv >> 3, w0 = (vv & 7) * 8;
    union { uint4 q; u16 e[8]; } u;
    u.q = *(const uint4*)(v + ((size_t)bh * S + k0 + key) * W + w0);
#pragma unroll
    for (int j = 0; j < 8; j++) T[w0 + j][key] = u.e[j];
  }
  __syncthreads();
#pragma unroll
  for (int it = 0; it < 2; it++) {
    int vv = tid + it * 256;
    int w = vv >> 3, koff = (vv & 7) * 8;
    *(uint4*)(vt + ((size_t)bh * W + w) * S + k0 + koff) = *(const uint4*)(&T[w][koff]);
  }
}

// ---------------------------------------------------------------------------
// Flash attention (MFMA). QBLK=256: 4 waves x 64 q-rows (4 groups of 16).
// Every K/V fragment ds_read and every staging write amortizes over 4
// q-groups (r5 diagnosis: per-CU LDS issue is the floor). Swapped QK^T,
// ballot mask (+ all-ones fast path), b64 P-stores, key-split 2-way,
// XOR-swizzled LDS (slot' = slot ^ ((row>>1)&3), both sides; all row bases
// are multiples of 16 so read xr = (l16>>1)&3, P-write row is l16-based).
// Grid (S/256, BH, 2) = 512 blocks; LDS 48KB -> 2 blocks/CU resident.
// ---------------------------------------------------------------------------
__global__ __launch_bounds__(256) void fattn_kernel(
    const u16* __restrict__ q, const u16* __restrict__ k,
    const u16* __restrict__ vt, const int* __restrict__ mask,
    u16* __restrict__ o_parts, float* __restrict__ l_parts)
{
  __shared__ __align__(16) u16 QP[2][256][32];  // Q staging, then P tiles
  __shared__ __align__(16) u16 Kl[2][64][32];   // K tile [key][w]
  __shared__ __align__(16) u16 Vl[2][64][32];   // V^T tile [w][key]

  const int tid = threadIdx.x, wave = tid >> 6, lane = tid & 63;
  const int quad = lane >> 4, l16 = lane & 15;
  const int bh = blockIdx.y, b = bh >> 4, h = bh & 15;
  const int q0 = blockIdx.x * 256;
  const int half = blockIdx.z;
  const int kbase = half * (S / 2);             // first key of this half
  const int wq0 = wave * 64;                    // wave's 64 q-rows
  const int sr  = tid >> 3;              // 0..31
  const int sg  = tid & 7;               // chunk along W: 0..7
  const int sp  = sg >> 2;               // plane (cols 0-31 / 32-63)
  const int sc0 = sg * 8;                // global col (u16 units)
  const int ssw = (((sg & 3) ^ ((sr >> 1) & 3)) << 3);
  const int xr = (l16 >> 1) & 3;
  const int rq = ((quad ^ xr) << 3);

  // stage Q tile 256x64 (swizzled)
#pragma unroll
  for (int t = 0; t < 8; t++) {
    int row = sr + t * 32;
    *(uint4*)(&QP[sp][row][ssw]) =
        *(const uint4*)(q + ((size_t)bh * S + q0 + row) * W + sc0);
  }
  __syncthreads();
  bf16x8 aq[4][2];
#pragma unroll
  for (int g = 0; g < 4; g++)
#pragma unroll
    for (int kc = 0; kc < 2; kc++)
      aq[g][kc] = *(const bf16x8*)(&QP[kc][wq0 + g * 16 + l16][rq]);

  bf16x8 ones;
  {
    u16 ov = (l16 == 0) ? (u16)0x3F80 : (u16)0;
#pragma unroll
    for (int j = 0; j < 8; j++) ones[j] = u2b(ov);
  }

  f32x4 o_acc[4][4] = {};
  f32x4 l_acc[4] = {};

  uint4 kr0, kr1, vr0, vr1;
  int mv;
  kr0 = *(const uint4*)(k  + ((size_t)bh * S + kbase + sr     ) * W + sc0);
  kr1 = *(const uint4*)(k  + ((size_t)bh * S + kbase + sr + 32) * W + sc0);
  vr0 = *(const uint4*)(vt + ((size_t)bh * W + sr     ) * S + kbase + sc0);
  vr1 = *(const uint4*)(vt + ((size_t)bh * W + sr + 32) * S + kbase + sc0);
  mv  = mask[b * S + kbase + lane];

  constexpr int NT = S / 128;   // 16 key tiles per half
  for (int kt = 0; kt < NT; kt++) {
    __syncthreads();
    *(uint4*)(&Kl[sp][sr     ][ssw]) = kr0;
    *(uint4*)(&Kl[sp][sr + 32][ssw]) = kr1;
    *(uint4*)(&Vl[sp][sr     ][ssw]) = vr0;
    *(uint4*)(&Vl[sp][sr + 32][ssw]) = vr1;
    u64 km = __ballot(mv != 0);
    __syncthreads();

    if (kt + 1 < NT) {
      int kn = kbase + (kt + 1) * 64;
      kr0 = *(const uint4*)(k  + ((size_t)bh * S + kn + sr     ) * W + sc0);
      kr1 = *(const uint4*)(k  + ((size_t)bh * S + kn + sr + 32) * W + sc0);
      vr0 = *(const uint4*)(vt + ((size_t)bh * W + sr     ) * S + kn + sc0);
      vr1 = *(const uint4*)(vt + ((size_t)bh * W + sr + 32) * S + kn + sc0);
      mv  = mask[b * S + kn + lane];
    }

    const bool allm = (km == ~0ull);   // wave-uniform fast path
#pragma unroll
    for (int tn = 0; tn < 4; tn++) {
      bf16x8 bk0 = *(const bf16x8*)(&Kl[0][tn * 16 + l16][rq]);
      bf16x8 bk1 = *(const bf16x8*)(&Kl[1][tn * 16 + l16][rq]);
      u32 nib = (u32)(km >> (tn * 16 + quad * 4)) & 0xFu;
      int slotp = (((tn & 1) * 2 + (quad >> 1)) ^ xr) * 8 + (quad & 1) * 4;
#pragma unroll
      for (int g = 0; g < 4; g++) {
        f32x4 s4 = {};
        s4 = __builtin_amdgcn_mfma_f32_16x16x32_bf16(bk0, aq[g][0], s4, 0, 0, 0);
        s4 = __builtin_amdgcn_mfma_f32_16x16x32_bf16(bk1, aq[g][1], s4, 0, 0, 0);
        union { u64 u; u16 e[4]; } pw;
        if (allm) {
#pragma unroll
          for (int r = 0; r < 4; r++) pw.e[r] = f2bf_cvt(__expf(s4[r]));
        } else {
#pragma unroll
          for (int r = 0; r < 4; r++) {
            float pm = (float)((nib >> r) & 1u);
            pw.e[r] = f2bf_cvt(__expf(s4[r]) * pm);
          }
        }
        *(u64*)(&QP[tn >> 1][wq0 + g * 16 + l16][slotp]) = pw.u;
      }
    }
    // no barrier: P slab is wave-private; same-wave DS ops are ordered

#pragma unroll
    for (int kc = 0; kc < 2; kc++) {
      bf16x8 ap[4];
#pragma unroll
      for (int g = 0; g < 4; g++)
        ap[g] = *(const bf16x8*)(&QP[kc][wq0 + g * 16 + l16][rq]);
#pragma unroll
      for (int tn = 0; tn < 4; tn++) {
        bf16x8 bv = *(const bf16x8*)(&Vl[kc][tn * 16 + l16][rq]);
#pragma unroll
        for (int g = 0; g < 4; g++)
          o_acc[g][tn] = __builtin_amdgcn_mfma_f32_16x16x32_bf16(ap[g], bv, o_acc[g][tn], 0, 0, 0);
      }
#pragma unroll
      for (int g = 0; g < 4; g++)
        l_acc[g] = __builtin_amdgcn_mfma_f32_16x16x32_bf16(ap[g], ones, l_acc[g], 0, 0, 0);
    }
  }

  u16* ob = o_parts + (size_t)half * M * D;
  float* lb = l_parts + (size_t)half * M * H;
#pragma unroll
  for (int g = 0; g < 4; g++) {
#pragma unroll
    for (int r = 0; r < 4; r++) {
      float lsum = __shfl(l_acc[g][r], lane & 0x30);
      int sg2 = q0 + wq0 + g * 16 + quad * 4 + r;
      if (l16 == 0) lb[((size_t)b * S + sg2) * H + h] = lsum;
#pragma unroll
      for (int tn = 0; tn < 4; tn++) {
        ob[((size_t)b * S + sg2) * D + h * W + tn * 16 + l16] = f2bf_cvt(o_acc[g][tn][r]);
      }
    }
  }
}

// ---------------------------------------------------------------------------
// Combine key-split partials: attn = (o0 + o1) / (l0 + l1). In-place on
// half 0 (same-address elementwise -> race-free).
// ---------------------------------------------------------------------------
__global__ __launch_bounds__(256) void combine_attn(
    const u16* __restrict__ o_parts, const float* __restrict__ l_parts,
    u16* __restrict__ attn)
{
  size_t idx = ((size_t)blockIdx.x * 256 + threadIdx.x) * 8;
  int row = (int)(idx >> 10);          // (b*S+s)
  int h = ((int)idx >> 6) & 15;        // head (8 elems stay in one head)
  float l = l_parts[(size_t)row * H + h] + l_parts[(size_t)M * H + (size_t)row * H + h];
  float inv = 1.0f / l;
  union { uint4 v; u16 e[8]; } a, bq, o;
  a.v  = *(const uint4*)(o_parts + idx);
  bq.v = *(const uint4*)(o_parts + (size_t)M * D + idx);
#pragma unroll
  for (int j = 0; j < 8; j++)
    o.e[j] = f2bf((bf2f(a.e[j]) + bf2f(bq.e[j])) * inv);
  *(uint4*)(attn + idx) = o.v;
}

// ---------------------------------------------------------------------------
// Fused residual + LayerNorm, one WAVE per row (no block barriers).
// grid = M/4 blocks of 256 threads.
// ---------------------------------------------------------------------------
template<typename TA, typename TR, typename TO>
__global__ __launch_bounds__(256) void ln_res_kernel(
    const TA* __restrict__ a, const TR* __restrict__ r,
    const float* __restrict__ g, const float* __restrict__ be,
    TO* __restrict__ out)
{
  const int tid = threadIdx.x, lane = tid & 63;
  const int row = blockIdx.x * 4 + (tid >> 6);
  const TA* ap = a + (size_t)row * D;
  const TR* rp = r + (size_t)row * D;
  float hv[16];
  float s = 0.f;
#pragma unroll
  for (int c = 0; c < 16; c++) {
    int d = c * 64 + lane;
    hv[c] = ldv(ap, d) + ldv(rp, d);
    s += hv[c];
  }
#pragma unroll
  for (int d = 1; d < 64; d <<= 1) s += __shfl_xor(s, d);
  float mean = s * (1.0f / D);
  float v = 0.f;
#pragma unroll
  for (int c = 0; c < 16; c++) { float t = hv[c] - mean; v += t * t; }
#pragma unroll
  for (int d = 1; d < 64; d <<= 1) v += __shfl_xor(v, d);
  float inv = rsqrtf(v * (1.0f / D) + 1e-12f);
#pragma unroll
  for (int c = 0; c < 16; c++) {
    int d = c * 64 + lane;
    stv(out, (size_t)row * D + d, g[d] * ((hv[c] - mean) * inv) + be[d]);
  }
}

// ---------------------------------------------------------------------------
// LN2 with split-K FFN2 partials: out = LN(a + p0 + p1 + bias). In-place
// safe when out == p0 (per-thread same-address read/write).
// ---------------------------------------------------------------------------
__global__ __launch_bounds__(256) void ln_res3_kernel(
    const u16* __restrict__ a, const float* __restrict__ p0,
    const float* __restrict__ p1, const float* __restrict__ bias,
    const float* __restrict__ g, const float* __restrict__ be,
    float* __restrict__ out)
{
  const int tid = threadIdx.x, lane = tid & 63;
  const int row = blockIdx.x * 4 + (tid >> 6);
  const u16* ap = a + (size_t)row * D;
  const float* q0 = p0 + (size_t)row * D;
  const float* q1 = p1 + (size_t)row * D;
  float hv[16];
  float s = 0.f;
#pragma unroll
  for (int c = 0; c < 16; c++) {
    int d = c * 64 + lane;
    hv[c] = bf2f(ap[d]) + q0[d] + q1[d] + bias[d];
    s += hv[c];
  }
#pragma unroll
  for (int d = 1; d < 64; d <<= 1) s += __shfl_xor(s, d);
  float mean = s * (1.0f / D);
  float v = 0.f;
#pragma unroll
  for (int c = 0; c < 16; c++) { float t = hv[c] - mean; v += t * t; }
#pragma unroll
  for (int d = 1; d < 64; d <<= 1) v += __shfl_xor(v, d);
  float inv = rsqrtf(v * (1.0f / D) + 1e-12f);
#pragma unroll
  for (int c = 0; c < 16; c++) {
    int d = c * 64 + lane;
    out[(size_t)row * D + d] = g[d] * ((hv[c] - mean) * inv) + be[d];
  }
}

// ---------------------------------------------------------------------------
extern "C" void kernel_launch(void* const* d_in, const int* in_sizes, int n_in,
                              void* d_out, int out_size, void* d_ws, size_t ws_size,
                              hipStream_t stream)
{
  const float* x  = (const float*)d_in[0];
  const int* mask = (const int*)d_in[1];
  const float* wq = (const float*)d_in[2];  const float* bq  = (const float*)d_in[3];
  const float* wk = (const float*)d_in[4];  const float* bk  = (const float*)d_in[5];
  const float* wv = (const float*)d_in[6];  const float* bv  = (const float*)d_in[7];
  const float* wo = (const float*)d_in[8];  const float* bo  = (const float*)d_in[9];
  const float* g1 = (const float*)d_in[10]; const float* b1  = (const float*)d_in[11];
  const float* w1 = (const float*)d_in[12]; const float* bf1 = (const float*)d_in[13];
  const float* w2 = (const float*)d_in[14]; const float* bf2 = (const float*)d_in[15];
  const float* g2 = (const float*)d_in[16]; const float* b2  = (const float*)d_in[17];

  // ws layout (base 48 MB; split-K FFN2 uses [48,64M) when available):
  //  A [0,8M):   wqkvT(6M)+woT(2M); wqkvT dead after QKV -> l_parts(512KB)
  //              lives at [0,0.5M) during fattn; then w1T(8M) -> w2T(8M)
  //  B [8,16M):  xb -> vt -> ff1[0:8M)
  //  C [16,24M): q  -> proj -> ff1[8:16M)
  //  D [24,32M): k  -> ff1[16:24M)
  //  E [32,48M): v(8M, dead after transpose_v) -> o_parts(16M); combine
  //              writes attn in-place over half 0 ([32,40M)) -> ff1[24:32M)
  //  F [40,48M): bqkv(12KB, dead by fattn) -> o_parts half1 -> h1
  //  G [48,64M): FFN2 split-K partial1 (fp32, 16M) -- only if ws_size allows
  //  ff2 partial0 -> d_out; LN2 in place on d_out.
  char* ws = (char*)d_ws;
  const size_t MB = 1024 * 1024;
  u16* wqkvT = (u16*)(ws + 0 * MB);          // (3072, 1024) bf16
  u16* woT   = (u16*)(ws + 6 * MB);          // (1024, 1024)
  u16* w1T   = (u16*)(ws + 0 * MB);          // (4096, 1024) after proj
  u16* w2T   = (u16*)(ws + 0 * MB);          // (1024, 4096) after ffn1
  u16* xb    = (u16*)(ws + 8 * MB);
  u16* vt    = (u16*)(ws + 8 * MB);
  u16* q     = (u16*)(ws + 16 * MB);
  u16* proj  = (u16*)(ws + 16 * MB);
  u16* kb    = (u16*)(ws + 24 * MB);
  u16* vb    = (u16*)(ws + 32 * MB);
  u16* oparts = (u16*)(ws + 32 * MB);        // 16 MB: 2 x (M,D) bf16 partials
  float* lparts = (float*)(ws + 0 * MB);     // 512 KB: 2 x (M,H) f32
  u16* attn  = (u16*)(ws + 32 * MB);         // combine output (aliases half0)
  u16* ff1   = (u16*)(ws + 8 * MB);          // 32 MB: [8,40)
  float* bqkv = (float*)(ws + 40 * MB);      // 12 KB
  u16* h1    = (u16*)(ws + 40 * MB);
  float* part1 = (float*)(ws + 48 * MB);     // 16 MB (gated on ws_size)
  float* out = (float*)d_out;

  const bool bigws = ws_size >= (size_t)64 * MB;

  dim3 blk(256);

  // prep: x -> bf16; weights -> bf16 transposed; bias concat
  conv_x_kernel<<<dim3(M * D / 1024), blk, 0, stream>>>(x, xb);
  transpose_w_kernel<<<dim3(16, 16), blk, 0, stream>>>(wq, wqkvT,            D, D);
  transpose_w_kernel<<<dim3(16, 16), blk, 0, stream>>>(wk, wqkvT + 1024*1024, D, D);
  transpose_w_kernel<<<dim3(16, 16), blk, 0, stream>>>(wv, wqkvT + 2048*1024, D, D);
  transpose_w_kernel<<<dim3(16, 16), blk, 0, stream>>>(wo, woT,              D, D);
  hipMemcpyAsync(bqkv,        bq, D * sizeof(float), hipMemcpyDeviceToDevice, stream);
  hipMemcpyAsync(bqkv + 1024, bk, D * sizeof(float), hipMemcpyDeviceToDevice, stream);
  hipMemcpyAsync(bqkv + 2048, bv, D * sizeof(float), hipMemcpyDeviceToDevice, stream);

  // fused QKV GEMM on the 256^2 8-phase template: (M,1024)@(1024,3072),
  // EPI=2 permute epilogue. Grid (12,16)=192 blocks; 12%8!=0 -> SWZ=false
  // (all blocks co-resident; unique panels ~14MB fit aggregate L2).
  gemm256<3072, 1024, 2, false><<<dim3(3072 / 256, M / 256), dim3(512), 0, stream>>>(
      xb, wqkvT, bqkv, q, 0.125f);

  transpose_v_kernel<<<dim3(S / 64, Bb * H), blk, 0, stream>>>(vb, vt);
  // key-split flash attention: QBLK=256, 512 blocks, partials
  fattn_kernel<<<dim3(S / 256, Bb * H, 2), blk, 0, stream>>>(
      q, kb, vt, mask, oparts, lparts);
  combine_attn<<<dim3(M * D / 2048), blk, 0, stream>>>(oparts, lparts, attn);

  // proj: N=1024 -> 128x64 tiles (512 blocks, 2/CU)
  gemm_bt_n64<u16><<<dim3(D / 64, M / 128), blk, 0, stream>>>(
      attn, woT, bo, proj, D, D);
  ln_res_kernel<float, u16, u16><<<dim3(M / 4), blk, 0, stream>>>(x, proj, g1, b1, h1);

  transpose_w_kernel<<<dim3(F / 64, D / 64), blk, 0, stream>>>(w1, w1T, D, F);
  // FFN1: 256^2 8-phase GEMM (T2+T3+T4+T5), 256 blocks of 512 thr = 1/CU
  gemm256<4096, 1024, 1, true><<<dim3(F / 256, M / 256), dim3(512), 0, stream>>>(
      h1, w1T, bf1, ff1, 1.0f);

  transpose_w_kernel<<<dim3(D / 64, F / 64), blk, 0, stream>>>(w2, w2T, F, D);
  if (bigws) {
    // FFN2: 256x128-tile 8-phase split-K (256 blocks = 1/CU), fp32 partials;
    // LN2 fuses the combine: out = LN(h1 + p0 + p1 + bf2)
    gemm_ffn2_splitk<<<dim3(D / 128, M / 256, 2), dim3(512), 0, stream>>>(
        ff1, w2T, out, part1);
    ln_res3_kernel<<<dim3(M / 4), blk, 0, stream>>>(h1, out, part1, bf2, g2, b2, out);
  } else {
    // fallback (small workspace): 2-phase 128x64 FFN2 + 2-input LN2
    gemm_bt_n64<float><<<dim3(D / 64, M / 128), blk, 0, stream>>>(
        ff1, w2T, bf2, out, D, F);
    ln_res_kernel<u16, float, float><<<dim3(M / 4), blk, 0, stream>>>(h1, out, g2, b2, out);
  }
}